// Round 2
// baseline (913.195 us; speedup 1.0000x reference)
//
#include <hip/hip_runtime.h>
#include <hip/hip_bf16.h>
#include <hip/hip_fp16.h>

// ---------------------------------------------------------------------------
// GCN 3-layer forward. N=100000, E=1600000, F: 64 -> 128 -> 128 -> 64.
// R11: XCD-sliced standalone gathers. agg kernels split the feature dim into
//      8 slices; slice = blockIdx%8 pins each slice to one XCD (round-robin
//      dispatch, measured). Per-XCD gather table slice (3.2 MB / 1.6 MB)
//      fits the 4 MB XCD L2 -> gathers become L2 hits; each table line is
//      fetched from LLC by exactly one XCD (kills the 8x duplication floor).
//   CSR: phist -> scan_blocks -> mid -> part2 -> finalize
//   F1: fag<64,128>  msgX(P) -> msg1(Q)      [+b1, relu, *dinv]
//   agg_slice<128,16> msg1(Q) -> aggH1(P)    [*dinv, f16]
//   dgemm: aggH1(P) -> msg3(Q)               [W2,+b2,relu | W3,*dinv]
//   agg_slice<64,8> msg3(Q) -> out (+b3, f32)
// ---------------------------------------------------------------------------

typedef _Float16 h8 __attribute__((ext_vector_type(8)));
typedef float f4 __attribute__((ext_vector_type(4)));

constexpr int BSHIFT = 7;                 // 128 nodes per bucket
constexpr int BNODES = 1 << BSHIFT;
constexpr int PB     = 256;               // partition blocks
constexpr int CAP    = 4096;              // finalize LDS stage capacity

// ---- f16 helpers ----------------------------------------------------------
__device__ inline void load8h(const _Float16* p, float* f) {
    h8 v = *(const h8*)p;
#pragma unroll
    for (int j = 0; j < 8; j++) f[j] = (float)v[j];
}

__device__ inline void store8h(_Float16* p, const float* f) {
    h8 v;
#pragma unroll
    for (int j = 0; j < 8; j++) v[j] = (_Float16)f[j];
    *(h8*)p = v;
}

__device__ inline void store4h(_Float16* p, float4 v) {
    _Float16 t[4] = {(_Float16)v.x, (_Float16)v.y, (_Float16)v.z, (_Float16)v.w};
    *(uint2*)p = *(uint2*)t;
}

// ---- CSR build ------------------------------------------------------------
__global__ __launch_bounds__(256) void phist_k(const int* __restrict__ dst,
                                               int* __restrict__ hist,
                                               int E, int nbuck, int chunk) {
    __shared__ int h[1024];
    for (int i = threadIdx.x; i < nbuck; i += 256) h[i] = 0;
    __syncthreads();
    int beg = blockIdx.x * chunk;
    int end = min(E, beg + chunk);
    for (int e = beg + threadIdx.x; e < end; e += 256)
        atomicAdd(&h[dst[e] >> BSHIFT], 1);
    __syncthreads();
    for (int i = threadIdx.x; i < nbuck; i += 256)
        hist[(long)blockIdx.x * nbuck + i] = h[i];
}

__global__ __launch_bounds__(256) void scan_blocks_k(const int* __restrict__ in,
                                                     int* __restrict__ excl,
                                                     int* __restrict__ bsums, int n) {
    __shared__ int s[256];
    int tid = threadIdx.x;
    int i = blockIdx.x * 256 + tid;
    int v = (i < n) ? in[i] : 0;
    s[tid] = v;
    __syncthreads();
    for (int off = 1; off < 256; off <<= 1) {
        int t = (tid >= off) ? s[tid - off] : 0;
        __syncthreads();
        s[tid] += t;
        __syncthreads();
    }
    if (i < n) excl[i] = s[tid] - v;
    if (tid == 255) bsums[blockIdx.x] = s[255];
}

// block 0: exclusive scan of bsums; block 1: column-sum hist -> scan -> bbase
__global__ __launch_bounds__(1024) void mid_k(int* __restrict__ bsums, int nb,
                                              const int* __restrict__ hist,
                                              int* __restrict__ bbase,
                                              int nbuck, int E) {
    __shared__ int s[1024];
    int tid = threadIdx.x;
    int v = 0;
    if (blockIdx.x == 0) {
        v = (tid < nb) ? bsums[tid] : 0;
    } else {
        if (tid < nbuck) {
            int t0 = 0, t1 = 0, t2 = 0, t3 = 0;
            for (int j = 0; j < PB; j += 4) {
                t0 += hist[(long)(j + 0) * nbuck + tid];
                t1 += hist[(long)(j + 1) * nbuck + tid];
                t2 += hist[(long)(j + 2) * nbuck + tid];
                t3 += hist[(long)(j + 3) * nbuck + tid];
            }
            v = (t0 + t1) + (t2 + t3);
        }
    }
    s[tid] = v;
    __syncthreads();
    for (int off = 1; off < 1024; off <<= 1) {
        int t = (tid >= off) ? s[tid - off] : 0;
        __syncthreads();
        s[tid] += t;
        __syncthreads();
    }
    if (blockIdx.x == 0) {
        if (tid < nb) bsums[tid] = s[tid] - v;
    } else {
        if (tid < nbuck) bbase[tid] = s[tid] - v;
        if (tid == 0) bbase[nbuck] = E;
    }
}

__global__ __launch_bounds__(256) void part2_k(const int* __restrict__ src,
                                               const int* __restrict__ dst,
                                               const int* __restrict__ offs,
                                               const int* __restrict__ bsums,
                                               unsigned* __restrict__ ebuf,
                                               int E, int nbuck, int chunk) {
    __shared__ int cur[1024];
    for (int i = threadIdx.x; i < nbuck; i += 256) {
        long flat = (long)blockIdx.x * nbuck + i;
        cur[i] = offs[flat] + bsums[flat >> 8];
    }
    __syncthreads();
    int beg = blockIdx.x * chunk;
    int end = min(E, beg + chunk);
    for (int e = beg + threadIdx.x; e < end; e += 256) {
        int d = dst[e];
        int b = d >> BSHIFT;
        int pos = atomicAdd(&cur[b], 1);
        ebuf[pos] = ((unsigned)(d & (BNODES - 1)) << 25) | (unsigned)src[e];
    }
}

__global__ __launch_bounds__(256) void finalize_k(const unsigned* __restrict__ ebuf,
                                                  const int* __restrict__ hist,
                                                  const int* __restrict__ offs,
                                                  const int* __restrict__ bsums,
                                                  const int* __restrict__ bbase,
                                                  int nbuck,
                                                  int* __restrict__ rowst,
                                                  int* __restrict__ rowend,
                                                  float* __restrict__ dinv,
                                                  int* __restrict__ col,
                                                  const float* __restrict__ x,
                                                  _Float16* __restrict__ msgX, int N) {
    __shared__ unsigned se[CAP];
    __shared__ int cj[PB], sj[PB], sb[PB];
    __shared__ int cnt_s[BNODES], scan_s[BNODES], cur_s[BNODES];
    __shared__ float di_s[BNODES];

    int b = blockIdx.x, tid = threadIdx.x;
    int node0 = b << BSHIFT;
    int nn = min(BNODES, N - node0);
    int beg = bbase[b];

    if (tid < PB) {
        long flat = (long)tid * nbuck + b;
        cj[tid] = hist[flat];
        sj[tid] = offs[flat] + bsums[flat >> 8];
    }
    if (tid < BNODES) cnt_s[tid] = 0;
    __syncthreads();

    if (tid < PB) sb[tid] = cj[tid];
    __syncthreads();
    for (int off = 1; off < PB; off <<= 1) {
        int t = 0;
        if (tid < PB && tid >= off) t = sb[tid - off];
        __syncthreads();
        if (tid < PB) sb[tid] += t;
        __syncthreads();
    }
    int m = sb[PB - 1];
    __syncthreads();

    // gather segments into LDS: 1 thread per segment (~8 edges each)
    {
        int j = tid;
        int base = sb[j] - cj[j], c = cj[j], s0 = sj[j];
        for (int k = 0; k < c; k++) {
            unsigned e = ebuf[s0 + k];
            int idx = base + k;
            if (idx < CAP) se[idx] = e;
            else atomicAdd(&cnt_s[e >> 25], 1);
        }
    }
    __syncthreads();

    int mcap = m < CAP ? m : CAP;
    for (int i = tid; i < mcap; i += 256) atomicAdd(&cnt_s[se[i] >> 25], 1);
    __syncthreads();

    int v = (tid < BNODES) ? cnt_s[tid] : 0;
    if (tid < BNODES) scan_s[tid] = v;
    __syncthreads();
    for (int off = 1; off < BNODES; off <<= 1) {
        int t = 0;
        if (tid < BNODES && tid >= off) t = scan_s[tid - off];
        __syncthreads();
        if (tid < BNODES) scan_s[tid] += t;
        __syncthreads();
    }
    if (tid < nn) {
        int ex = scan_s[tid] - v;
        int st = beg + ex;
        rowst[node0 + tid] = st;
        rowend[node0 + tid] = st + v;
        float di = rsqrtf((float)v + 1.0f);
        dinv[node0 + tid] = di;
        di_s[tid] = di;
        cur_s[tid] = ex;
    }
    __syncthreads();

    for (int i = tid; i < mcap; i += 256) {
        unsigned e = se[i];
        int p = atomicAdd(&cur_s[e >> 25], 1);
        col[beg + p] = (int)(e & 0x1FFFFFFu);
    }
    if (m > CAP) {  // overflow spill (statistically never)
        int j = tid;
        int base = sb[j] - cj[j], c = cj[j], s0 = sj[j];
        for (int k = 0; k < c; k++) {
            int idx = base + k;
            if (idx >= CAP) {
                unsigned e = ebuf[s0 + k];
                int p = atomicAdd(&cur_s[e >> 25], 1);
                col[beg + p] = (int)(e & 0x1FFFFFFu);
            }
        }
    }

    // fused msgX prep: msgX[n,64] f16 = dinv[n] * x[n,:]
    for (int t = tid; t < nn * 16; t += 256) {
        int nl = t >> 4, q = t & 15;
        int node = node0 + nl;
        float4 vx = *(const float4*)(x + (long)node * 64 + q * 4);
        float di = di_s[nl];
        vx.x *= di; vx.y *= di; vx.z *= di; vx.w *= di;
        store4h(msgX + (long)node * 64 + q * 4, vx);
    }
}

// ---- fused aggregate + MFMA GEMM (layer 1 only, K=64) ---------------------
template <int K, int FOUT, bool BIAS, bool RELU, bool DINV_OUT>
__global__ __launch_bounds__(256) void fag_k(const _Float16* __restrict__ msg,
                                             const int* __restrict__ rowst,
                                             const int* __restrict__ rowend,
                                             const int* __restrict__ col,
                                             const float* __restrict__ dinv,
                                             const _Float16* __restrict__ Wsw,
                                             const float* __restrict__ bias,
                                             _Float16* __restrict__ C, int n) {
    constexpr int NT = FOUT / 16, NC = K / 32;
    constexpr int LDK = K + 8;
    constexpr int LPN = K / 8;
    constexpr int NPB = 256 / LPN;
    __shared__ _Float16 As[64 * LDK];

    int tid = threadIdx.x;
    int row0 = blockIdx.x * 64;

#pragma unroll
    for (int pass = 0; pass < 64 / NPB; pass++) {
        int nl = pass * NPB + tid / LPN;
        int q = tid % LPN;
        int node = row0 + nl;
        float acc[8];
        if (node < n) {
            load8h(msg + (long)node * K + q * 8, acc);  // self (dinv folded)
            int beg = rowst[node], end = rowend[node];
            int e = beg;
            for (; e + 4 <= end; e += 4) {
                int s0 = col[e], s1 = col[e + 1], s2 = col[e + 2], s3 = col[e + 3];
                h8 v0 = *(const h8*)(msg + (long)s0 * K + q * 8);
                h8 v1 = *(const h8*)(msg + (long)s1 * K + q * 8);
                h8 v2 = *(const h8*)(msg + (long)s2 * K + q * 8);
                h8 v3 = *(const h8*)(msg + (long)s3 * K + q * 8);
#pragma unroll
                for (int j = 0; j < 8; j++)
                    acc[j] += ((float)v0[j] + (float)v1[j]) + ((float)v2[j] + (float)v3[j]);
            }
            for (; e < end; e++) {
                int s = col[e];
                h8 v = *(const h8*)(msg + (long)s * K + q * 8);
#pragma unroll
                for (int j = 0; j < 8; j++) acc[j] += (float)v[j];
            }
            float di = dinv[node];
#pragma unroll
            for (int j = 0; j < 8; j++) acc[j] *= di;
        } else {
#pragma unroll
            for (int j = 0; j < 8; j++) acc[j] = 0.f;
        }
        h8 o;
#pragma unroll
        for (int j = 0; j < 8; j++) o[j] = (_Float16)acc[j];
        *(h8*)(As + nl * LDK + q * 8) = o;
    }
    __syncthreads();

    int lane = tid & 63, wave = tid >> 6;
    int quad = lane >> 4, cl = lane & 15;
    int r0 = wave * 16;

    h8 a[NC];
#pragma unroll
    for (int c = 0; c < NC; c++)
        a[c] = *(const h8*)(As + (r0 + cl) * LDK + quad * 8 + c * 32);

    f4 acc2[NT];
#pragma unroll
    for (int t = 0; t < NT; t++) acc2[t] = (f4){0.f, 0.f, 0.f, 0.f};

    const h8* wv = (const h8*)Wsw;
#pragma unroll
    for (int c = 0; c < NC; c++) {
#pragma unroll
        for (int t = 0; t < NT; t++)
            acc2[t] = __builtin_amdgcn_mfma_f32_16x16x32_f16(
                a[c], wv[(c * NT + t) * 64 + lane], acc2[t], 0, 0, 0);
    }

#pragma unroll
    for (int t = 0; t < NT; t++) {
        int c0 = t * 16 + cl;
        float bb = BIAS ? bias[c0] : 0.f;
#pragma unroll
        for (int r = 0; r < 4; r++) {
            int row = row0 + r0 + quad * 4 + r;
            if (row >= n) continue;
            float v = acc2[t][r] + bb;
            if (RELU) v = fmaxf(v, 0.f);
            if (DINV_OUT) v *= dinv[row];
            C[(long)row * FOUT + c0] = (_Float16)v;
        }
    }
}

// ---- XCD-sliced standalone aggregation ------------------------------------
// Feature dim split into 8 slices of FS; slice = blockIdx%8 -> lands on one
// XCD (round-robin dispatch). Per-XCD table slice = N*FS*2B fits 4MB L2.
template <int F, int FS, bool BIAS, bool F16OUT>
__global__ __launch_bounds__(256) void agg_slice_k(const _Float16* __restrict__ msg,
                                                   const int* __restrict__ rowst,
                                                   const int* __restrict__ rowend,
                                                   const int* __restrict__ col,
                                                   const float* __restrict__ dinv,
                                                   const float* __restrict__ b,
                                                   void* __restrict__ out, int n) {
    constexpr int LPS = FS / 8;            // lanes per node (within slice)
    constexpr int NPB = 256 / LPS;         // nodes per block
    int slice = blockIdx.x & 7;
    int blk   = blockIdx.x >> 3;
    int node  = blk * NPB + threadIdx.x / LPS;
    int q     = threadIdx.x % LPS;
    if (node >= n) return;
    int f0 = slice * FS + q * 8;
    const _Float16* mp = msg + f0;

    float acc[8];
    load8h(mp + (long)node * F, acc);      // self (dinv folded upstream)

    int beg = rowst[node], end = rowend[node];
    int e = beg;
    for (; e + 8 <= end; e += 8) {         // 8 independent gathers in flight
        h8 v[8];
#pragma unroll
        for (int u = 0; u < 8; u++)
            v[u] = *(const h8*)(mp + (long)col[e + u] * F);
#pragma unroll
        for (int j = 0; j < 8; j++)
            acc[j] += (((float)v[0][j] + (float)v[1][j]) + ((float)v[2][j] + (float)v[3][j])) +
                      (((float)v[4][j] + (float)v[5][j]) + ((float)v[6][j] + (float)v[7][j]));
    }
    for (; e + 4 <= end; e += 4) {
        h8 v0 = *(const h8*)(mp + (long)col[e] * F);
        h8 v1 = *(const h8*)(mp + (long)col[e + 1] * F);
        h8 v2 = *(const h8*)(mp + (long)col[e + 2] * F);
        h8 v3 = *(const h8*)(mp + (long)col[e + 3] * F);
#pragma unroll
        for (int j = 0; j < 8; j++)
            acc[j] += ((float)v0[j] + (float)v1[j]) + ((float)v2[j] + (float)v3[j]);
    }
    for (; e < end; e++) {
        h8 v = *(const h8*)(mp + (long)col[e] * F);
#pragma unroll
        for (int j = 0; j < 8; j++) acc[j] += (float)v[j];
    }

    float di = dinv[node];
    float o[8];
#pragma unroll
    for (int j = 0; j < 8; j++) o[j] = di * acc[j];
    if (BIAS) {
#pragma unroll
        for (int j = 0; j < 8; j++) o[j] += b[f0 + j];
    }
    if (F16OUT) {
        store8h((_Float16*)out + (long)node * F + f0, o);
    } else {
        float* d = (float*)out + (long)node * F + f0;
        *(float4*)d = make_float4(o[0], o[1], o[2], o[3]);
        *(float4*)(d + 4) = make_float4(o[4], o[5], o[6], o[7]);
    }
}

// ---- weight swizzle -------------------------------------------------------
template <int K, int FOUT>
__device__ inline void wfrag(const float* __restrict__ W,
                             _Float16* __restrict__ Wsw, int t) {
    constexpr int NT = FOUT / 16;
    int lane = t & 63;
    int tile = (t >> 6) % NT;
    int chunk = (t >> 6) / NT;
    int kbase = chunk * 32 + (lane >> 4) * 8;
    int nc = tile * 16 + (lane & 15);
    h8 v;
#pragma unroll
    for (int j = 0; j < 8; j++) v[j] = (_Float16)W[(kbase + j) * FOUT + nc];
    ((h8*)Wsw)[t] = v;
}

__global__ __launch_bounds__(256) void wprep3_k(const float* __restrict__ W1,
                                                const float* __restrict__ W2,
                                                const float* __restrict__ W3,
                                                _Float16* __restrict__ w1s,
                                                _Float16* __restrict__ w2s,
                                                _Float16* __restrict__ w3s) {
    int t = blockIdx.x * 256 + threadIdx.x;
    if (t < 1024) wfrag<64, 128>(W1, w1s, t);
    else if (t < 3072) wfrag<128, 128>(W2, w2s, t - 1024);
    else if (t < 4096) wfrag<128, 64>(W3, w3s, t - 3072);
}

// ---- fused double GEMM: msg3 = dinv (.) ( relu(A@W2 + b2) @ W3 ) ----------
// 64 rows/block, 4 waves; each wave owns 16 rows end-to-end (no barrier:
// the intermediate tile rows are wave-private in LDS).
__global__ __launch_bounds__(256) void dgemm_k(const _Float16* __restrict__ A,
                                               const _Float16* __restrict__ w2s,
                                               const _Float16* __restrict__ w3s,
                                               const float* __restrict__ b2,
                                               const float* __restrict__ dinv,
                                               _Float16* __restrict__ C, int n) {
    constexpr int LDK = 136;
    __shared__ _Float16 Hs[64 * LDK];

    int tid = threadIdx.x, lane = tid & 63, wave = tid >> 6;
    int quad = lane >> 4, cl = lane & 15;
    int row0 = blockIdx.x * 64, r0 = wave * 16;

    // GEMM-1: rows r0..r0+15, K=128 -> 128
    h8 a[4];
    const _Float16* arow = A + (long)(row0 + r0 + cl) * 128 + quad * 8;
#pragma unroll
    for (int c = 0; c < 4; c++) a[c] = *(const h8*)(arow + c * 32);

    f4 acc1[8];
#pragma unroll
    for (int t = 0; t < 8; t++) acc1[t] = (f4){0.f, 0.f, 0.f, 0.f};
    const h8* wv2 = (const h8*)w2s;
#pragma unroll
    for (int c = 0; c < 4; c++) {
#pragma unroll
        for (int t = 0; t < 8; t++)
            acc1[t] = __builtin_amdgcn_mfma_f32_16x16x32_f16(
                a[c], wv2[(c * 8 + t) * 64 + lane], acc1[t], 0, 0, 0);
    }

    // epilogue 1: +b2, relu -> wave-private LDS rows
#pragma unroll
    for (int t = 0; t < 8; t++) {
        int c0 = t * 16 + cl;
        float bb = b2[c0];
#pragma unroll
        for (int r = 0; r < 4; r++) {
            float v = fmaxf(acc1[t][r] + bb, 0.f);
            Hs[(r0 + quad * 4 + r) * LDK + c0] = (_Float16)v;
        }
    }
    __builtin_amdgcn_s_waitcnt(0);   // drain LDS writes (wave-private rows)

    // GEMM-2: K=128 -> 64
    h8 a2[4];
#pragma unroll
    for (int c = 0; c < 4; c++)
        a2[c] = *(const h8*)(Hs + (r0 + cl) * LDK + quad * 8 + c * 32);

    f4 acc2[4];
#pragma unroll
    for (int t = 0; t < 4; t++) acc2[t] = (f4){0.f, 0.f, 0.f, 0.f};
    const h8* wv3 = (const h8*)w3s;
#pragma unroll
    for (int c = 0; c < 4; c++) {
#pragma unroll
        for (int t = 0; t < 4; t++)
            acc2[t] = __builtin_amdgcn_mfma_f32_16x16x32_f16(
                a2[c], wv3[(c * 4 + t) * 64 + lane], acc2[t], 0, 0, 0);
    }

    // epilogue 2: *dinv, store msg3
#pragma unroll
    for (int t = 0; t < 4; t++) {
        int c0 = t * 16 + cl;
#pragma unroll
        for (int r = 0; r < 4; r++) {
            int row = row0 + r0 + quad * 4 + r;
            if (row >= n) continue;
            float v = acc2[t][r] * dinv[row];
            C[(long)row * 64 + c0] = (_Float16)v;
        }
    }
}

extern "C" void kernel_launch(void* const* d_in, const int* in_sizes, int n_in,
                              void* d_out, int out_size, void* d_ws, size_t ws_size,
                              hipStream_t stream) {
    const float* x  = (const float*)d_in[0];
    const int*   ei = (const int*)d_in[1];
    const float* W1 = (const float*)d_in[2];
    const float* b1 = (const float*)d_in[3];
    const float* W2 = (const float*)d_in[4];
    const float* b2 = (const float*)d_in[5];
    const float* W3 = (const float*)d_in[6];
    const float* b3 = (const float*)d_in[7];
    float* out = (float*)d_out;

    const int N = in_sizes[0] / 64;
    const int E = in_sizes[1] / 2;
    const int* src = ei;
    const int* dst = ei + E;
    const int nbuck = (N + BNODES - 1) >> BSHIFT;   // 782
    const int chunk = (E + PB - 1) / PB;            // 6250
    const int n2 = PB * nbuck;                      // 200192
    const int nb2 = (n2 + 255) / 256;               // 782

    // workspace carve-up (4-byte elems)
    int*   hist   = (int*)d_ws;                   // PB*nbuck
    int*   offs   = hist + n2;                    // PB*nbuck
    int*   bsums  = offs + n2;                    // 1024
    int*   bbase  = bsums + 1024;                 // nbuck+1
    int*   rowst  = bbase + nbuck + 1;            // N
    int*   rowend = rowst + N;                    // N
    float* dinv   = (float*)(rowend + N);         // N
    int*   col    = (int*)(dinv + N);             // E
    _Float16* w1s = (_Float16*)(col + E);         // 64*128 f16
    _Float16* w2s = w1s + 64 * 128;               // 128*128 f16
    _Float16* w3s = w2s + 128 * 128;              // 128*64 f16
    float* P      = (float*)(w3s + 128 * 64);     // N*128 f32 worth
    float* Q      = P + (long)N * 128;            // N*128 f32 worth

    _Float16* msgX  = (_Float16*)P;   // N x 64 f16
    unsigned* ebuf  = (unsigned*)Q;   // E x 4B (dead after finalize)
    _Float16* msg1  = (_Float16*)Q;   // N x 128 f16 (F1 out)
    _Float16* aggH1 = (_Float16*)P;   // N x 128 f16 (msgX dead)
    _Float16* msg3  = (_Float16*)Q;   // N x 64 f16  (msg1 dead)

    const int gb = (N + 63) / 64;

    // ---- weight swizzle ----
    wprep3_k<<<16, 256, 0, stream>>>(W1, W2, W3, w1s, w2s, w3s);

    // ---- CSR build ----
    phist_k<<<PB, 256, 0, stream>>>(dst, hist, E, nbuck, chunk);
    scan_blocks_k<<<nb2, 256, 0, stream>>>(hist, offs, bsums, n2);
    mid_k<<<2, 1024, 0, stream>>>(bsums, nb2, hist, bbase, nbuck, E);
    part2_k<<<PB, 256, 0, stream>>>(src, dst, offs, bsums, ebuf, E, nbuck, chunk);
    finalize_k<<<nbuck, 256, 0, stream>>>(ebuf, hist, offs, bsums, bbase, nbuck,
                                          rowst, rowend, dinv, col, x, msgX, N);

    // ---- layer 1 (fused agg+gemm): msgX(P) -> msg1(Q) ----
    fag_k<64, 128, true, true, true><<<gb, 256, 0, stream>>>(
        msgX, rowst, rowend, col, dinv, w1s, b1, msg1, N);

    // ---- layer 2 gather (XCD-sliced): msg1(Q) -> aggH1(P) ----
    const int nb128 = (N + 127) / 128;   // 782
    agg_slice_k<128, 16, false, true><<<8 * nb128, 256, 0, stream>>>(
        msg1, rowst, rowend, col, dinv, nullptr, (void*)aggH1, N);

    // ---- fused gemm2+gemm3: aggH1(P) -> msg3(Q) ----
    dgemm_k<<<gb, 256, 0, stream>>>(aggH1, w2s, w3s, b2, dinv, msg3, N);

    // ---- layer 3 gather (XCD-sliced): msg3(Q) -> out ----
    const int nb256 = (N + 255) / 256;   // 391
    agg_slice_k<64, 8, true, false><<<8 * nb256, 256, 0, stream>>>(
        msg3, rowst, rowend, col, dinv, b3, (void*)out, N);
}

// Round 3
// 433.294 us; speedup vs baseline: 2.1076x; 2.1076x over previous
//
#include <hip/hip_runtime.h>
#include <hip/hip_bf16.h>
#include <hip/hip_fp16.h>

// ---------------------------------------------------------------------------
// GCN 3-layer forward. N=100000, E=1600000, F: 64 -> 128 -> 128 -> 64.
// R12: slice-MAJOR XCD-sliced gathers. R11 failed (940MB fetch): strided
//      16-feat slices occupy one 64B line per 256B row -> 6.4MB/XCD > L2.
//      Now msg1 is stored [8][N][16] (fag epilogue) and msg3 [8][N][8]
//      (dgemm epilogue): each slice contiguous (3.2/1.6 MB) -> resident in
//      the 4MB XCD L2; slice = blockIdx%8 pins slice to XCD (round-robin).
//   CSR: phist -> scan_blocks -> mid -> part2 -> finalize
//   F1: fag<64,128>  msgX(P) -> msg1 slice-major (Q)  [+b1, relu, *dinv]
//   agg_sm2: msg1(Q) -> aggH1 row-major (P)           [*dinv, f16]
//   dgemm: aggH1(P) -> msg3 slice-major (Q)           [W2,+b2,relu | W3,*dinv]
//   agg_sm3: msg3(Q) -> out (+b3, f32)
// ---------------------------------------------------------------------------

typedef _Float16 h8 __attribute__((ext_vector_type(8)));
typedef float f4 __attribute__((ext_vector_type(4)));

constexpr int BSHIFT = 7;                 // 128 nodes per bucket
constexpr int BNODES = 1 << BSHIFT;
constexpr int PB     = 256;               // partition blocks
constexpr int CAP    = 4096;              // finalize LDS stage capacity

// ---- f16 helpers ----------------------------------------------------------
__device__ inline void load8h(const _Float16* p, float* f) {
    h8 v = *(const h8*)p;
#pragma unroll
    for (int j = 0; j < 8; j++) f[j] = (float)v[j];
}

__device__ inline void store8h(_Float16* p, const float* f) {
    h8 v;
#pragma unroll
    for (int j = 0; j < 8; j++) v[j] = (_Float16)f[j];
    *(h8*)p = v;
}

__device__ inline void store4h(_Float16* p, float4 v) {
    _Float16 t[4] = {(_Float16)v.x, (_Float16)v.y, (_Float16)v.z, (_Float16)v.w};
    *(uint2*)p = *(uint2*)t;
}

// ---- CSR build ------------------------------------------------------------
__global__ __launch_bounds__(256) void phist_k(const int* __restrict__ dst,
                                               int* __restrict__ hist,
                                               int E, int nbuck, int chunk) {
    __shared__ int h[1024];
    for (int i = threadIdx.x; i < nbuck; i += 256) h[i] = 0;
    __syncthreads();
    int beg = blockIdx.x * chunk;
    int end = min(E, beg + chunk);
    for (int e = beg + threadIdx.x; e < end; e += 256)
        atomicAdd(&h[dst[e] >> BSHIFT], 1);
    __syncthreads();
    for (int i = threadIdx.x; i < nbuck; i += 256)
        hist[(long)blockIdx.x * nbuck + i] = h[i];
}

__global__ __launch_bounds__(256) void scan_blocks_k(const int* __restrict__ in,
                                                     int* __restrict__ excl,
                                                     int* __restrict__ bsums, int n) {
    __shared__ int s[256];
    int tid = threadIdx.x;
    int i = blockIdx.x * 256 + tid;
    int v = (i < n) ? in[i] : 0;
    s[tid] = v;
    __syncthreads();
    for (int off = 1; off < 256; off <<= 1) {
        int t = (tid >= off) ? s[tid - off] : 0;
        __syncthreads();
        s[tid] += t;
        __syncthreads();
    }
    if (i < n) excl[i] = s[tid] - v;
    if (tid == 255) bsums[blockIdx.x] = s[255];
}

// block 0: exclusive scan of bsums; block 1: column-sum hist -> scan -> bbase
__global__ __launch_bounds__(1024) void mid_k(int* __restrict__ bsums, int nb,
                                              const int* __restrict__ hist,
                                              int* __restrict__ bbase,
                                              int nbuck, int E) {
    __shared__ int s[1024];
    int tid = threadIdx.x;
    int v = 0;
    if (blockIdx.x == 0) {
        v = (tid < nb) ? bsums[tid] : 0;
    } else {
        if (tid < nbuck) {
            int t0 = 0, t1 = 0, t2 = 0, t3 = 0;
            for (int j = 0; j < PB; j += 4) {
                t0 += hist[(long)(j + 0) * nbuck + tid];
                t1 += hist[(long)(j + 1) * nbuck + tid];
                t2 += hist[(long)(j + 2) * nbuck + tid];
                t3 += hist[(long)(j + 3) * nbuck + tid];
            }
            v = (t0 + t1) + (t2 + t3);
        }
    }
    s[tid] = v;
    __syncthreads();
    for (int off = 1; off < 1024; off <<= 1) {
        int t = (tid >= off) ? s[tid - off] : 0;
        __syncthreads();
        s[tid] += t;
        __syncthreads();
    }
    if (blockIdx.x == 0) {
        if (tid < nb) bsums[tid] = s[tid] - v;
    } else {
        if (tid < nbuck) bbase[tid] = s[tid] - v;
        if (tid == 0) bbase[nbuck] = E;
    }
}

__global__ __launch_bounds__(256) void part2_k(const int* __restrict__ src,
                                               const int* __restrict__ dst,
                                               const int* __restrict__ offs,
                                               const int* __restrict__ bsums,
                                               unsigned* __restrict__ ebuf,
                                               int E, int nbuck, int chunk) {
    __shared__ int cur[1024];
    for (int i = threadIdx.x; i < nbuck; i += 256) {
        long flat = (long)blockIdx.x * nbuck + i;
        cur[i] = offs[flat] + bsums[flat >> 8];
    }
    __syncthreads();
    int beg = blockIdx.x * chunk;
    int end = min(E, beg + chunk);
    for (int e = beg + threadIdx.x; e < end; e += 256) {
        int d = dst[e];
        int b = d >> BSHIFT;
        int pos = atomicAdd(&cur[b], 1);
        ebuf[pos] = ((unsigned)(d & (BNODES - 1)) << 25) | (unsigned)src[e];
    }
}

__global__ __launch_bounds__(256) void finalize_k(const unsigned* __restrict__ ebuf,
                                                  const int* __restrict__ hist,
                                                  const int* __restrict__ offs,
                                                  const int* __restrict__ bsums,
                                                  const int* __restrict__ bbase,
                                                  int nbuck,
                                                  int* __restrict__ rowst,
                                                  int* __restrict__ rowend,
                                                  float* __restrict__ dinv,
                                                  int* __restrict__ col,
                                                  const float* __restrict__ x,
                                                  _Float16* __restrict__ msgX, int N) {
    __shared__ unsigned se[CAP];
    __shared__ int cj[PB], sj[PB], sb[PB];
    __shared__ int cnt_s[BNODES], scan_s[BNODES], cur_s[BNODES];
    __shared__ float di_s[BNODES];

    int b = blockIdx.x, tid = threadIdx.x;
    int node0 = b << BSHIFT;
    int nn = min(BNODES, N - node0);
    int beg = bbase[b];

    if (tid < PB) {
        long flat = (long)tid * nbuck + b;
        cj[tid] = hist[flat];
        sj[tid] = offs[flat] + bsums[flat >> 8];
    }
    if (tid < BNODES) cnt_s[tid] = 0;
    __syncthreads();

    if (tid < PB) sb[tid] = cj[tid];
    __syncthreads();
    for (int off = 1; off < PB; off <<= 1) {
        int t = 0;
        if (tid < PB && tid >= off) t = sb[tid - off];
        __syncthreads();
        if (tid < PB) sb[tid] += t;
        __syncthreads();
    }
    int m = sb[PB - 1];
    __syncthreads();

    // gather segments into LDS: 1 thread per segment (~8 edges each)
    {
        int j = tid;
        int base = sb[j] - cj[j], c = cj[j], s0 = sj[j];
        for (int k = 0; k < c; k++) {
            unsigned e = ebuf[s0 + k];
            int idx = base + k;
            if (idx < CAP) se[idx] = e;
            else atomicAdd(&cnt_s[e >> 25], 1);
        }
    }
    __syncthreads();

    int mcap = m < CAP ? m : CAP;
    for (int i = tid; i < mcap; i += 256) atomicAdd(&cnt_s[se[i] >> 25], 1);
    __syncthreads();

    int v = (tid < BNODES) ? cnt_s[tid] : 0;
    if (tid < BNODES) scan_s[tid] = v;
    __syncthreads();
    for (int off = 1; off < BNODES; off <<= 1) {
        int t = 0;
        if (tid < BNODES && tid >= off) t = scan_s[tid - off];
        __syncthreads();
        if (tid < BNODES) scan_s[tid] += t;
        __syncthreads();
    }
    if (tid < nn) {
        int ex = scan_s[tid] - v;
        int st = beg + ex;
        rowst[node0 + tid] = st;
        rowend[node0 + tid] = st + v;
        float di = rsqrtf((float)v + 1.0f);
        dinv[node0 + tid] = di;
        di_s[tid] = di;
        cur_s[tid] = ex;
    }
    __syncthreads();

    for (int i = tid; i < mcap; i += 256) {
        unsigned e = se[i];
        int p = atomicAdd(&cur_s[e >> 25], 1);
        col[beg + p] = (int)(e & 0x1FFFFFFu);
    }
    if (m > CAP) {  // overflow spill (statistically never)
        int j = tid;
        int base = sb[j] - cj[j], c = cj[j], s0 = sj[j];
        for (int k = 0; k < c; k++) {
            int idx = base + k;
            if (idx >= CAP) {
                unsigned e = ebuf[s0 + k];
                int p = atomicAdd(&cur_s[e >> 25], 1);
                col[beg + p] = (int)(e & 0x1FFFFFFu);
            }
        }
    }

    // fused msgX prep: msgX[n,64] f16 = dinv[n] * x[n,:]
    for (int t = tid; t < nn * 16; t += 256) {
        int nl = t >> 4, q = t & 15;
        int node = node0 + nl;
        float4 vx = *(const float4*)(x + (long)node * 64 + q * 4);
        float di = di_s[nl];
        vx.x *= di; vx.y *= di; vx.z *= di; vx.w *= di;
        store4h(msgX + (long)node * 64 + q * 4, vx);
    }
}

// ---- fused aggregate + MFMA GEMM (layer 1 only, K=64) ---------------------
// SMOUT: write C slice-major [NT][n][16] (for XCD-sliced consumer).
template <int K, int FOUT, bool BIAS, bool RELU, bool DINV_OUT, bool SMOUT>
__global__ __launch_bounds__(256) void fag_k(const _Float16* __restrict__ msg,
                                             const int* __restrict__ rowst,
                                             const int* __restrict__ rowend,
                                             const int* __restrict__ col,
                                             const float* __restrict__ dinv,
                                             const _Float16* __restrict__ Wsw,
                                             const float* __restrict__ bias,
                                             _Float16* __restrict__ C, int n) {
    constexpr int NT = FOUT / 16, NC = K / 32;
    constexpr int LDK = K + 8;
    constexpr int LPN = K / 8;
    constexpr int NPB = 256 / LPN;
    __shared__ _Float16 As[64 * LDK];

    int tid = threadIdx.x;
    int row0 = blockIdx.x * 64;

#pragma unroll
    for (int pass = 0; pass < 64 / NPB; pass++) {
        int nl = pass * NPB + tid / LPN;
        int q = tid % LPN;
        int node = row0 + nl;
        float acc[8];
        if (node < n) {
            load8h(msg + (long)node * K + q * 8, acc);  // self (dinv folded)
            int beg = rowst[node], end = rowend[node];
            int e = beg;
            for (; e + 4 <= end; e += 4) {
                int s0 = col[e], s1 = col[e + 1], s2 = col[e + 2], s3 = col[e + 3];
                h8 v0 = *(const h8*)(msg + (long)s0 * K + q * 8);
                h8 v1 = *(const h8*)(msg + (long)s1 * K + q * 8);
                h8 v2 = *(const h8*)(msg + (long)s2 * K + q * 8);
                h8 v3 = *(const h8*)(msg + (long)s3 * K + q * 8);
#pragma unroll
                for (int j = 0; j < 8; j++)
                    acc[j] += ((float)v0[j] + (float)v1[j]) + ((float)v2[j] + (float)v3[j]);
            }
            for (; e < end; e++) {
                int s = col[e];
                h8 v = *(const h8*)(msg + (long)s * K + q * 8);
#pragma unroll
                for (int j = 0; j < 8; j++) acc[j] += (float)v[j];
            }
            float di = dinv[node];
#pragma unroll
            for (int j = 0; j < 8; j++) acc[j] *= di;
        } else {
#pragma unroll
            for (int j = 0; j < 8; j++) acc[j] = 0.f;
        }
        h8 o;
#pragma unroll
        for (int j = 0; j < 8; j++) o[j] = (_Float16)acc[j];
        *(h8*)(As + nl * LDK + q * 8) = o;
    }
    __syncthreads();

    int lane = tid & 63, wave = tid >> 6;
    int quad = lane >> 4, cl = lane & 15;
    int r0 = wave * 16;

    h8 a[NC];
#pragma unroll
    for (int c = 0; c < NC; c++)
        a[c] = *(const h8*)(As + (r0 + cl) * LDK + quad * 8 + c * 32);

    f4 acc2[NT];
#pragma unroll
    for (int t = 0; t < NT; t++) acc2[t] = (f4){0.f, 0.f, 0.f, 0.f};

    const h8* wv = (const h8*)Wsw;
#pragma unroll
    for (int c = 0; c < NC; c++) {
#pragma unroll
        for (int t = 0; t < NT; t++)
            acc2[t] = __builtin_amdgcn_mfma_f32_16x16x32_f16(
                a[c], wv[(c * NT + t) * 64 + lane], acc2[t], 0, 0, 0);
    }

#pragma unroll
    for (int t = 0; t < NT; t++) {
        int c0 = t * 16 + cl;
        float bb = BIAS ? bias[c0] : 0.f;
#pragma unroll
        for (int r = 0; r < 4; r++) {
            int row = row0 + r0 + quad * 4 + r;
            if (row >= n) continue;
            float v = acc2[t][r] + bb;
            if (RELU) v = fmaxf(v, 0.f);
            if (DINV_OUT) v *= dinv[row];
            if (SMOUT)
                C[((long)t * n + row) * 16 + cl] = (_Float16)v;
            else
                C[(long)row * FOUT + c0] = (_Float16)v;
        }
    }
}

// ---- XCD-sliced slice-major aggregation, layer 2 --------------------------
// msg: [8][n][16] f16 slice-major (slice window = n*32B = 3.2MB, fits XCD L2)
// out: [n][128] f16 row-major.  slice = blockIdx%8 -> XCD pin (round-robin).
__global__ __launch_bounds__(256) void agg_sm2_k(const _Float16* __restrict__ msg,
                                                 const int* __restrict__ rowst,
                                                 const int* __restrict__ rowend,
                                                 const int* __restrict__ col,
                                                 const float* __restrict__ dinv,
                                                 _Float16* __restrict__ out, int n) {
    int slice = blockIdx.x & 7;
    int blk   = blockIdx.x >> 3;
    int node  = blk * 128 + (threadIdx.x >> 1);
    int q     = threadIdx.x & 1;
    if (node >= n) return;
    const _Float16* mp = msg + (long)slice * n * 16 + q * 8;

    float acc[8];
    load8h(mp + (long)node * 16, acc);     // self (dinv folded upstream)

    int beg = rowst[node], end = rowend[node];
    int e = beg;
    for (; e + 8 <= end; e += 8) {         // 8 independent gathers in flight
        h8 v[8];
#pragma unroll
        for (int u = 0; u < 8; u++)
            v[u] = *(const h8*)(mp + (long)col[e + u] * 16);
#pragma unroll
        for (int j = 0; j < 8; j++)
            acc[j] += (((float)v[0][j] + (float)v[1][j]) + ((float)v[2][j] + (float)v[3][j])) +
                      (((float)v[4][j] + (float)v[5][j]) + ((float)v[6][j] + (float)v[7][j]));
    }
    for (; e + 4 <= end; e += 4) {
        h8 v0 = *(const h8*)(mp + (long)col[e] * 16);
        h8 v1 = *(const h8*)(mp + (long)col[e + 1] * 16);
        h8 v2 = *(const h8*)(mp + (long)col[e + 2] * 16);
        h8 v3 = *(const h8*)(mp + (long)col[e + 3] * 16);
#pragma unroll
        for (int j = 0; j < 8; j++)
            acc[j] += ((float)v0[j] + (float)v1[j]) + ((float)v2[j] + (float)v3[j]);
    }
    for (; e < end; e++) {
        h8 v = *(const h8*)(mp + (long)col[e] * 16);
#pragma unroll
        for (int j = 0; j < 8; j++) acc[j] += (float)v[j];
    }

    float di = dinv[node];
    float o[8];
#pragma unroll
    for (int j = 0; j < 8; j++) o[j] = di * acc[j];
    store8h(out + (long)node * 128 + slice * 16 + q * 8, o);
}

// ---- XCD-sliced slice-major aggregation, layer 3 --------------------------
// msg: [8][n][8] f16 slice-major (window = n*16B = 1.6MB); out [n][64] f32.
// One lane per node (whole 8-feat slice in one h8).
__global__ __launch_bounds__(256) void agg_sm3_k(const _Float16* __restrict__ msg,
                                                 const int* __restrict__ rowst,
                                                 const int* __restrict__ rowend,
                                                 const int* __restrict__ col,
                                                 const float* __restrict__ dinv,
                                                 const float* __restrict__ b,
                                                 float* __restrict__ out, int n) {
    int slice = blockIdx.x & 7;
    int blk   = blockIdx.x >> 3;
    int node  = blk * 256 + threadIdx.x;
    if (node >= n) return;
    const _Float16* mp = msg + (long)slice * n * 8;

    float acc[8];
    load8h(mp + (long)node * 8, acc);      // self (dinv folded upstream)

    int beg = rowst[node], end = rowend[node];
    int e = beg;
    for (; e + 8 <= end; e += 8) {
        h8 v[8];
#pragma unroll
        for (int u = 0; u < 8; u++)
            v[u] = *(const h8*)(mp + (long)col[e + u] * 8);
#pragma unroll
        for (int j = 0; j < 8; j++)
            acc[j] += (((float)v[0][j] + (float)v[1][j]) + ((float)v[2][j] + (float)v[3][j])) +
                      (((float)v[4][j] + (float)v[5][j]) + ((float)v[6][j] + (float)v[7][j]));
    }
    for (; e + 4 <= end; e += 4) {
        h8 v0 = *(const h8*)(mp + (long)col[e] * 8);
        h8 v1 = *(const h8*)(mp + (long)col[e + 1] * 8);
        h8 v2 = *(const h8*)(mp + (long)col[e + 2] * 8);
        h8 v3 = *(const h8*)(mp + (long)col[e + 3] * 8);
#pragma unroll
        for (int j = 0; j < 8; j++)
            acc[j] += ((float)v0[j] + (float)v1[j]) + ((float)v2[j] + (float)v3[j]);
    }
    for (; e < end; e++) {
        h8 v = *(const h8*)(mp + (long)col[e] * 8);
#pragma unroll
        for (int j = 0; j < 8; j++) acc[j] += (float)v[j];
    }

    float di = dinv[node];
    float o[8];
#pragma unroll
    for (int j = 0; j < 8; j++) o[j] = di * acc[j] + b[slice * 8 + j];
    float* d = out + (long)node * 64 + slice * 8;
    *(float4*)d = make_float4(o[0], o[1], o[2], o[3]);
    *(float4*)(d + 4) = make_float4(o[4], o[5], o[6], o[7]);
}

// ---- weight swizzle -------------------------------------------------------
template <int K, int FOUT>
__device__ inline void wfrag(const float* __restrict__ W,
                             _Float16* __restrict__ Wsw, int t) {
    constexpr int NT = FOUT / 16;
    int lane = t & 63;
    int tile = (t >> 6) % NT;
    int chunk = (t >> 6) / NT;
    int kbase = chunk * 32 + (lane >> 4) * 8;
    int nc = tile * 16 + (lane & 15);
    h8 v;
#pragma unroll
    for (int j = 0; j < 8; j++) v[j] = (_Float16)W[(kbase + j) * FOUT + nc];
    ((h8*)Wsw)[t] = v;
}

__global__ __launch_bounds__(256) void wprep3_k(const float* __restrict__ W1,
                                                const float* __restrict__ W2,
                                                const float* __restrict__ W3,
                                                _Float16* __restrict__ w1s,
                                                _Float16* __restrict__ w2s,
                                                _Float16* __restrict__ w3s) {
    int t = blockIdx.x * 256 + threadIdx.x;
    if (t < 1024) wfrag<64, 128>(W1, w1s, t);
    else if (t < 3072) wfrag<128, 128>(W2, w2s, t - 1024);
    else if (t < 4096) wfrag<128, 64>(W3, w3s, t - 3072);
}

// ---- fused double GEMM: msg3 = dinv (.) ( relu(A@W2 + b2) @ W3 ) ----------
// 64 rows/block, 4 waves; each wave owns 16 rows end-to-end (no barrier:
// the intermediate tile rows are wave-private in LDS).
// Output msg3 written SLICE-MAJOR [8][n][8] for the XCD-sliced layer-3 agg.
__global__ __launch_bounds__(256) void dgemm_k(const _Float16* __restrict__ A,
                                               const _Float16* __restrict__ w2s,
                                               const _Float16* __restrict__ w3s,
                                               const float* __restrict__ b2,
                                               const float* __restrict__ dinv,
                                               _Float16* __restrict__ C, int n) {
    constexpr int LDK = 136;
    __shared__ _Float16 Hs[64 * LDK];

    int tid = threadIdx.x, lane = tid & 63, wave = tid >> 6;
    int quad = lane >> 4, cl = lane & 15;
    int row0 = blockIdx.x * 64, r0 = wave * 16;

    // GEMM-1: rows r0..r0+15, K=128 -> 128
    h8 a[4];
    const _Float16* arow = A + (long)(row0 + r0 + cl) * 128 + quad * 8;
#pragma unroll
    for (int c = 0; c < 4; c++) a[c] = *(const h8*)(arow + c * 32);

    f4 acc1[8];
#pragma unroll
    for (int t = 0; t < 8; t++) acc1[t] = (f4){0.f, 0.f, 0.f, 0.f};
    const h8* wv2 = (const h8*)w2s;
#pragma unroll
    for (int c = 0; c < 4; c++) {
#pragma unroll
        for (int t = 0; t < 8; t++)
            acc1[t] = __builtin_amdgcn_mfma_f32_16x16x32_f16(
                a[c], wv2[(c * 8 + t) * 64 + lane], acc1[t], 0, 0, 0);
    }

    // epilogue 1: +b2, relu -> wave-private LDS rows
#pragma unroll
    for (int t = 0; t < 8; t++) {
        int c0 = t * 16 + cl;
        float bb = b2[c0];
#pragma unroll
        for (int r = 0; r < 4; r++) {
            float v = fmaxf(acc1[t][r] + bb, 0.f);
            Hs[(r0 + quad * 4 + r) * LDK + c0] = (_Float16)v;
        }
    }
    __builtin_amdgcn_s_waitcnt(0);   // drain LDS writes (wave-private rows)

    // GEMM-2: K=128 -> 64
    h8 a2[4];
#pragma unroll
    for (int c = 0; c < 4; c++)
        a2[c] = *(const h8*)(Hs + (r0 + cl) * LDK + quad * 8 + c * 32);

    f4 acc2[4];
#pragma unroll
    for (int t = 0; t < 4; t++) acc2[t] = (f4){0.f, 0.f, 0.f, 0.f};
    const h8* wv3 = (const h8*)w3s;
#pragma unroll
    for (int c = 0; c < 4; c++) {
#pragma unroll
        for (int t = 0; t < 4; t++)
            acc2[t] = __builtin_amdgcn_mfma_f32_16x16x32_f16(
                a2[c], wv3[(c * 4 + t) * 64 + lane], acc2[t], 0, 0, 0);
    }

    // epilogue 2: *dinv, store msg3 slice-major [8][n][8]
#pragma unroll
    for (int t = 0; t < 4; t++) {
        int c0 = t * 16 + cl;
        int sl = c0 >> 3, sp = c0 & 7;
#pragma unroll
        for (int r = 0; r < 4; r++) {
            int row = row0 + r0 + quad * 4 + r;
            if (row >= n) continue;
            float v = acc2[t][r] * dinv[row];
            C[((long)sl * n + row) * 8 + sp] = (_Float16)v;
        }
    }
}

extern "C" void kernel_launch(void* const* d_in, const int* in_sizes, int n_in,
                              void* d_out, int out_size, void* d_ws, size_t ws_size,
                              hipStream_t stream) {
    const float* x  = (const float*)d_in[0];
    const int*   ei = (const int*)d_in[1];
    const float* W1 = (const float*)d_in[2];
    const float* b1 = (const float*)d_in[3];
    const float* W2 = (const float*)d_in[4];
    const float* b2 = (const float*)d_in[5];
    const float* W3 = (const float*)d_in[6];
    const float* b3 = (const float*)d_in[7];
    float* out = (float*)d_out;

    const int N = in_sizes[0] / 64;
    const int E = in_sizes[1] / 2;
    const int* src = ei;
    const int* dst = ei + E;
    const int nbuck = (N + BNODES - 1) >> BSHIFT;   // 782
    const int chunk = (E + PB - 1) / PB;            // 6250
    const int n2 = PB * nbuck;                      // 200192
    const int nb2 = (n2 + 255) / 256;               // 782

    // workspace carve-up (4-byte elems)
    int*   hist   = (int*)d_ws;                   // PB*nbuck
    int*   offs   = hist + n2;                    // PB*nbuck
    int*   bsums  = offs + n2;                    // 1024
    int*   bbase  = bsums + 1024;                 // nbuck+1
    int*   rowst  = bbase + nbuck + 1;            // N
    int*   rowend = rowst + N;                    // N
    float* dinv   = (float*)(rowend + N);         // N
    int*   col    = (int*)(dinv + N);             // E
    _Float16* w1s = (_Float16*)(col + E);         // 64*128 f16
    _Float16* w2s = w1s + 64 * 128;               // 128*128 f16
    _Float16* w3s = w2s + 128 * 128;              // 128*64 f16
    float* P      = (float*)(w3s + 128 * 64);     // N*128 f32 worth
    float* Q      = P + (long)N * 128;            // N*128 f32 worth

    _Float16* msgX  = (_Float16*)P;   // N x 64 f16
    unsigned* ebuf  = (unsigned*)Q;   // E x 4B (dead after finalize)
    _Float16* msg1  = (_Float16*)Q;   // [8][N][16] f16 slice-major (F1 out)
    _Float16* aggH1 = (_Float16*)P;   // N x 128 f16 row-major (msgX dead)
    _Float16* msg3  = (_Float16*)Q;   // [8][N][8] f16 slice-major (msg1 dead)

    const int gb = (N + 63) / 64;

    // ---- weight swizzle ----
    wprep3_k<<<16, 256, 0, stream>>>(W1, W2, W3, w1s, w2s, w3s);

    // ---- CSR build ----
    phist_k<<<PB, 256, 0, stream>>>(dst, hist, E, nbuck, chunk);
    scan_blocks_k<<<nb2, 256, 0, stream>>>(hist, offs, bsums, n2);
    mid_k<<<2, 1024, 0, stream>>>(bsums, nb2, hist, bbase, nbuck, E);
    part2_k<<<PB, 256, 0, stream>>>(src, dst, offs, bsums, ebuf, E, nbuck, chunk);
    finalize_k<<<nbuck, 256, 0, stream>>>(ebuf, hist, offs, bsums, bbase, nbuck,
                                          rowst, rowend, dinv, col, x, msgX, N);

    // ---- layer 1 (fused agg+gemm): msgX(P) -> msg1 slice-major (Q) ----
    fag_k<64, 128, true, true, true, true><<<gb, 256, 0, stream>>>(
        msgX, rowst, rowend, col, dinv, w1s, b1, msg1, N);

    // ---- layer 2 gather (XCD-sliced, slice-major in): msg1(Q) -> aggH1(P) ----
    const int nb128 = (N + 127) / 128;   // 782
    agg_sm2_k<<<8 * nb128, 256, 0, stream>>>(
        msg1, rowst, rowend, col, dinv, aggH1, N);

    // ---- fused gemm2+gemm3: aggH1(P) -> msg3 slice-major (Q) ----
    dgemm_k<<<gb, 256, 0, stream>>>(aggH1, w2s, w3s, b2, dinv, msg3, N);

    // ---- layer 3 gather (XCD-sliced, slice-major in): msg3(Q) -> out ----
    const int nb256 = (N + 255) / 256;   // 391
    agg_sm3_k<<<8 * nb256, 256, 0, stream>>>(
        msg3, rowst, rowend, col, dinv, b3, out, N);
}

// Round 4
// 402.852 us; speedup vs baseline: 2.2668x; 1.0756x over previous
//
#include <hip/hip_runtime.h>
#include <hip/hip_bf16.h>
#include <hip/hip_fp16.h>

// ---------------------------------------------------------------------------
// GCN 3-layer forward. N=100000, E=1600000, F: 64 -> 128 -> 128 -> 64.
// R13: edge-parallel XCD-sliced gathers. R12's slice-major cut FETCH 940->155MB
//      but 2-lane/node teams were L1-request-bound (32 seg/instr on col AND
//      gather, long serial chains): 108us at 24% HBM. Now 8 lanes/node
//      (4 edge-slots x 2 halves): col 4x fewer requests, 4x TLP, shfl reduce.
//      agg2 writes slice-major (coalesced 256B/wave, kills 2x write amp);
//      dgemm reads slice-major A. agg3 same structure (8 slots, 16B slices).
//   CSR: phist -> scan_blocks -> mid -> part2 -> finalize
//   F1: fag<64,128>  msgX(P) -> msg1 [8][N][16] (Q)   [+b1, relu, *dinv]
//   agg2: msg1(Q) -> aggH2 [8][N][16] (P)             [*dinv, f16]
//   dgemm: aggH2(P) -> msg3 [8][N][8] (Q)             [W2,+b2,relu | W3,*dinv]
//   agg3: msg3(Q) -> out (+b3, f32)
// ---------------------------------------------------------------------------

typedef _Float16 h8 __attribute__((ext_vector_type(8)));
typedef float f4 __attribute__((ext_vector_type(4)));

constexpr int BSHIFT = 7;                 // 128 nodes per bucket
constexpr int BNODES = 1 << BSHIFT;
constexpr int PB     = 256;               // partition blocks
constexpr int CAP    = 4096;              // finalize LDS stage capacity

// ---- f16 helpers ----------------------------------------------------------
__device__ inline void load8h(const _Float16* p, float* f) {
    h8 v = *(const h8*)p;
#pragma unroll
    for (int j = 0; j < 8; j++) f[j] = (float)v[j];
}

__device__ inline void store8h(_Float16* p, const float* f) {
    h8 v;
#pragma unroll
    for (int j = 0; j < 8; j++) v[j] = (_Float16)f[j];
    *(h8*)p = v;
}

__device__ inline void store4h(_Float16* p, float4 v) {
    _Float16 t[4] = {(_Float16)v.x, (_Float16)v.y, (_Float16)v.z, (_Float16)v.w};
    *(uint2*)p = *(uint2*)t;
}

// ---- CSR build ------------------------------------------------------------
__global__ __launch_bounds__(256) void phist_k(const int* __restrict__ dst,
                                               int* __restrict__ hist,
                                               int E, int nbuck, int chunk) {
    __shared__ int h[1024];
    for (int i = threadIdx.x; i < nbuck; i += 256) h[i] = 0;
    __syncthreads();
    int beg = blockIdx.x * chunk;
    int end = min(E, beg + chunk);
    for (int e = beg + threadIdx.x; e < end; e += 256)
        atomicAdd(&h[dst[e] >> BSHIFT], 1);
    __syncthreads();
    for (int i = threadIdx.x; i < nbuck; i += 256)
        hist[(long)blockIdx.x * nbuck + i] = h[i];
}

__global__ __launch_bounds__(256) void scan_blocks_k(const int* __restrict__ in,
                                                     int* __restrict__ excl,
                                                     int* __restrict__ bsums, int n) {
    __shared__ int s[256];
    int tid = threadIdx.x;
    int i = blockIdx.x * 256 + tid;
    int v = (i < n) ? in[i] : 0;
    s[tid] = v;
    __syncthreads();
    for (int off = 1; off < 256; off <<= 1) {
        int t = (tid >= off) ? s[tid - off] : 0;
        __syncthreads();
        s[tid] += t;
        __syncthreads();
    }
    if (i < n) excl[i] = s[tid] - v;
    if (tid == 255) bsums[blockIdx.x] = s[255];
}

// block 0: exclusive scan of bsums; block 1: column-sum hist -> scan -> bbase
__global__ __launch_bounds__(1024) void mid_k(int* __restrict__ bsums, int nb,
                                              const int* __restrict__ hist,
                                              int* __restrict__ bbase,
                                              int nbuck, int E) {
    __shared__ int s[1024];
    int tid = threadIdx.x;
    int v = 0;
    if (blockIdx.x == 0) {
        v = (tid < nb) ? bsums[tid] : 0;
    } else {
        if (tid < nbuck) {
            int t0 = 0, t1 = 0, t2 = 0, t3 = 0;
            for (int j = 0; j < PB; j += 4) {
                t0 += hist[(long)(j + 0) * nbuck + tid];
                t1 += hist[(long)(j + 1) * nbuck + tid];
                t2 += hist[(long)(j + 2) * nbuck + tid];
                t3 += hist[(long)(j + 3) * nbuck + tid];
            }
            v = (t0 + t1) + (t2 + t3);
        }
    }
    s[tid] = v;
    __syncthreads();
    for (int off = 1; off < 1024; off <<= 1) {
        int t = (tid >= off) ? s[tid - off] : 0;
        __syncthreads();
        s[tid] += t;
        __syncthreads();
    }
    if (blockIdx.x == 0) {
        if (tid < nb) bsums[tid] = s[tid] - v;
    } else {
        if (tid < nbuck) bbase[tid] = s[tid] - v;
        if (tid == 0) bbase[nbuck] = E;
    }
}

__global__ __launch_bounds__(256) void part2_k(const int* __restrict__ src,
                                               const int* __restrict__ dst,
                                               const int* __restrict__ offs,
                                               const int* __restrict__ bsums,
                                               unsigned* __restrict__ ebuf,
                                               int E, int nbuck, int chunk) {
    __shared__ int cur[1024];
    for (int i = threadIdx.x; i < nbuck; i += 256) {
        long flat = (long)blockIdx.x * nbuck + i;
        cur[i] = offs[flat] + bsums[flat >> 8];
    }
    __syncthreads();
    int beg = blockIdx.x * chunk;
    int end = min(E, beg + chunk);
    for (int e = beg + threadIdx.x; e < end; e += 256) {
        int d = dst[e];
        int b = d >> BSHIFT;
        int pos = atomicAdd(&cur[b], 1);
        ebuf[pos] = ((unsigned)(d & (BNODES - 1)) << 25) | (unsigned)src[e];
    }
}

__global__ __launch_bounds__(256) void finalize_k(const unsigned* __restrict__ ebuf,
                                                  const int* __restrict__ hist,
                                                  const int* __restrict__ offs,
                                                  const int* __restrict__ bsums,
                                                  const int* __restrict__ bbase,
                                                  int nbuck,
                                                  int* __restrict__ rowst,
                                                  int* __restrict__ rowend,
                                                  float* __restrict__ dinv,
                                                  int* __restrict__ col,
                                                  const float* __restrict__ x,
                                                  _Float16* __restrict__ msgX, int N) {
    __shared__ unsigned se[CAP];
    __shared__ int cj[PB], sj[PB], sb[PB];
    __shared__ int cnt_s[BNODES], scan_s[BNODES], cur_s[BNODES];
    __shared__ float di_s[BNODES];

    int b = blockIdx.x, tid = threadIdx.x;
    int node0 = b << BSHIFT;
    int nn = min(BNODES, N - node0);
    int beg = bbase[b];

    if (tid < PB) {
        long flat = (long)tid * nbuck + b;
        cj[tid] = hist[flat];
        sj[tid] = offs[flat] + bsums[flat >> 8];
    }
    if (tid < BNODES) cnt_s[tid] = 0;
    __syncthreads();

    if (tid < PB) sb[tid] = cj[tid];
    __syncthreads();
    for (int off = 1; off < PB; off <<= 1) {
        int t = 0;
        if (tid < PB && tid >= off) t = sb[tid - off];
        __syncthreads();
        if (tid < PB) sb[tid] += t;
        __syncthreads();
    }
    int m = sb[PB - 1];
    __syncthreads();

    // gather segments into LDS: 1 thread per segment (~8 edges each)
    {
        int j = tid;
        int base = sb[j] - cj[j], c = cj[j], s0 = sj[j];
        for (int k = 0; k < c; k++) {
            unsigned e = ebuf[s0 + k];
            int idx = base + k;
            if (idx < CAP) se[idx] = e;
            else atomicAdd(&cnt_s[e >> 25], 1);
        }
    }
    __syncthreads();

    int mcap = m < CAP ? m : CAP;
    for (int i = tid; i < mcap; i += 256) atomicAdd(&cnt_s[se[i] >> 25], 1);
    __syncthreads();

    int v = (tid < BNODES) ? cnt_s[tid] : 0;
    if (tid < BNODES) scan_s[tid] = v;
    __syncthreads();
    for (int off = 1; off < BNODES; off <<= 1) {
        int t = 0;
        if (tid < BNODES && tid >= off) t = scan_s[tid - off];
        __syncthreads();
        if (tid < BNODES) scan_s[tid] += t;
        __syncthreads();
    }
    if (tid < nn) {
        int ex = scan_s[tid] - v;
        int st = beg + ex;
        rowst[node0 + tid] = st;
        rowend[node0 + tid] = st + v;
        float di = rsqrtf((float)v + 1.0f);
        dinv[node0 + tid] = di;
        di_s[tid] = di;
        cur_s[tid] = ex;
    }
    __syncthreads();

    for (int i = tid; i < mcap; i += 256) {
        unsigned e = se[i];
        int p = atomicAdd(&cur_s[e >> 25], 1);
        col[beg + p] = (int)(e & 0x1FFFFFFu);
    }
    if (m > CAP) {  // overflow spill (statistically never)
        int j = tid;
        int base = sb[j] - cj[j], c = cj[j], s0 = sj[j];
        for (int k = 0; k < c; k++) {
            int idx = base + k;
            if (idx >= CAP) {
                unsigned e = ebuf[s0 + k];
                int p = atomicAdd(&cur_s[e >> 25], 1);
                col[beg + p] = (int)(e & 0x1FFFFFFu);
            }
        }
    }

    // fused msgX prep: msgX[n,64] f16 = dinv[n] * x[n,:]
    for (int t = tid; t < nn * 16; t += 256) {
        int nl = t >> 4, q = t & 15;
        int node = node0 + nl;
        float4 vx = *(const float4*)(x + (long)node * 64 + q * 4);
        float di = di_s[nl];
        vx.x *= di; vx.y *= di; vx.z *= di; vx.w *= di;
        store4h(msgX + (long)node * 64 + q * 4, vx);
    }
}

// ---- fused aggregate + MFMA GEMM (layer 1 only, K=64) ---------------------
// SMOUT: write C slice-major [NT][n][16] (for XCD-sliced consumer).
template <int K, int FOUT, bool BIAS, bool RELU, bool DINV_OUT, bool SMOUT>
__global__ __launch_bounds__(256) void fag_k(const _Float16* __restrict__ msg,
                                             const int* __restrict__ rowst,
                                             const int* __restrict__ rowend,
                                             const int* __restrict__ col,
                                             const float* __restrict__ dinv,
                                             const _Float16* __restrict__ Wsw,
                                             const float* __restrict__ bias,
                                             _Float16* __restrict__ C, int n) {
    constexpr int NT = FOUT / 16, NC = K / 32;
    constexpr int LDK = K + 8;
    constexpr int LPN = K / 8;
    constexpr int NPB = 256 / LPN;
    __shared__ _Float16 As[64 * LDK];

    int tid = threadIdx.x;
    int row0 = blockIdx.x * 64;

#pragma unroll
    for (int pass = 0; pass < 64 / NPB; pass++) {
        int nl = pass * NPB + tid / LPN;
        int q = tid % LPN;
        int node = row0 + nl;
        float acc[8];
        if (node < n) {
            load8h(msg + (long)node * K + q * 8, acc);  // self (dinv folded)
            int beg = rowst[node], end = rowend[node];
            int e = beg;
            for (; e + 4 <= end; e += 4) {
                int s0 = col[e], s1 = col[e + 1], s2 = col[e + 2], s3 = col[e + 3];
                h8 v0 = *(const h8*)(msg + (long)s0 * K + q * 8);
                h8 v1 = *(const h8*)(msg + (long)s1 * K + q * 8);
                h8 v2 = *(const h8*)(msg + (long)s2 * K + q * 8);
                h8 v3 = *(const h8*)(msg + (long)s3 * K + q * 8);
#pragma unroll
                for (int j = 0; j < 8; j++)
                    acc[j] += ((float)v0[j] + (float)v1[j]) + ((float)v2[j] + (float)v3[j]);
            }
            for (; e < end; e++) {
                int s = col[e];
                h8 v = *(const h8*)(msg + (long)s * K + q * 8);
#pragma unroll
                for (int j = 0; j < 8; j++) acc[j] += (float)v[j];
            }
            float di = dinv[node];
#pragma unroll
            for (int j = 0; j < 8; j++) acc[j] *= di;
        } else {
#pragma unroll
            for (int j = 0; j < 8; j++) acc[j] = 0.f;
        }
        h8 o;
#pragma unroll
        for (int j = 0; j < 8; j++) o[j] = (_Float16)acc[j];
        *(h8*)(As + nl * LDK + q * 8) = o;
    }
    __syncthreads();

    int lane = tid & 63, wave = tid >> 6;
    int quad = lane >> 4, cl = lane & 15;
    int r0 = wave * 16;

    h8 a[NC];
#pragma unroll
    for (int c = 0; c < NC; c++)
        a[c] = *(const h8*)(As + (r0 + cl) * LDK + quad * 8 + c * 32);

    f4 acc2[NT];
#pragma unroll
    for (int t = 0; t < NT; t++) acc2[t] = (f4){0.f, 0.f, 0.f, 0.f};

    const h8* wv = (const h8*)Wsw;
#pragma unroll
    for (int c = 0; c < NC; c++) {
#pragma unroll
        for (int t = 0; t < NT; t++)
            acc2[t] = __builtin_amdgcn_mfma_f32_16x16x32_f16(
                a[c], wv[(c * NT + t) * 64 + lane], acc2[t], 0, 0, 0);
    }

#pragma unroll
    for (int t = 0; t < NT; t++) {
        int c0 = t * 16 + cl;
        float bb = BIAS ? bias[c0] : 0.f;
#pragma unroll
        for (int r = 0; r < 4; r++) {
            int row = row0 + r0 + quad * 4 + r;
            if (row >= n) continue;
            float v = acc2[t][r] + bb;
            if (RELU) v = fmaxf(v, 0.f);
            if (DINV_OUT) v *= dinv[row];
            if (SMOUT)
                C[((long)t * n + row) * 16 + cl] = (_Float16)v;
            else
                C[(long)row * FOUT + c0] = (_Float16)v;
        }
    }
}

// ---- edge-parallel XCD-sliced aggregation, layer 2 ------------------------
// msg: [8][n][16] f16 slice-major (slice window 3.2MB fits XCD L2).
// out: [8][n][16] f16 slice-major (coalesced 256B/wave stores).
// 8 lanes/node: tid = node_local<<3 | eslot<<1 | q. 4 edge slots x 2 halves.
// slice = blockIdx%8 -> XCD pin (round-robin dispatch).
__global__ __launch_bounds__(256) void agg_ep2_k(const _Float16* __restrict__ msg,
                                                 const int* __restrict__ rowst,
                                                 const int* __restrict__ rowend,
                                                 const int* __restrict__ col,
                                                 const float* __restrict__ dinv,
                                                 _Float16* __restrict__ out, int n) {
    int slice = blockIdx.x & 7;
    int blk   = blockIdx.x >> 3;
    int tid   = threadIdx.x;
    int node  = blk * 32 + (tid >> 3);
    int eslot = (tid >> 1) & 3;
    int q     = tid & 1;
    if (node >= n) return;
    const _Float16* mp = msg + (long)slice * n * 16 + q * 8;

    float acc[8];
    if (eslot == 0) {                      // self (dinv folded upstream)
        load8h(mp + (long)node * 16, acc);
    } else {
#pragma unroll
        for (int j = 0; j < 8; j++) acc[j] = 0.f;
    }

    int beg = rowst[node], end = rowend[node];
    int e = beg + eslot;
    for (; e + 4 < end; e += 8) {          // 2 gathers in flight per lane
        int s0 = col[e], s1 = col[e + 4];
        h8 v0 = *(const h8*)(mp + (long)s0 * 16);
        h8 v1 = *(const h8*)(mp + (long)s1 * 16);
#pragma unroll
        for (int j = 0; j < 8; j++) acc[j] += (float)v0[j] + (float)v1[j];
    }
    if (e < end) {
        int s = col[e];
        h8 v = *(const h8*)(mp + (long)s * 16);
#pragma unroll
        for (int j = 0; j < 8; j++) acc[j] += (float)v[j];
    }

    // reduce across edge slots (lanes ^2, ^4 share node & q)
#pragma unroll
    for (int j = 0; j < 8; j++) {
        acc[j] += __shfl_xor(acc[j], 2);
        acc[j] += __shfl_xor(acc[j], 4);
    }

    if ((tid & 6) == 0) {                  // eslot==0 lanes (both q) write
        float di = dinv[node];
        float o[8];
#pragma unroll
        for (int j = 0; j < 8; j++) o[j] = di * acc[j];
        store8h(out + ((long)slice * n + node) * 16 + q * 8, o);
    }
}

// ---- edge-parallel XCD-sliced aggregation, layer 3 ------------------------
// msg: [8][n][8] f16 slice-major (window 1.6MB); out [n][64] f32 row-major.
// 8 lanes/node = 8 edge slots (whole 16B slice per lane).
__global__ __launch_bounds__(256) void agg_ep3_k(const _Float16* __restrict__ msg,
                                                 const int* __restrict__ rowst,
                                                 const int* __restrict__ rowend,
                                                 const int* __restrict__ col,
                                                 const float* __restrict__ dinv,
                                                 const float* __restrict__ b,
                                                 float* __restrict__ out, int n) {
    int slice = blockIdx.x & 7;
    int blk   = blockIdx.x >> 3;
    int tid   = threadIdx.x;
    int node  = blk * 32 + (tid >> 3);
    int eslot = tid & 7;
    if (node >= n) return;
    const _Float16* mp = msg + (long)slice * n * 8;

    float acc[8];
    if (eslot == 0) {                      // self (dinv folded upstream)
        load8h(mp + (long)node * 8, acc);
    } else {
#pragma unroll
        for (int j = 0; j < 8; j++) acc[j] = 0.f;
    }

    int beg = rowst[node], end = rowend[node];
    int e = beg + eslot;
    for (; e + 8 < end; e += 16) {         // 2 gathers in flight per lane
        int s0 = col[e], s1 = col[e + 8];
        h8 v0 = *(const h8*)(mp + (long)s0 * 8);
        h8 v1 = *(const h8*)(mp + (long)s1 * 8);
#pragma unroll
        for (int j = 0; j < 8; j++) acc[j] += (float)v0[j] + (float)v1[j];
    }
    if (e < end) {
        int s = col[e];
        h8 v = *(const h8*)(mp + (long)s * 8);
#pragma unroll
        for (int j = 0; j < 8; j++) acc[j] += (float)v[j];
    }

    // reduce across 8 edge slots
#pragma unroll
    for (int j = 0; j < 8; j++) {
        acc[j] += __shfl_xor(acc[j], 1);
        acc[j] += __shfl_xor(acc[j], 2);
        acc[j] += __shfl_xor(acc[j], 4);
    }

    if (eslot == 0) {
        float di = dinv[node];
        float o[8];
#pragma unroll
        for (int j = 0; j < 8; j++) o[j] = di * acc[j] + b[slice * 8 + j];
        float* d = out + (long)node * 64 + slice * 8;
        *(float4*)d = make_float4(o[0], o[1], o[2], o[3]);
        *(float4*)(d + 4) = make_float4(o[4], o[5], o[6], o[7]);
    }
}

// ---- weight swizzle -------------------------------------------------------
template <int K, int FOUT>
__device__ inline void wfrag(const float* __restrict__ W,
                             _Float16* __restrict__ Wsw, int t) {
    constexpr int NT = FOUT / 16;
    int lane = t & 63;
    int tile = (t >> 6) % NT;
    int chunk = (t >> 6) / NT;
    int kbase = chunk * 32 + (lane >> 4) * 8;
    int nc = tile * 16 + (lane & 15);
    h8 v;
#pragma unroll
    for (int j = 0; j < 8; j++) v[j] = (_Float16)W[(kbase + j) * FOUT + nc];
    ((h8*)Wsw)[t] = v;
}

__global__ __launch_bounds__(256) void wprep3_k(const float* __restrict__ W1,
                                                const float* __restrict__ W2,
                                                const float* __restrict__ W3,
                                                _Float16* __restrict__ w1s,
                                                _Float16* __restrict__ w2s,
                                                _Float16* __restrict__ w3s) {
    int t = blockIdx.x * 256 + threadIdx.x;
    if (t < 1024) wfrag<64, 128>(W1, w1s, t);
    else if (t < 3072) wfrag<128, 128>(W2, w2s, t - 1024);
    else if (t < 4096) wfrag<128, 64>(W3, w3s, t - 3072);
}

// ---- fused double GEMM: msg3 = dinv (.) ( relu(A@W2 + b2) @ W3 ) ----------
// 64 rows/block, 4 waves; each wave owns 16 rows end-to-end (no barrier:
// the intermediate tile rows are wave-private in LDS).
// A read SLICE-MAJOR [8][n][16]; msg3 written SLICE-MAJOR [8][n][8].
__global__ __launch_bounds__(256) void dgemm_k(const _Float16* __restrict__ A,
                                               const _Float16* __restrict__ w2s,
                                               const _Float16* __restrict__ w3s,
                                               const float* __restrict__ b2,
                                               const float* __restrict__ dinv,
                                               _Float16* __restrict__ C, int n) {
    constexpr int LDK = 136;
    __shared__ _Float16 Hs[64 * LDK];

    int tid = threadIdx.x, lane = tid & 63, wave = tid >> 6;
    int quad = lane >> 4, cl = lane & 15;
    int row0 = blockIdx.x * 64, r0 = wave * 16;
    int arow = row0 + r0 + cl;

    // GEMM-1: rows r0..r0+15, K=128 -> 128.  A[f] at [f>>4][row][f&15]:
    // f = c*32 + quad*8 -> slice = c*2 + (quad>>1), off = (quad&1)*8.
    h8 a[4];
#pragma unroll
    for (int c = 0; c < 4; c++) {
        int sl = c * 2 + (quad >> 1);
        a[c] = *(const h8*)(A + ((long)sl * n + arow) * 16 + (quad & 1) * 8);
    }

    f4 acc1[8];
#pragma unroll
    for (int t = 0; t < 8; t++) acc1[t] = (f4){0.f, 0.f, 0.f, 0.f};
    const h8* wv2 = (const h8*)w2s;
#pragma unroll
    for (int c = 0; c < 4; c++) {
#pragma unroll
        for (int t = 0; t < 8; t++)
            acc1[t] = __builtin_amdgcn_mfma_f32_16x16x32_f16(
                a[c], wv2[(c * 8 + t) * 64 + lane], acc1[t], 0, 0, 0);
    }

    // epilogue 1: +b2, relu -> wave-private LDS rows
#pragma unroll
    for (int t = 0; t < 8; t++) {
        int c0 = t * 16 + cl;
        float bb = b2[c0];
#pragma unroll
        for (int r = 0; r < 4; r++) {
            float v = fmaxf(acc1[t][r] + bb, 0.f);
            Hs[(r0 + quad * 4 + r) * LDK + c0] = (_Float16)v;
        }
    }
    __builtin_amdgcn_s_waitcnt(0);   // drain LDS writes (wave-private rows)

    // GEMM-2: K=128 -> 64
    h8 a2[4];
#pragma unroll
    for (int c = 0; c < 4; c++)
        a2[c] = *(const h8*)(Hs + (r0 + cl) * LDK + quad * 8 + c * 32);

    f4 acc2[4];
#pragma unroll
    for (int t = 0; t < 4; t++) acc2[t] = (f4){0.f, 0.f, 0.f, 0.f};
    const h8* wv3 = (const h8*)w3s;
#pragma unroll
    for (int c = 0; c < 4; c++) {
#pragma unroll
        for (int t = 0; t < 4; t++)
            acc2[t] = __builtin_amdgcn_mfma_f32_16x16x32_f16(
                a2[c], wv3[(c * 4 + t) * 64 + lane], acc2[t], 0, 0, 0);
    }

    // epilogue 2: *dinv, store msg3 slice-major [8][n][8]
#pragma unroll
    for (int t = 0; t < 4; t++) {
        int c0 = t * 16 + cl;
        int sl = c0 >> 3, sp = c0 & 7;
#pragma unroll
        for (int r = 0; r < 4; r++) {
            int row = row0 + r0 + quad * 4 + r;
            if (row >= n) continue;
            float v = acc2[t][r] * dinv[row];
            C[((long)sl * n + row) * 8 + sp] = (_Float16)v;
        }
    }
}

extern "C" void kernel_launch(void* const* d_in, const int* in_sizes, int n_in,
                              void* d_out, int out_size, void* d_ws, size_t ws_size,
                              hipStream_t stream) {
    const float* x  = (const float*)d_in[0];
    const int*   ei = (const int*)d_in[1];
    const float* W1 = (const float*)d_in[2];
    const float* b1 = (const float*)d_in[3];
    const float* W2 = (const float*)d_in[4];
    const float* b2 = (const float*)d_in[5];
    const float* W3 = (const float*)d_in[6];
    const float* b3 = (const float*)d_in[7];
    float* out = (float*)d_out;

    const int N = in_sizes[0] / 64;
    const int E = in_sizes[1] / 2;
    const int* src = ei;
    const int* dst = ei + E;
    const int nbuck = (N + BNODES - 1) >> BSHIFT;   // 782
    const int chunk = (E + PB - 1) / PB;            // 6250
    const int n2 = PB * nbuck;                      // 200192
    const int nb2 = (n2 + 255) / 256;               // 782

    // workspace carve-up (4-byte elems)
    int*   hist   = (int*)d_ws;                   // PB*nbuck
    int*   offs   = hist + n2;                    // PB*nbuck
    int*   bsums  = offs + n2;                    // 1024
    int*   bbase  = bsums + 1024;                 // nbuck+1
    int*   rowst  = bbase + nbuck + 1;            // N
    int*   rowend = rowst + N;                    // N
    float* dinv   = (float*)(rowend + N);         // N
    int*   col    = (int*)(dinv + N);             // E
    _Float16* w1s = (_Float16*)(col + E);         // 64*128 f16
    _Float16* w2s = w1s + 64 * 128;               // 128*128 f16
    _Float16* w3s = w2s + 128 * 128;              // 128*64 f16
    float* P      = (float*)(w3s + 128 * 64);     // N*128 f32 worth
    float* Q      = P + (long)N * 128;            // N*128 f32 worth

    _Float16* msgX  = (_Float16*)P;   // N x 64 f16
    unsigned* ebuf  = (unsigned*)Q;   // E x 4B (dead after finalize)
    _Float16* msg1  = (_Float16*)Q;   // [8][N][16] f16 slice-major (F1 out)
    _Float16* aggH2 = (_Float16*)P;   // [8][N][16] f16 slice-major (msgX dead)
    _Float16* msg3  = (_Float16*)Q;   // [8][N][8] f16 slice-major (msg1 dead)

    const int gb = (N + 63) / 64;

    // ---- weight swizzle ----
    wprep3_k<<<16, 256, 0, stream>>>(W1, W2, W3, w1s, w2s, w3s);

    // ---- CSR build ----
    phist_k<<<PB, 256, 0, stream>>>(dst, hist, E, nbuck, chunk);
    scan_blocks_k<<<nb2, 256, 0, stream>>>(hist, offs, bsums, n2);
    mid_k<<<2, 1024, 0, stream>>>(bsums, nb2, hist, bbase, nbuck, E);
    part2_k<<<PB, 256, 0, stream>>>(src, dst, offs, bsums, ebuf, E, nbuck, chunk);
    finalize_k<<<nbuck, 256, 0, stream>>>(ebuf, hist, offs, bsums, bbase, nbuck,
                                          rowst, rowend, dinv, col, x, msgX, N);

    // ---- layer 1 (fused agg+gemm): msgX(P) -> msg1 slice-major (Q) ----
    fag_k<64, 128, true, true, true, true><<<gb, 256, 0, stream>>>(
        msgX, rowst, rowend, col, dinv, w1s, b1, msg1, N);

    // ---- layer 2 gather (edge-parallel, XCD-sliced): msg1(Q) -> aggH2(P) ----
    const int nb32 = (N + 31) / 32;      // 3125
    agg_ep2_k<<<8 * nb32, 256, 0, stream>>>(
        msg1, rowst, rowend, col, dinv, aggH2, N);

    // ---- fused gemm2+gemm3: aggH2(P) -> msg3 slice-major (Q) ----
    dgemm_k<<<gb, 256, 0, stream>>>(aggH2, w2s, w3s, b2, dinv, msg3, N);

    // ---- layer 3 gather (edge-parallel, XCD-sliced): msg3(Q) -> out ----
    agg_ep3_k<<<8 * nb32, 256, 0, stream>>>(
        msg3, rowst, rowend, col, dinv, b3, out, N);
}

// Round 6
// 384.561 us; speedup vs baseline: 2.3746x; 1.0476x over previous
//
#include <hip/hip_runtime.h>
#include <hip/hip_bf16.h>
#include <hip/hip_fp16.h>

// ---------------------------------------------------------------------------
// GCN 3-layer forward. N=100000, E=1600000, F: 64 -> 128 -> 128 -> 64.
// R14: (a) agg_ep2 4-deep ILP (4 col + 4 gathers in flight per lane; R13's
//      2-deep was latency-chain bound: 87us, nothing saturated, FETCH 49MB
//      proves L2 residency works). (b) layer-3 path reverted to row-major
//      (dgemm stores [N][64]; R10-style agg_f16_k<64> 8-deep broadcast-col
//      gather): 128B rows = 2 full 64B lines/edge beats ep3's 16B granules.
//   CSR: phist -> scan_blocks -> mid -> part2 -> finalize
//   F1: fag<64,128>  msgX(P) -> msg1 [8][N][16] (Q)   [+b1, relu, *dinv]
//   agg_ep2: msg1(Q) -> aggH2 [8][N][16] (P)          [*dinv, f16]
//   dgemm: aggH2(P) -> msg3 [N][64] (Q)               [W2,+b2,relu | W3,*dinv]
//   agg_f16<64>: msg3(Q) -> out (+b3, f32)
// ---------------------------------------------------------------------------

typedef _Float16 h8 __attribute__((ext_vector_type(8)));
typedef float f4 __attribute__((ext_vector_type(4)));

constexpr int BSHIFT = 7;                 // 128 nodes per bucket
constexpr int BNODES = 1 << BSHIFT;
constexpr int PB     = 256;               // partition blocks
constexpr int CAP    = 4096;              // finalize LDS stage capacity

// ---- f16 helpers ----------------------------------------------------------
__device__ inline void load8h(const _Float16* p, float* f) {
    h8 v = *(const h8*)p;
#pragma unroll
    for (int j = 0; j < 8; j++) f[j] = (float)v[j];
}

__device__ inline void store8h(_Float16* p, const float* f) {
    h8 v;
#pragma unroll
    for (int j = 0; j < 8; j++) v[j] = (_Float16)f[j];
    *(h8*)p = v;
}

__device__ inline void store4h(_Float16* p, float4 v) {
    _Float16 t[4] = {(_Float16)v.x, (_Float16)v.y, (_Float16)v.z, (_Float16)v.w};
    *(uint2*)p = *(uint2*)t;
}

// ---- CSR build ------------------------------------------------------------
__global__ __launch_bounds__(256) void phist_k(const int* __restrict__ dst,
                                               int* __restrict__ hist,
                                               int E, int nbuck, int chunk) {
    __shared__ int h[1024];
    for (int i = threadIdx.x; i < nbuck; i += 256) h[i] = 0;
    __syncthreads();
    int beg = blockIdx.x * chunk;
    int end = min(E, beg + chunk);
    for (int e = beg + threadIdx.x; e < end; e += 256)
        atomicAdd(&h[dst[e] >> BSHIFT], 1);
    __syncthreads();
    for (int i = threadIdx.x; i < nbuck; i += 256)
        hist[(long)blockIdx.x * nbuck + i] = h[i];
}

__global__ __launch_bounds__(256) void scan_blocks_k(const int* __restrict__ in,
                                                     int* __restrict__ excl,
                                                     int* __restrict__ bsums, int n) {
    __shared__ int s[256];
    int tid = threadIdx.x;
    int i = blockIdx.x * 256 + tid;
    int v = (i < n) ? in[i] : 0;
    s[tid] = v;
    __syncthreads();
    for (int off = 1; off < 256; off <<= 1) {
        int t = (tid >= off) ? s[tid - off] : 0;
        __syncthreads();
        s[tid] += t;
        __syncthreads();
    }
    if (i < n) excl[i] = s[tid] - v;
    if (tid == 255) bsums[blockIdx.x] = s[255];
}

// block 0: exclusive scan of bsums; block 1: column-sum hist -> scan -> bbase
__global__ __launch_bounds__(1024) void mid_k(int* __restrict__ bsums, int nb,
                                              const int* __restrict__ hist,
                                              int* __restrict__ bbase,
                                              int nbuck, int E) {
    __shared__ int s[1024];
    int tid = threadIdx.x;
    int v = 0;
    if (blockIdx.x == 0) {
        v = (tid < nb) ? bsums[tid] : 0;
    } else {
        if (tid < nbuck) {
            int t0 = 0, t1 = 0, t2 = 0, t3 = 0;
            for (int j = 0; j < PB; j += 4) {
                t0 += hist[(long)(j + 0) * nbuck + tid];
                t1 += hist[(long)(j + 1) * nbuck + tid];
                t2 += hist[(long)(j + 2) * nbuck + tid];
                t3 += hist[(long)(j + 3) * nbuck + tid];
            }
            v = (t0 + t1) + (t2 + t3);
        }
    }
    s[tid] = v;
    __syncthreads();
    for (int off = 1; off < 1024; off <<= 1) {
        int t = (tid >= off) ? s[tid - off] : 0;
        __syncthreads();
        s[tid] += t;
        __syncthreads();
    }
    if (blockIdx.x == 0) {
        if (tid < nb) bsums[tid] = s[tid] - v;
    } else {
        if (tid < nbuck) bbase[tid] = s[tid] - v;
        if (tid == 0) bbase[nbuck] = E;
    }
}

__global__ __launch_bounds__(256) void part2_k(const int* __restrict__ src,
                                               const int* __restrict__ dst,
                                               const int* __restrict__ offs,
                                               const int* __restrict__ bsums,
                                               unsigned* __restrict__ ebuf,
                                               int E, int nbuck, int chunk) {
    __shared__ int cur[1024];
    for (int i = threadIdx.x; i < nbuck; i += 256) {
        long flat = (long)blockIdx.x * nbuck + i;
        cur[i] = offs[flat] + bsums[flat >> 8];
    }
    __syncthreads();
    int beg = blockIdx.x * chunk;
    int end = min(E, beg + chunk);
    for (int e = beg + threadIdx.x; e < end; e += 256) {
        int d = dst[e];
        int b = d >> BSHIFT;
        int pos = atomicAdd(&cur[b], 1);
        ebuf[pos] = ((unsigned)(d & (BNODES - 1)) << 25) | (unsigned)src[e];
    }
}

__global__ __launch_bounds__(256) void finalize_k(const unsigned* __restrict__ ebuf,
                                                  const int* __restrict__ hist,
                                                  const int* __restrict__ offs,
                                                  const int* __restrict__ bsums,
                                                  const int* __restrict__ bbase,
                                                  int nbuck,
                                                  int* __restrict__ rowst,
                                                  int* __restrict__ rowend,
                                                  float* __restrict__ dinv,
                                                  int* __restrict__ col,
                                                  const float* __restrict__ x,
                                                  _Float16* __restrict__ msgX, int N) {
    __shared__ unsigned se[CAP];
    __shared__ int cj[PB], sj[PB], sb[PB];
    __shared__ int cnt_s[BNODES], scan_s[BNODES], cur_s[BNODES];
    __shared__ float di_s[BNODES];

    int b = blockIdx.x, tid = threadIdx.x;
    int node0 = b << BSHIFT;
    int nn = min(BNODES, N - node0);
    int beg = bbase[b];

    if (tid < PB) {
        long flat = (long)tid * nbuck + b;
        cj[tid] = hist[flat];
        sj[tid] = offs[flat] + bsums[flat >> 8];
    }
    if (tid < BNODES) cnt_s[tid] = 0;
    __syncthreads();

    if (tid < PB) sb[tid] = cj[tid];
    __syncthreads();
    for (int off = 1; off < PB; off <<= 1) {
        int t = 0;
        if (tid < PB && tid >= off) t = sb[tid - off];
        __syncthreads();
        if (tid < PB) sb[tid] += t;
        __syncthreads();
    }
    int m = sb[PB - 1];
    __syncthreads();

    // gather segments into LDS: 1 thread per segment (~8 edges each)
    {
        int j = tid;
        int base = sb[j] - cj[j], c = cj[j], s0 = sj[j];
        for (int k = 0; k < c; k++) {
            unsigned e = ebuf[s0 + k];
            int idx = base + k;
            if (idx < CAP) se[idx] = e;
            else atomicAdd(&cnt_s[e >> 25], 1);
        }
    }
    __syncthreads();

    int mcap = m < CAP ? m : CAP;
    for (int i = tid; i < mcap; i += 256) atomicAdd(&cnt_s[se[i] >> 25], 1);
    __syncthreads();

    int v = (tid < BNODES) ? cnt_s[tid] : 0;
    if (tid < BNODES) scan_s[tid] = v;
    __syncthreads();
    for (int off = 1; off < BNODES; off <<= 1) {
        int t = 0;
        if (tid < BNODES && tid >= off) t = scan_s[tid - off];
        __syncthreads();
        if (tid < BNODES) scan_s[tid] += t;
        __syncthreads();
    }
    if (tid < nn) {
        int ex = scan_s[tid] - v;
        int st = beg + ex;
        rowst[node0 + tid] = st;
        rowend[node0 + tid] = st + v;
        float di = rsqrtf((float)v + 1.0f);
        dinv[node0 + tid] = di;
        di_s[tid] = di;
        cur_s[tid] = ex;
    }
    __syncthreads();

    for (int i = tid; i < mcap; i += 256) {
        unsigned e = se[i];
        int p = atomicAdd(&cur_s[e >> 25], 1);
        col[beg + p] = (int)(e & 0x1FFFFFFu);
    }
    if (m > CAP) {  // overflow spill (statistically never)
        int j = tid;
        int base = sb[j] - cj[j], c = cj[j], s0 = sj[j];
        for (int k = 0; k < c; k++) {
            int idx = base + k;
            if (idx >= CAP) {
                unsigned e = ebuf[s0 + k];
                int p = atomicAdd(&cur_s[e >> 25], 1);
                col[beg + p] = (int)(e & 0x1FFFFFFu);
            }
        }
    }

    // fused msgX prep: msgX[n,64] f16 = dinv[n] * x[n,:]
    for (int t = tid; t < nn * 16; t += 256) {
        int nl = t >> 4, q = t & 15;
        int node = node0 + nl;
        float4 vx = *(const float4*)(x + (long)node * 64 + q * 4);
        float di = di_s[nl];
        vx.x *= di; vx.y *= di; vx.z *= di; vx.w *= di;
        store4h(msgX + (long)node * 64 + q * 4, vx);
    }
}

// ---- fused aggregate + MFMA GEMM (layer 1 only, K=64) ---------------------
// SMOUT: write C slice-major [NT][n][16] (for XCD-sliced consumer).
template <int K, int FOUT, bool BIAS, bool RELU, bool DINV_OUT, bool SMOUT>
__global__ __launch_bounds__(256) void fag_k(const _Float16* __restrict__ msg,
                                             const int* __restrict__ rowst,
                                             const int* __restrict__ rowend,
                                             const int* __restrict__ col,
                                             const float* __restrict__ dinv,
                                             const _Float16* __restrict__ Wsw,
                                             const float* __restrict__ bias,
                                             _Float16* __restrict__ C, int n) {
    constexpr int NT = FOUT / 16, NC = K / 32;
    constexpr int LDK = K + 8;
    constexpr int LPN = K / 8;
    constexpr int NPB = 256 / LPN;
    __shared__ _Float16 As[64 * LDK];

    int tid = threadIdx.x;
    int row0 = blockIdx.x * 64;

#pragma unroll
    for (int pass = 0; pass < 64 / NPB; pass++) {
        int nl = pass * NPB + tid / LPN;
        int q = tid % LPN;
        int node = row0 + nl;
        float acc[8];
        if (node < n) {
            load8h(msg + (long)node * K + q * 8, acc);  // self (dinv folded)
            int beg = rowst[node], end = rowend[node];
            int e = beg;
            for (; e + 4 <= end; e += 4) {
                int s0 = col[e], s1 = col[e + 1], s2 = col[e + 2], s3 = col[e + 3];
                h8 v0 = *(const h8*)(msg + (long)s0 * K + q * 8);
                h8 v1 = *(const h8*)(msg + (long)s1 * K + q * 8);
                h8 v2 = *(const h8*)(msg + (long)s2 * K + q * 8);
                h8 v3 = *(const h8*)(msg + (long)s3 * K + q * 8);
#pragma unroll
                for (int j = 0; j < 8; j++)
                    acc[j] += ((float)v0[j] + (float)v1[j]) + ((float)v2[j] + (float)v3[j]);
            }
            for (; e < end; e++) {
                int s = col[e];
                h8 v = *(const h8*)(msg + (long)s * K + q * 8);
#pragma unroll
                for (int j = 0; j < 8; j++) acc[j] += (float)v[j];
            }
            float di = dinv[node];
#pragma unroll
            for (int j = 0; j < 8; j++) acc[j] *= di;
        } else {
#pragma unroll
            for (int j = 0; j < 8; j++) acc[j] = 0.f;
        }
        h8 o;
#pragma unroll
        for (int j = 0; j < 8; j++) o[j] = (_Float16)acc[j];
        *(h8*)(As + nl * LDK + q * 8) = o;
    }
    __syncthreads();

    int lane = tid & 63, wave = tid >> 6;
    int quad = lane >> 4, cl = lane & 15;
    int r0 = wave * 16;

    h8 a[NC];
#pragma unroll
    for (int c = 0; c < NC; c++)
        a[c] = *(const h8*)(As + (r0 + cl) * LDK + quad * 8 + c * 32);

    f4 acc2[NT];
#pragma unroll
    for (int t = 0; t < NT; t++) acc2[t] = (f4){0.f, 0.f, 0.f, 0.f};

    const h8* wv = (const h8*)Wsw;
#pragma unroll
    for (int c = 0; c < NC; c++) {
#pragma unroll
        for (int t = 0; t < NT; t++)
            acc2[t] = __builtin_amdgcn_mfma_f32_16x16x32_f16(
                a[c], wv[(c * NT + t) * 64 + lane], acc2[t], 0, 0, 0);
    }

#pragma unroll
    for (int t = 0; t < NT; t++) {
        int c0 = t * 16 + cl;
        float bb = BIAS ? bias[c0] : 0.f;
#pragma unroll
        for (int r = 0; r < 4; r++) {
            int row = row0 + r0 + quad * 4 + r;
            if (row >= n) continue;
            float v = acc2[t][r] + bb;
            if (RELU) v = fmaxf(v, 0.f);
            if (DINV_OUT) v *= dinv[row];
            if (SMOUT)
                C[((long)t * n + row) * 16 + cl] = (_Float16)v;
            else
                C[(long)row * FOUT + c0] = (_Float16)v;
        }
    }
}

// ---- edge-parallel XCD-sliced aggregation, layer 2 ------------------------
// msg: [8][n][16] f16 slice-major (slice window 3.2MB fits XCD L2).
// out: [8][n][16] f16 slice-major (coalesced 256B/wave stores).
// 8 lanes/node: tid = node_local<<3 | eslot<<1 | q. 4 edge slots x 2 halves.
// slice = blockIdx%8 -> XCD pin (round-robin dispatch). 4-deep ILP.
__global__ __launch_bounds__(256) void agg_ep2_k(const _Float16* __restrict__ msg,
                                                 const int* __restrict__ rowst,
                                                 const int* __restrict__ rowend,
                                                 const int* __restrict__ col,
                                                 const float* __restrict__ dinv,
                                                 _Float16* __restrict__ out, int n) {
    int slice = blockIdx.x & 7;
    int blk   = blockIdx.x >> 3;
    int tid   = threadIdx.x;
    int node  = blk * 32 + (tid >> 3);
    int eslot = (tid >> 1) & 3;
    int q     = tid & 1;
    if (node >= n) return;
    const _Float16* mp = msg + (long)slice * n * 16 + q * 8;

    float acc[8];
    if (eslot == 0) {                      // self (dinv folded upstream)
        load8h(mp + (long)node * 16, acc);
    } else {
#pragma unroll
        for (int j = 0; j < 8; j++) acc[j] = 0.f;
    }

    int beg = rowst[node], end = rowend[node];
    int e = beg + eslot;
    for (; e + 12 < end; e += 16) {        // 4 col + 4 gathers in flight
        int s0 = col[e], s1 = col[e + 4], s2 = col[e + 8], s3 = col[e + 12];
        h8 v0 = *(const h8*)(mp + (long)s0 * 16);
        h8 v1 = *(const h8*)(mp + (long)s1 * 16);
        h8 v2 = *(const h8*)(mp + (long)s2 * 16);
        h8 v3 = *(const h8*)(mp + (long)s3 * 16);
#pragma unroll
        for (int j = 0; j < 8; j++)
            acc[j] += (((float)v0[j] + (float)v1[j]) + ((float)v2[j] + (float)v3[j]));
    }
    for (; e < end; e += 4) {
        int s = col[e];
        h8 v = *(const h8*)(mp + (long)s * 16);
#pragma unroll
        for (int j = 0; j < 8; j++) acc[j] += (float)v[j];
    }

    // reduce across edge slots (lanes ^2, ^4 share node & q)
#pragma unroll
    for (int j = 0; j < 8; j++) {
        acc[j] += __shfl_xor(acc[j], 2);
        acc[j] += __shfl_xor(acc[j], 4);
    }

    if ((tid & 6) == 0) {                  // eslot==0 lanes (both q) write
        float di = dinv[node];
        float o[8];
#pragma unroll
        for (int j = 0; j < 8; j++) o[j] = di * acc[j];
        store8h(out + ((long)slice * n + node) * 16 + q * 8, o);
    }
}

// ---- standalone row-major aggregation (layer 3; broadcast col, 8-deep) ----
template <int F, bool BIAS, bool F16OUT>
__global__ __launch_bounds__(256) void agg_f16_k(const _Float16* __restrict__ msg,
                                                 const int* __restrict__ rowst,
                                                 const int* __restrict__ rowend,
                                                 const int* __restrict__ col,
                                                 const float* __restrict__ dinv,
                                                 const float* __restrict__ b,
                                                 void* __restrict__ out, int n) {
    constexpr int LPN = F / 8;
    constexpr int NPB = 256 / LPN;
    int node = blockIdx.x * NPB + threadIdx.x / LPN;
    int q = threadIdx.x % LPN;
    if (node >= n) return;

    float acc[8];
    load8h(msg + (long)node * F + q * 8, acc);

    int beg = rowst[node], end = rowend[node];
    int e = beg;
    for (; e + 8 <= end; e += 8) {     // 8 independent gathers in flight
        h8 v[8];
#pragma unroll
        for (int u = 0; u < 8; u++)
            v[u] = *(const h8*)(msg + (long)col[e + u] * F + q * 8);
#pragma unroll
        for (int j = 0; j < 8; j++)
            acc[j] += (((float)v[0][j] + (float)v[1][j]) + ((float)v[2][j] + (float)v[3][j])) +
                      (((float)v[4][j] + (float)v[5][j]) + ((float)v[6][j] + (float)v[7][j]));
    }
    for (; e + 4 <= end; e += 4) {
        h8 v0 = *(const h8*)(msg + (long)col[e] * F + q * 8);
        h8 v1 = *(const h8*)(msg + (long)col[e + 1] * F + q * 8);
        h8 v2 = *(const h8*)(msg + (long)col[e + 2] * F + q * 8);
        h8 v3 = *(const h8*)(msg + (long)col[e + 3] * F + q * 8);
#pragma unroll
        for (int j = 0; j < 8; j++)
            acc[j] += ((float)v0[j] + (float)v1[j]) + ((float)v2[j] + (float)v3[j]);
    }
    for (; e < end; e++) {
        h8 v = *(const h8*)(msg + (long)col[e] * F + q * 8);
#pragma unroll
        for (int j = 0; j < 8; j++) acc[j] += (float)v[j];
    }

    float di = dinv[node];
    float o[8];
#pragma unroll
    for (int j = 0; j < 8; j++) o[j] = di * acc[j];
    if (BIAS) {
#pragma unroll
        for (int j = 0; j < 8; j++) o[j] += b[q * 8 + j];
    }
    if (F16OUT) {
        store8h((_Float16*)out + (long)node * F + q * 8, o);
    } else {
        float* dst = (float*)out + (long)node * F + q * 8;
        *(float4*)dst = make_float4(o[0], o[1], o[2], o[3]);
        *(float4*)(dst + 4) = make_float4(o[4], o[5], o[6], o[7]);
    }
}

// ---- weight swizzle -------------------------------------------------------
template <int K, int FOUT>
__device__ inline void wfrag(const float* __restrict__ W,
                             _Float16* __restrict__ Wsw, int t) {
    constexpr int NT = FOUT / 16;
    int lane = t & 63;
    int tile = (t >> 6) % NT;
    int chunk = (t >> 6) / NT;
    int kbase = chunk * 32 + (lane >> 4) * 8;
    int nc = tile * 16 + (lane & 15);
    h8 v;
#pragma unroll
    for (int j = 0; j < 8; j++) v[j] = (_Float16)W[(kbase + j) * FOUT + nc];
    ((h8*)Wsw)[t] = v;
}

__global__ __launch_bounds__(256) void wprep3_k(const float* __restrict__ W1,
                                                const float* __restrict__ W2,
                                                const float* __restrict__ W3,
                                                _Float16* __restrict__ w1s,
                                                _Float16* __restrict__ w2s,
                                                _Float16* __restrict__ w3s) {
    int t = blockIdx.x * 256 + threadIdx.x;
    if (t < 1024) wfrag<64, 128>(W1, w1s, t);
    else if (t < 3072) wfrag<128, 128>(W2, w2s, t - 1024);
    else if (t < 4096) wfrag<128, 64>(W3, w3s, t - 3072);
}

// ---- fused double GEMM: msg3 = dinv (.) ( relu(A@W2 + b2) @ W3 ) ----------
// 64 rows/block, 4 waves; each wave owns 16 rows end-to-end (no barrier:
// the intermediate tile rows are wave-private in LDS).
// A read SLICE-MAJOR [8][n][16]; msg3 written ROW-MAJOR [n][64].
__global__ __launch_bounds__(256) void dgemm_k(const _Float16* __restrict__ A,
                                               const _Float16* __restrict__ w2s,
                                               const _Float16* __restrict__ w3s,
                                               const float* __restrict__ b2,
                                               const float* __restrict__ dinv,
                                               _Float16* __restrict__ C, int n) {
    constexpr int LDK = 136;
    __shared__ _Float16 Hs[64 * LDK];

    int tid = threadIdx.x, lane = tid & 63, wave = tid >> 6;
    int quad = lane >> 4, cl = lane & 15;
    int row0 = blockIdx.x * 64, r0 = wave * 16;
    int arow = row0 + r0 + cl;

    // GEMM-1: rows r0..r0+15, K=128 -> 128.  A[f] at [f>>4][row][f&15]:
    // f = c*32 + quad*8 -> slice = c*2 + (quad>>1), off = (quad&1)*8.
    h8 a[4];
#pragma unroll
    for (int c = 0; c < 4; c++) {
        int sl = c * 2 + (quad >> 1);
        a[c] = *(const h8*)(A + ((long)sl * n + arow) * 16 + (quad & 1) * 8);
    }

    f4 acc1[8];
#pragma unroll
    for (int t = 0; t < 8; t++) acc1[t] = (f4){0.f, 0.f, 0.f, 0.f};
    const h8* wv2 = (const h8*)w2s;
#pragma unroll
    for (int c = 0; c < 4; c++) {
#pragma unroll
        for (int t = 0; t < 8; t++)
            acc1[t] = __builtin_amdgcn_mfma_f32_16x16x32_f16(
                a[c], wv2[(c * 8 + t) * 64 + lane], acc1[t], 0, 0, 0);
    }

    // epilogue 1: +b2, relu -> wave-private LDS rows
#pragma unroll
    for (int t = 0; t < 8; t++) {
        int c0 = t * 16 + cl;
        float bb = b2[c0];
#pragma unroll
        for (int r = 0; r < 4; r++) {
            float v = fmaxf(acc1[t][r] + bb, 0.f);
            Hs[(r0 + quad * 4 + r) * LDK + c0] = (_Float16)v;
        }
    }
    __builtin_amdgcn_s_waitcnt(0);   // drain LDS writes (wave-private rows)

    // GEMM-2: K=128 -> 64
    h8 a2[4];
#pragma unroll
    for (int c = 0; c < 4; c++)
        a2[c] = *(const h8*)(Hs + (r0 + cl) * LDK + quad * 8 + c * 32);

    f4 acc2[4];
#pragma unroll
    for (int t = 0; t < 4; t++) acc2[t] = (f4){0.f, 0.f, 0.f, 0.f};
    const h8* wv3 = (const h8*)w3s;
#pragma unroll
    for (int c = 0; c < 4; c++) {
#pragma unroll
        for (int t = 0; t < 4; t++)
            acc2[t] = __builtin_amdgcn_mfma_f32_16x16x32_f16(
                a2[c], wv3[(c * 4 + t) * 64 + lane], acc2[t], 0, 0, 0);
    }

    // epilogue 2: *dinv, store msg3 row-major [n][64]
#pragma unroll
    for (int t = 0; t < 4; t++) {
        int c0 = t * 16 + cl;
#pragma unroll
        for (int r = 0; r < 4; r++) {
            int row = row0 + r0 + quad * 4 + r;
            if (row >= n) continue;
            float v = acc2[t][r] * dinv[row];
            C[(long)row * 64 + c0] = (_Float16)v;
        }
    }
}

extern "C" void kernel_launch(void* const* d_in, const int* in_sizes, int n_in,
                              void* d_out, int out_size, void* d_ws, size_t ws_size,
                              hipStream_t stream) {
    const float* x  = (const float*)d_in[0];
    const int*   ei = (const int*)d_in[1];
    const float* W1 = (const float*)d_in[2];
    const float* b1 = (const float*)d_in[3];
    const float* W2 = (const float*)d_in[4];
    const float* b2 = (const float*)d_in[5];
    const float* W3 = (const float*)d_in[6];
    const float* b3 = (const float*)d_in[7];
    float* out = (float*)d_out;

    const int N = in_sizes[0] / 64;
    const int E = in_sizes[1] / 2;
    const int* src = ei;
    const int* dst = ei + E;
    const int nbuck = (N + BNODES - 1) >> BSHIFT;   // 782
    const int chunk = (E + PB - 1) / PB;            // 6250
    const int n2 = PB * nbuck;                      // 200192
    const int nb2 = (n2 + 255) / 256;               // 782

    // workspace carve-up (4-byte elems)
    int*   hist   = (int*)d_ws;                   // PB*nbuck
    int*   offs   = hist + n2;                    // PB*nbuck
    int*   bsums  = offs + n2;                    // 1024
    int*   bbase  = bsums + 1024;                 // nbuck+1
    int*   rowst  = bbase + nbuck + 1;            // N
    int*   rowend = rowst + N;                    // N
    float* dinv   = (float*)(rowend + N);         // N
    int*   col    = (int*)(dinv + N);             // E
    _Float16* w1s = (_Float16*)(col + E);         // 64*128 f16
    _Float16* w2s = w1s + 64 * 128;               // 128*128 f16
    _Float16* w3s = w2s + 128 * 128;              // 128*64 f16
    float* P      = (float*)(w3s + 128 * 64);     // N*128 f32 worth
    float* Q      = P + (long)N * 128;            // N*128 f32 worth

    _Float16* msgX  = (_Float16*)P;   // N x 64 f16
    unsigned* ebuf  = (unsigned*)Q;   // E x 4B (dead after finalize)
    _Float16* msg1  = (_Float16*)Q;   // [8][N][16] f16 slice-major (F1 out)
    _Float16* aggH2 = (_Float16*)P;   // [8][N][16] f16 slice-major (msgX dead)
    _Float16* msg3  = (_Float16*)Q;   // [N][64] f16 row-major (msg1 dead)

    const int gb = (N + 63) / 64;

    // ---- weight swizzle ----
    wprep3_k<<<16, 256, 0, stream>>>(W1, W2, W3, w1s, w2s, w3s);

    // ---- CSR build ----
    phist_k<<<PB, 256, 0, stream>>>(dst, hist, E, nbuck, chunk);
    scan_blocks_k<<<nb2, 256, 0, stream>>>(hist, offs, bsums, n2);
    mid_k<<<2, 1024, 0, stream>>>(bsums, nb2, hist, bbase, nbuck, E);
    part2_k<<<PB, 256, 0, stream>>>(src, dst, offs, bsums, ebuf, E, nbuck, chunk);
    finalize_k<<<nbuck, 256, 0, stream>>>(ebuf, hist, offs, bsums, bbase, nbuck,
                                          rowst, rowend, dinv, col, x, msgX, N);

    // ---- layer 1 (fused agg+gemm): msgX(P) -> msg1 slice-major (Q) ----
    fag_k<64, 128, true, true, true, true><<<gb, 256, 0, stream>>>(
        msgX, rowst, rowend, col, dinv, w1s, b1, msg1, N);

    // ---- layer 2 gather (edge-parallel, XCD-sliced): msg1(Q) -> aggH2(P) ----
    const int nb32 = (N + 31) / 32;      // 3125
    agg_ep2_k<<<8 * nb32, 256, 0, stream>>>(
        msg1, rowst, rowend, col, dinv, aggH2, N);

    // ---- fused gemm2+gemm3: aggH2(P) -> msg3 row-major (Q) ----
    dgemm_k<<<gb, 256, 0, stream>>>(aggH2, w2s, w3s, b2, dinv, msg3, N);

    // ---- layer 3 gather (row-major, 8-deep): msg3(Q) -> out ----
    agg_f16_k<64, true, false><<<(N + 31) / 32, 256, 0, stream>>>(
        msg3, rowst, rowend, col, dinv, b3, (void*)out, N);
}

// Round 7
// 375.458 us; speedup vs baseline: 2.4322x; 1.0242x over previous
//
#include <hip/hip_runtime.h>
#include <hip/hip_bf16.h>
#include <hip/hip_fp16.h>

// ---------------------------------------------------------------------------
// GCN 3-layer forward. N=100000, E=1600000, F: 64 -> 128 -> 128 -> 64.
// R15: LDS-staged col windows in ALL gather kernels. R14 showed 4-deep ILP
//      is null (87->88us): wall is per-request cost (scalar col loads, 4
//      requests/line, L2-miss to LLC at chain head). CSR rows of consecutive
//      nodes are contiguous -> each block cooperatively stages its col window
//      (coalesced, 1 req/line) into LDS; gather loop reads col from LDS.
//      Fallback to global on (statistically never) window overflow.
//   CSR: phist -> scan_blocks -> mid -> part2 -> finalize
//   F1: fag<64,128>  msgX(P) -> msg1 [8][N][16] (Q)   [+b1, relu, *dinv]
//   agg_ep2: msg1(Q) -> aggH2 [8][N][16] (P)          [*dinv, f16]
//   dgemm: aggH2(P) -> msg3 [N][64] (Q)               [W2,+b2,relu | W3,*dinv]
//   agg_f16<64>: msg3(Q) -> out (+b3, f32)
// ---------------------------------------------------------------------------

typedef _Float16 h8 __attribute__((ext_vector_type(8)));
typedef float f4 __attribute__((ext_vector_type(4)));

constexpr int BSHIFT = 7;                 // 128 nodes per bucket
constexpr int BNODES = 1 << BSHIFT;
constexpr int PB     = 256;               // partition blocks
constexpr int CAP    = 4096;              // finalize LDS stage capacity

// ---- f16 helpers ----------------------------------------------------------
__device__ inline void load8h(const _Float16* p, float* f) {
    h8 v = *(const h8*)p;
#pragma unroll
    for (int j = 0; j < 8; j++) f[j] = (float)v[j];
}

__device__ inline void store8h(_Float16* p, const float* f) {
    h8 v;
#pragma unroll
    for (int j = 0; j < 8; j++) v[j] = (_Float16)f[j];
    *(h8*)p = v;
}

__device__ inline void store4h(_Float16* p, float4 v) {
    _Float16 t[4] = {(_Float16)v.x, (_Float16)v.y, (_Float16)v.z, (_Float16)v.w};
    *(uint2*)p = *(uint2*)t;
}

// ---- CSR build ------------------------------------------------------------
__global__ __launch_bounds__(256) void phist_k(const int* __restrict__ dst,
                                               int* __restrict__ hist,
                                               int E, int nbuck, int chunk) {
    __shared__ int h[1024];
    for (int i = threadIdx.x; i < nbuck; i += 256) h[i] = 0;
    __syncthreads();
    int beg = blockIdx.x * chunk;
    int end = min(E, beg + chunk);
    for (int e = beg + threadIdx.x; e < end; e += 256)
        atomicAdd(&h[dst[e] >> BSHIFT], 1);
    __syncthreads();
    for (int i = threadIdx.x; i < nbuck; i += 256)
        hist[(long)blockIdx.x * nbuck + i] = h[i];
}

__global__ __launch_bounds__(256) void scan_blocks_k(const int* __restrict__ in,
                                                     int* __restrict__ excl,
                                                     int* __restrict__ bsums, int n) {
    __shared__ int s[256];
    int tid = threadIdx.x;
    int i = blockIdx.x * 256 + tid;
    int v = (i < n) ? in[i] : 0;
    s[tid] = v;
    __syncthreads();
    for (int off = 1; off < 256; off <<= 1) {
        int t = (tid >= off) ? s[tid - off] : 0;
        __syncthreads();
        s[tid] += t;
        __syncthreads();
    }
    if (i < n) excl[i] = s[tid] - v;
    if (tid == 255) bsums[blockIdx.x] = s[255];
}

// block 0: exclusive scan of bsums; block 1: column-sum hist -> scan -> bbase
__global__ __launch_bounds__(1024) void mid_k(int* __restrict__ bsums, int nb,
                                              const int* __restrict__ hist,
                                              int* __restrict__ bbase,
                                              int nbuck, int E) {
    __shared__ int s[1024];
    int tid = threadIdx.x;
    int v = 0;
    if (blockIdx.x == 0) {
        v = (tid < nb) ? bsums[tid] : 0;
    } else {
        if (tid < nbuck) {
            int t0 = 0, t1 = 0, t2 = 0, t3 = 0;
            for (int j = 0; j < PB; j += 4) {
                t0 += hist[(long)(j + 0) * nbuck + tid];
                t1 += hist[(long)(j + 1) * nbuck + tid];
                t2 += hist[(long)(j + 2) * nbuck + tid];
                t3 += hist[(long)(j + 3) * nbuck + tid];
            }
            v = (t0 + t1) + (t2 + t3);
        }
    }
    s[tid] = v;
    __syncthreads();
    for (int off = 1; off < 1024; off <<= 1) {
        int t = (tid >= off) ? s[tid - off] : 0;
        __syncthreads();
        s[tid] += t;
        __syncthreads();
    }
    if (blockIdx.x == 0) {
        if (tid < nb) bsums[tid] = s[tid] - v;
    } else {
        if (tid < nbuck) bbase[tid] = s[tid] - v;
        if (tid == 0) bbase[nbuck] = E;
    }
}

__global__ __launch_bounds__(256) void part2_k(const int* __restrict__ src,
                                               const int* __restrict__ dst,
                                               const int* __restrict__ offs,
                                               const int* __restrict__ bsums,
                                               unsigned* __restrict__ ebuf,
                                               int E, int nbuck, int chunk) {
    __shared__ int cur[1024];
    for (int i = threadIdx.x; i < nbuck; i += 256) {
        long flat = (long)blockIdx.x * nbuck + i;
        cur[i] = offs[flat] + bsums[flat >> 8];
    }
    __syncthreads();
    int beg = blockIdx.x * chunk;
    int end = min(E, beg + chunk);
    for (int e = beg + threadIdx.x; e < end; e += 256) {
        int d = dst[e];
        int b = d >> BSHIFT;
        int pos = atomicAdd(&cur[b], 1);
        ebuf[pos] = ((unsigned)(d & (BNODES - 1)) << 25) | (unsigned)src[e];
    }
}

__global__ __launch_bounds__(256) void finalize_k(const unsigned* __restrict__ ebuf,
                                                  const int* __restrict__ hist,
                                                  const int* __restrict__ offs,
                                                  const int* __restrict__ bsums,
                                                  const int* __restrict__ bbase,
                                                  int nbuck,
                                                  int* __restrict__ rowst,
                                                  int* __restrict__ rowend,
                                                  float* __restrict__ dinv,
                                                  int* __restrict__ col,
                                                  const float* __restrict__ x,
                                                  _Float16* __restrict__ msgX, int N) {
    __shared__ unsigned se[CAP];
    __shared__ int cj[PB], sj[PB], sb[PB];
    __shared__ int cnt_s[BNODES], scan_s[BNODES], cur_s[BNODES];
    __shared__ float di_s[BNODES];

    int b = blockIdx.x, tid = threadIdx.x;
    int node0 = b << BSHIFT;
    int nn = min(BNODES, N - node0);
    int beg = bbase[b];

    if (tid < PB) {
        long flat = (long)tid * nbuck + b;
        cj[tid] = hist[flat];
        sj[tid] = offs[flat] + bsums[flat >> 8];
    }
    if (tid < BNODES) cnt_s[tid] = 0;
    __syncthreads();

    if (tid < PB) sb[tid] = cj[tid];
    __syncthreads();
    for (int off = 1; off < PB; off <<= 1) {
        int t = 0;
        if (tid < PB && tid >= off) t = sb[tid - off];
        __syncthreads();
        if (tid < PB) sb[tid] += t;
        __syncthreads();
    }
    int m = sb[PB - 1];
    __syncthreads();

    // gather segments into LDS: 1 thread per segment (~8 edges each)
    {
        int j = tid;
        int base = sb[j] - cj[j], c = cj[j], s0 = sj[j];
        for (int k = 0; k < c; k++) {
            unsigned e = ebuf[s0 + k];
            int idx = base + k;
            if (idx < CAP) se[idx] = e;
            else atomicAdd(&cnt_s[e >> 25], 1);
        }
    }
    __syncthreads();

    int mcap = m < CAP ? m : CAP;
    for (int i = tid; i < mcap; i += 256) atomicAdd(&cnt_s[se[i] >> 25], 1);
    __syncthreads();

    int v = (tid < BNODES) ? cnt_s[tid] : 0;
    if (tid < BNODES) scan_s[tid] = v;
    __syncthreads();
    for (int off = 1; off < BNODES; off <<= 1) {
        int t = 0;
        if (tid < BNODES && tid >= off) t = scan_s[tid - off];
        __syncthreads();
        if (tid < BNODES) scan_s[tid] += t;
        __syncthreads();
    }
    if (tid < nn) {
        int ex = scan_s[tid] - v;
        int st = beg + ex;
        rowst[node0 + tid] = st;
        rowend[node0 + tid] = st + v;
        float di = rsqrtf((float)v + 1.0f);
        dinv[node0 + tid] = di;
        di_s[tid] = di;
        cur_s[tid] = ex;
    }
    __syncthreads();

    for (int i = tid; i < mcap; i += 256) {
        unsigned e = se[i];
        int p = atomicAdd(&cur_s[e >> 25], 1);
        col[beg + p] = (int)(e & 0x1FFFFFFu);
    }
    if (m > CAP) {  // overflow spill (statistically never)
        int j = tid;
        int base = sb[j] - cj[j], c = cj[j], s0 = sj[j];
        for (int k = 0; k < c; k++) {
            int idx = base + k;
            if (idx >= CAP) {
                unsigned e = ebuf[s0 + k];
                int p = atomicAdd(&cur_s[e >> 25], 1);
                col[beg + p] = (int)(e & 0x1FFFFFFu);
            }
        }
    }

    // fused msgX prep: msgX[n,64] f16 = dinv[n] * x[n,:]
    for (int t = tid; t < nn * 16; t += 256) {
        int nl = t >> 4, q = t & 15;
        int node = node0 + nl;
        float4 vx = *(const float4*)(x + (long)node * 64 + q * 4);
        float di = di_s[nl];
        vx.x *= di; vx.y *= di; vx.z *= di; vx.w *= di;
        store4h(msgX + (long)node * 64 + q * 4, vx);
    }
}

// ---- fused aggregate + MFMA GEMM (layer 1 only, K=64) ---------------------
// SMOUT: write C slice-major [NT][n][16] (for XCD-sliced consumer).
// Col window of the block's 64 nodes staged in LDS (contiguous CSR ranges).
template <int K, int FOUT, bool BIAS, bool RELU, bool DINV_OUT, bool SMOUT>
__global__ __launch_bounds__(256) void fag_k(const _Float16* __restrict__ msg,
                                             const int* __restrict__ rowst,
                                             const int* __restrict__ rowend,
                                             const int* __restrict__ col,
                                             const float* __restrict__ dinv,
                                             const _Float16* __restrict__ Wsw,
                                             const float* __restrict__ bias,
                                             _Float16* __restrict__ C, int n) {
    constexpr int NT = FOUT / 16, NC = K / 32;
    constexpr int LDK = K + 8;
    constexpr int LPN = K / 8;
    constexpr int NPB = 256 / LPN;
    constexpr int CC = 2560;               // col window cap (mean ~1107)
    __shared__ _Float16 As[64 * LDK];
    __shared__ int cls[CC];

    int tid = threadIdx.x;
    int row0 = blockIdx.x * 64;

    // stage col window (coalesced bulk load; windows of consecutive nodes
    // are contiguous by CSR construction)
    int lastn = min(row0 + 64, n) - 1;
    int beg0 = rowst[row0];
    int win  = rowend[lastn] - beg0;
    int wl = min(win, CC);
    for (int i = tid; i < wl; i += 256) cls[i] = col[beg0 + i];
    __syncthreads();
    const int* cb = (win <= CC) ? (const int*)cls : (col + beg0);

#pragma unroll
    for (int pass = 0; pass < 64 / NPB; pass++) {
        int nl = pass * NPB + tid / LPN;
        int q = tid % LPN;
        int node = row0 + nl;
        float acc[8];
        if (node < n) {
            load8h(msg + (long)node * K + q * 8, acc);  // self (dinv folded)
            int beg = rowst[node] - beg0, end = rowend[node] - beg0;
            int e = beg;
            for (; e + 4 <= end; e += 4) {
                int s0 = cb[e], s1 = cb[e + 1], s2 = cb[e + 2], s3 = cb[e + 3];
                h8 v0 = *(const h8*)(msg + (long)s0 * K + q * 8);
                h8 v1 = *(const h8*)(msg + (long)s1 * K + q * 8);
                h8 v2 = *(const h8*)(msg + (long)s2 * K + q * 8);
                h8 v3 = *(const h8*)(msg + (long)s3 * K + q * 8);
#pragma unroll
                for (int j = 0; j < 8; j++)
                    acc[j] += ((float)v0[j] + (float)v1[j]) + ((float)v2[j] + (float)v3[j]);
            }
            for (; e < end; e++) {
                int s = cb[e];
                h8 v = *(const h8*)(msg + (long)s * K + q * 8);
#pragma unroll
                for (int j = 0; j < 8; j++) acc[j] += (float)v[j];
            }
            float di = dinv[node];
#pragma unroll
            for (int j = 0; j < 8; j++) acc[j] *= di;
        } else {
#pragma unroll
            for (int j = 0; j < 8; j++) acc[j] = 0.f;
        }
        h8 o;
#pragma unroll
        for (int j = 0; j < 8; j++) o[j] = (_Float16)acc[j];
        *(h8*)(As + nl * LDK + q * 8) = o;
    }
    __syncthreads();

    int lane = tid & 63, wave = tid >> 6;
    int quad = lane >> 4, cl = lane & 15;
    int r0 = wave * 16;

    h8 a[NC];
#pragma unroll
    for (int c = 0; c < NC; c++)
        a[c] = *(const h8*)(As + (r0 + cl) * LDK + quad * 8 + c * 32);

    f4 acc2[NT];
#pragma unroll
    for (int t = 0; t < NT; t++) acc2[t] = (f4){0.f, 0.f, 0.f, 0.f};

    const h8* wv = (const h8*)Wsw;
#pragma unroll
    for (int c = 0; c < NC; c++) {
#pragma unroll
        for (int t = 0; t < NT; t++)
            acc2[t] = __builtin_amdgcn_mfma_f32_16x16x32_f16(
                a[c], wv[(c * NT + t) * 64 + lane], acc2[t], 0, 0, 0);
    }

#pragma unroll
    for (int t = 0; t < NT; t++) {
        int c0 = t * 16 + cl;
        float bb = BIAS ? bias[c0] : 0.f;
#pragma unroll
        for (int r = 0; r < 4; r++) {
            int row = row0 + r0 + quad * 4 + r;
            if (row >= n) continue;
            float v = acc2[t][r] + bb;
            if (RELU) v = fmaxf(v, 0.f);
            if (DINV_OUT) v *= dinv[row];
            if (SMOUT)
                C[((long)t * n + row) * 16 + cl] = (_Float16)v;
            else
                C[(long)row * FOUT + c0] = (_Float16)v;
        }
    }
}

// ---- edge-parallel XCD-sliced aggregation, layer 2 ------------------------
// msg: [8][n][16] f16 slice-major (slice window 3.2MB fits XCD L2).
// out: [8][n][16] f16 slice-major.  slice = blockIdx%8 -> XCD pin.
// 8 lanes/node (4 edge slots x 2 halves); col window staged in LDS.
__global__ __launch_bounds__(256) void agg_ep2_k(const _Float16* __restrict__ msg,
                                                 const int* __restrict__ rowst,
                                                 const int* __restrict__ rowend,
                                                 const int* __restrict__ col,
                                                 const float* __restrict__ dinv,
                                                 _Float16* __restrict__ out, int n) {
    constexpr int CC = 1536;               // col window cap (mean ~553)
    __shared__ int cls[CC];
    int slice = blockIdx.x & 7;
    int blk   = blockIdx.x >> 3;
    int tid   = threadIdx.x;
    int node0b = blk * 32;

    int lastn = min(node0b + 32, n) - 1;
    int beg0 = rowst[node0b];
    int win  = rowend[lastn] - beg0;
    int wl = min(win, CC);
    for (int i = tid; i < wl; i += 256) cls[i] = col[beg0 + i];
    __syncthreads();
    const int* cb = (win <= CC) ? (const int*)cls : (col + beg0);

    int node  = node0b + (tid >> 3);
    int eslot = (tid >> 1) & 3;
    int q     = tid & 1;
    if (node >= n) return;
    const _Float16* mp = msg + (long)slice * n * 16 + q * 8;

    float acc[8];
    if (eslot == 0) {                      // self (dinv folded upstream)
        load8h(mp + (long)node * 16, acc);
    } else {
#pragma unroll
        for (int j = 0; j < 8; j++) acc[j] = 0.f;
    }

    int beg = rowst[node] - beg0, end = rowend[node] - beg0;
    int e = beg + eslot;
    for (; e + 12 < end; e += 16) {        // 4 col + 4 gathers in flight
        int s0 = cb[e], s1 = cb[e + 4], s2 = cb[e + 8], s3 = cb[e + 12];
        h8 v0 = *(const h8*)(mp + (long)s0 * 16);
        h8 v1 = *(const h8*)(mp + (long)s1 * 16);
        h8 v2 = *(const h8*)(mp + (long)s2 * 16);
        h8 v3 = *(const h8*)(mp + (long)s3 * 16);
#pragma unroll
        for (int j = 0; j < 8; j++)
            acc[j] += (((float)v0[j] + (float)v1[j]) + ((float)v2[j] + (float)v3[j]));
    }
    for (; e < end; e += 4) {
        int s = cb[e];
        h8 v = *(const h8*)(mp + (long)s * 16);
#pragma unroll
        for (int j = 0; j < 8; j++) acc[j] += (float)v[j];
    }

    // reduce across edge slots (lanes ^2, ^4 share node & q)
#pragma unroll
    for (int j = 0; j < 8; j++) {
        acc[j] += __shfl_xor(acc[j], 2);
        acc[j] += __shfl_xor(acc[j], 4);
    }

    if ((tid & 6) == 0) {                  // eslot==0 lanes (both q) write
        float di = dinv[node];
        float o[8];
#pragma unroll
        for (int j = 0; j < 8; j++) o[j] = di * acc[j];
        store8h(out + ((long)slice * n + node) * 16 + q * 8, o);
    }
}

// ---- standalone row-major aggregation (layer 3; LDS col, 8-deep) ----------
template <int F, bool BIAS, bool F16OUT>
__global__ __launch_bounds__(256) void agg_f16_k(const _Float16* __restrict__ msg,
                                                 const int* __restrict__ rowst,
                                                 const int* __restrict__ rowend,
                                                 const int* __restrict__ col,
                                                 const float* __restrict__ dinv,
                                                 const float* __restrict__ b,
                                                 void* __restrict__ out, int n) {
    constexpr int LPN = F / 8;
    constexpr int NPB = 256 / LPN;
    constexpr int CC = NPB * 48;           // 1536 for NPB=32
    __shared__ int cls[CC];
    int tid = threadIdx.x;
    int node0b = blockIdx.x * NPB;

    int lastn = min(node0b + NPB, n) - 1;
    int beg0 = rowst[node0b];
    int win  = rowend[lastn] - beg0;
    int wl = min(win, CC);
    for (int i = tid; i < wl; i += 256) cls[i] = col[beg0 + i];
    __syncthreads();
    const int* cb = (win <= CC) ? (const int*)cls : (col + beg0);

    int node = node0b + tid / LPN;
    int q = tid % LPN;
    if (node >= n) return;

    float acc[8];
    load8h(msg + (long)node * F + q * 8, acc);

    int beg = rowst[node] - beg0, end = rowend[node] - beg0;
    int e = beg;
    for (; e + 8 <= end; e += 8) {     // 8 independent gathers in flight
        h8 v[8];
#pragma unroll
        for (int u = 0; u < 8; u++)
            v[u] = *(const h8*)(msg + (long)cb[e + u] * F + q * 8);
#pragma unroll
        for (int j = 0; j < 8; j++)
            acc[j] += (((float)v[0][j] + (float)v[1][j]) + ((float)v[2][j] + (float)v[3][j])) +
                      (((float)v[4][j] + (float)v[5][j]) + ((float)v[6][j] + (float)v[7][j]));
    }
    for (; e + 4 <= end; e += 4) {
        h8 v0 = *(const h8*)(msg + (long)cb[e] * F + q * 8);
        h8 v1 = *(const h8*)(msg + (long)cb[e + 1] * F + q * 8);
        h8 v2 = *(const h8*)(msg + (long)cb[e + 2] * F + q * 8);
        h8 v3 = *(const h8*)(msg + (long)cb[e + 3] * F + q * 8);
#pragma unroll
        for (int j = 0; j < 8; j++)
            acc[j] += ((float)v0[j] + (float)v1[j]) + ((float)v2[j] + (float)v3[j]);
    }
    for (; e < end; e++) {
        h8 v = *(const h8*)(msg + (long)cb[e] * F + q * 8);
#pragma unroll
        for (int j = 0; j < 8; j++) acc[j] += (float)v[j];
    }

    float di = dinv[node];
    float o[8];
#pragma unroll
    for (int j = 0; j < 8; j++) o[j] = di * acc[j];
    if (BIAS) {
#pragma unroll
        for (int j = 0; j < 8; j++) o[j] += b[q * 8 + j];
    }
    if (F16OUT) {
        store8h((_Float16*)out + (long)node * F + q * 8, o);
    } else {
        float* dst = (float*)out + (long)node * F + q * 8;
        *(float4*)dst = make_float4(o[0], o[1], o[2], o[3]);
        *(float4*)(dst + 4) = make_float4(o[4], o[5], o[6], o[7]);
    }
}

// ---- weight swizzle -------------------------------------------------------
template <int K, int FOUT>
__device__ inline void wfrag(const float* __restrict__ W,
                             _Float16* __restrict__ Wsw, int t) {
    constexpr int NT = FOUT / 16;
    int lane = t & 63;
    int tile = (t >> 6) % NT;
    int chunk = (t >> 6) / NT;
    int kbase = chunk * 32 + (lane >> 4) * 8;
    int nc = tile * 16 + (lane & 15);
    h8 v;
#pragma unroll
    for (int j = 0; j < 8; j++) v[j] = (_Float16)W[(kbase + j) * FOUT + nc];
    ((h8*)Wsw)[t] = v;
}

__global__ __launch_bounds__(256) void wprep3_k(const float* __restrict__ W1,
                                                const float* __restrict__ W2,
                                                const float* __restrict__ W3,
                                                _Float16* __restrict__ w1s,
                                                _Float16* __restrict__ w2s,
                                                _Float16* __restrict__ w3s) {
    int t = blockIdx.x * 256 + threadIdx.x;
    if (t < 1024) wfrag<64, 128>(W1, w1s, t);
    else if (t < 3072) wfrag<128, 128>(W2, w2s, t - 1024);
    else if (t < 4096) wfrag<128, 64>(W3, w3s, t - 3072);
}

// ---- fused double GEMM: msg3 = dinv (.) ( relu(A@W2 + b2) @ W3 ) ----------
// 64 rows/block, 4 waves; each wave owns 16 rows end-to-end (no barrier:
// the intermediate tile rows are wave-private in LDS).
// A read SLICE-MAJOR [8][n][16]; msg3 written ROW-MAJOR [n][64].
__global__ __launch_bounds__(256) void dgemm_k(const _Float16* __restrict__ A,
                                               const _Float16* __restrict__ w2s,
                                               const _Float16* __restrict__ w3s,
                                               const float* __restrict__ b2,
                                               const float* __restrict__ dinv,
                                               _Float16* __restrict__ C, int n) {
    constexpr int LDK = 136;
    __shared__ _Float16 Hs[64 * LDK];

    int tid = threadIdx.x, lane = tid & 63, wave = tid >> 6;
    int quad = lane >> 4, cl = lane & 15;
    int row0 = blockIdx.x * 64, r0 = wave * 16;
    int arow = row0 + r0 + cl;

    // GEMM-1: rows r0..r0+15, K=128 -> 128.  A[f] at [f>>4][row][f&15]:
    // f = c*32 + quad*8 -> slice = c*2 + (quad>>1), off = (quad&1)*8.
    h8 a[4];
#pragma unroll
    for (int c = 0; c < 4; c++) {
        int sl = c * 2 + (quad >> 1);
        a[c] = *(const h8*)(A + ((long)sl * n + arow) * 16 + (quad & 1) * 8);
    }

    f4 acc1[8];
#pragma unroll
    for (int t = 0; t < 8; t++) acc1[t] = (f4){0.f, 0.f, 0.f, 0.f};
    const h8* wv2 = (const h8*)w2s;
#pragma unroll
    for (int c = 0; c < 4; c++) {
#pragma unroll
        for (int t = 0; t < 8; t++)
            acc1[t] = __builtin_amdgcn_mfma_f32_16x16x32_f16(
                a[c], wv2[(c * 8 + t) * 64 + lane], acc1[t], 0, 0, 0);
    }

    // epilogue 1: +b2, relu -> wave-private LDS rows
#pragma unroll
    for (int t = 0; t < 8; t++) {
        int c0 = t * 16 + cl;
        float bb = b2[c0];
#pragma unroll
        for (int r = 0; r < 4; r++) {
            float v = fmaxf(acc1[t][r] + bb, 0.f);
            Hs[(r0 + quad * 4 + r) * LDK + c0] = (_Float16)v;
        }
    }
    __builtin_amdgcn_s_waitcnt(0);   // drain LDS writes (wave-private rows)

    // GEMM-2: K=128 -> 64
    h8 a2[4];
#pragma unroll
    for (int c = 0; c < 4; c++)
        a2[c] = *(const h8*)(Hs + (r0 + cl) * LDK + quad * 8 + c * 32);

    f4 acc2[4];
#pragma unroll
    for (int t = 0; t < 4; t++) acc2[t] = (f4){0.f, 0.f, 0.f, 0.f};
    const h8* wv3 = (const h8*)w3s;
#pragma unroll
    for (int c = 0; c < 4; c++) {
#pragma unroll
        for (int t = 0; t < 4; t++)
            acc2[t] = __builtin_amdgcn_mfma_f32_16x16x32_f16(
                a2[c], wv3[(c * 4 + t) * 64 + lane], acc2[t], 0, 0, 0);
    }

    // epilogue 2: *dinv, store msg3 row-major [n][64]
#pragma unroll
    for (int t = 0; t < 4; t++) {
        int c0 = t * 16 + cl;
#pragma unroll
        for (int r = 0; r < 4; r++) {
            int row = row0 + r0 + quad * 4 + r;
            if (row >= n) continue;
            float v = acc2[t][r] * dinv[row];
            C[(long)row * 64 + c0] = (_Float16)v;
        }
    }
}

extern "C" void kernel_launch(void* const* d_in, const int* in_sizes, int n_in,
                              void* d_out, int out_size, void* d_ws, size_t ws_size,
                              hipStream_t stream) {
    const float* x  = (const float*)d_in[0];
    const int*   ei = (const int*)d_in[1];
    const float* W1 = (const float*)d_in[2];
    const float* b1 = (const float*)d_in[3];
    const float* W2 = (const float*)d_in[4];
    const float* b2 = (const float*)d_in[5];
    const float* W3 = (const float*)d_in[6];
    const float* b3 = (const float*)d_in[7];
    float* out = (float*)d_out;

    const int N = in_sizes[0] / 64;
    const int E = in_sizes[1] / 2;
    const int* src = ei;
    const int* dst = ei + E;
    const int nbuck = (N + BNODES - 1) >> BSHIFT;   // 782
    const int chunk = (E + PB - 1) / PB;            // 6250
    const int n2 = PB * nbuck;                      // 200192
    const int nb2 = (n2 + 255) / 256;               // 782

    // workspace carve-up (4-byte elems)
    int*   hist   = (int*)d_ws;                   // PB*nbuck
    int*   offs   = hist + n2;                    // PB*nbuck
    int*   bsums  = offs + n2;                    // 1024
    int*   bbase  = bsums + 1024;                 // nbuck+1
    int*   rowst  = bbase + nbuck + 1;            // N
    int*   rowend = rowst + N;                    // N
    float* dinv   = (float*)(rowend + N);         // N
    int*   col    = (int*)(dinv + N);             // E
    _Float16* w1s = (_Float16*)(col + E);         // 64*128 f16
    _Float16* w2s = w1s + 64 * 128;               // 128*128 f16
    _Float16* w3s = w2s + 128 * 128;              // 128*64 f16
    float* P      = (float*)(w3s + 128 * 64);     // N*128 f32 worth
    float* Q      = P + (long)N * 128;            // N*128 f32 worth

    _Float16* msgX  = (_Float16*)P;   // N x 64 f16
    unsigned* ebuf  = (unsigned*)Q;   // E x 4B (dead after finalize)
    _Float16* msg1  = (_Float16*)Q;   // [8][N][16] f16 slice-major (F1 out)
    _Float16* aggH2 = (_Float16*)P;   // [8][N][16] f16 slice-major (msgX dead)
    _Float16* msg3  = (_Float16*)Q;   // [N][64] f16 row-major (msg1 dead)

    const int gb = (N + 63) / 64;

    // ---- weight swizzle ----
    wprep3_k<<<16, 256, 0, stream>>>(W1, W2, W3, w1s, w2s, w3s);

    // ---- CSR build ----
    phist_k<<<PB, 256, 0, stream>>>(dst, hist, E, nbuck, chunk);
    scan_blocks_k<<<nb2, 256, 0, stream>>>(hist, offs, bsums, n2);
    mid_k<<<2, 1024, 0, stream>>>(bsums, nb2, hist, bbase, nbuck, E);
    part2_k<<<PB, 256, 0, stream>>>(src, dst, offs, bsums, ebuf, E, nbuck, chunk);
    finalize_k<<<nbuck, 256, 0, stream>>>(ebuf, hist, offs, bsums, bbase, nbuck,
                                          rowst, rowend, dinv, col, x, msgX, N);

    // ---- layer 1 (fused agg+gemm): msgX(P) -> msg1 slice-major (Q) ----
    fag_k<64, 128, true, true, true, true><<<gb, 256, 0, stream>>>(
        msgX, rowst, rowend, col, dinv, w1s, b1, msg1, N);

    // ---- layer 2 gather (edge-parallel, XCD-sliced, LDS col): msg1 -> aggH2 ----
    const int nb32 = (N + 31) / 32;      // 3125
    agg_ep2_k<<<8 * nb32, 256, 0, stream>>>(
        msg1, rowst, rowend, col, dinv, aggH2, N);

    // ---- fused gemm2+gemm3: aggH2(P) -> msg3 row-major (Q) ----
    dgemm_k<<<gb, 256, 0, stream>>>(aggH2, w2s, w3s, b2, dinv, msg3, N);

    // ---- layer 3 gather (row-major, LDS col, 8-deep): msg3(Q) -> out ----
    agg_f16_k<64, true, false><<<(N + 31) / 32, 256, 0, stream>>>(
        msg3, rowst, rowend, col, dinv, b3, (void*)out, N);
}

// Round 8
// 363.977 us; speedup vs baseline: 2.5089x; 1.0315x over previous
//
#include <hip/hip_runtime.h>
#include <hip/hip_bf16.h>
#include <hip/hip_fp16.h>

// ---------------------------------------------------------------------------
// GCN 3-layer forward. N=100000, E=1600000, F: 64 -> 128 -> 128 -> 64.
// R16: layer-2 gather = 64B-granule, src-half partitioned, XCD-pinned.
//      R15 proved layer-2 is L2-REQUEST-bound (~25.6M 16B requests = 83us);
//      64B slices (32 feats) coalesce 4 lanes -> 1 req/edge-slice (6.4M),
//      and src-half partitioning (8 XCDs = 4 slices x 2 halves) keeps the
//      per-XCD window at (N/2)*64B = 3.2MB < 4MB L2. Partials [2][4][N][32];
//      combine (pA+pB+self)*dinv folded into dgemm A-load. CSR rows gain a
//      src-half partition point midp[] (built in finalize).
//   CSR: phist -> scan_blocks -> mid -> part2 -> finalize(+midp)
//   F1: fag<64,128>  msgX(P) -> msg1 [4][N][32] (Q)   [+b1, relu, *dinv]
//   agg_h2 x(slice,half): msg1(Q) -> part [2][4][N][32] (P)
//   dgemm: (part,msg1,dinv) -> msg3 [N][64] (Q)       [W2,+b2,relu | W3,*dinv]
//   agg_f16<64>: msg3(Q) -> out (+b3, f32)
// ---------------------------------------------------------------------------

typedef _Float16 h8 __attribute__((ext_vector_type(8)));
typedef float f4 __attribute__((ext_vector_type(4)));

constexpr int BSHIFT = 7;                 // 128 nodes per bucket
constexpr int BNODES = 1 << BSHIFT;
constexpr int PB     = 256;               // partition blocks
constexpr int CAP    = 4096;              // finalize LDS stage capacity

// ---- f16 helpers ----------------------------------------------------------
__device__ inline void load8h(const _Float16* p, float* f) {
    h8 v = *(const h8*)p;
#pragma unroll
    for (int j = 0; j < 8; j++) f[j] = (float)v[j];
}

__device__ inline void store8h(_Float16* p, const float* f) {
    h8 v;
#pragma unroll
    for (int j = 0; j < 8; j++) v[j] = (_Float16)f[j];
    *(h8*)p = v;
}

__device__ inline void store4h(_Float16* p, float4 v) {
    _Float16 t[4] = {(_Float16)v.x, (_Float16)v.y, (_Float16)v.z, (_Float16)v.w};
    *(uint2*)p = *(uint2*)t;
}

// ---- CSR build ------------------------------------------------------------
__global__ __launch_bounds__(256) void phist_k(const int* __restrict__ dst,
                                               int* __restrict__ hist,
                                               int E, int nbuck, int chunk) {
    __shared__ int h[1024];
    for (int i = threadIdx.x; i < nbuck; i += 256) h[i] = 0;
    __syncthreads();
    int beg = blockIdx.x * chunk;
    int end = min(E, beg + chunk);
    for (int e = beg + threadIdx.x; e < end; e += 256)
        atomicAdd(&h[dst[e] >> BSHIFT], 1);
    __syncthreads();
    for (int i = threadIdx.x; i < nbuck; i += 256)
        hist[(long)blockIdx.x * nbuck + i] = h[i];
}

__global__ __launch_bounds__(256) void scan_blocks_k(const int* __restrict__ in,
                                                     int* __restrict__ excl,
                                                     int* __restrict__ bsums, int n) {
    __shared__ int s[256];
    int tid = threadIdx.x;
    int i = blockIdx.x * 256 + tid;
    int v = (i < n) ? in[i] : 0;
    s[tid] = v;
    __syncthreads();
    for (int off = 1; off < 256; off <<= 1) {
        int t = (tid >= off) ? s[tid - off] : 0;
        __syncthreads();
        s[tid] += t;
        __syncthreads();
    }
    if (i < n) excl[i] = s[tid] - v;
    if (tid == 255) bsums[blockIdx.x] = s[255];
}

// block 0: exclusive scan of bsums; block 1: column-sum hist -> scan -> bbase
__global__ __launch_bounds__(1024) void mid_k(int* __restrict__ bsums, int nb,
                                              const int* __restrict__ hist,
                                              int* __restrict__ bbase,
                                              int nbuck, int E) {
    __shared__ int s[1024];
    int tid = threadIdx.x;
    int v = 0;
    if (blockIdx.x == 0) {
        v = (tid < nb) ? bsums[tid] : 0;
    } else {
        if (tid < nbuck) {
            int t0 = 0, t1 = 0, t2 = 0, t3 = 0;
            for (int j = 0; j < PB; j += 4) {
                t0 += hist[(long)(j + 0) * nbuck + tid];
                t1 += hist[(long)(j + 1) * nbuck + tid];
                t2 += hist[(long)(j + 2) * nbuck + tid];
                t3 += hist[(long)(j + 3) * nbuck + tid];
            }
            v = (t0 + t1) + (t2 + t3);
        }
    }
    s[tid] = v;
    __syncthreads();
    for (int off = 1; off < 1024; off <<= 1) {
        int t = (tid >= off) ? s[tid - off] : 0;
        __syncthreads();
        s[tid] += t;
        __syncthreads();
    }
    if (blockIdx.x == 0) {
        if (tid < nb) bsums[tid] = s[tid] - v;
    } else {
        if (tid < nbuck) bbase[tid] = s[tid] - v;
        if (tid == 0) bbase[nbuck] = E;
    }
}

__global__ __launch_bounds__(256) void part2_k(const int* __restrict__ src,
                                               const int* __restrict__ dst,
                                               const int* __restrict__ offs,
                                               const int* __restrict__ bsums,
                                               unsigned* __restrict__ ebuf,
                                               int E, int nbuck, int chunk) {
    __shared__ int cur[1024];
    for (int i = threadIdx.x; i < nbuck; i += 256) {
        long flat = (long)blockIdx.x * nbuck + i;
        cur[i] = offs[flat] + bsums[flat >> 8];
    }
    __syncthreads();
    int beg = blockIdx.x * chunk;
    int end = min(E, beg + chunk);
    for (int e = beg + threadIdx.x; e < end; e += 256) {
        int d = dst[e];
        int b = d >> BSHIFT;
        int pos = atomicAdd(&cur[b], 1);
        ebuf[pos] = ((unsigned)(d & (BNODES - 1)) << 25) | (unsigned)src[e];
    }
}

__global__ __launch_bounds__(256) void finalize_k(const unsigned* __restrict__ ebuf,
                                                  const int* __restrict__ hist,
                                                  const int* __restrict__ offs,
                                                  const int* __restrict__ bsums,
                                                  const int* __restrict__ bbase,
                                                  int nbuck,
                                                  int* __restrict__ rowst,
                                                  int* __restrict__ rowend,
                                                  int* __restrict__ midp,
                                                  float* __restrict__ dinv,
                                                  int* __restrict__ col,
                                                  const float* __restrict__ x,
                                                  _Float16* __restrict__ msgX,
                                                  int N, int H) {
    __shared__ unsigned se[CAP];
    __shared__ int cj[PB], sj[PB], sb[PB];
    __shared__ int cnt_s[BNODES], cntA_s[BNODES], scan_s[BNODES];
    __shared__ int cur_s[BNODES], curB_s[BNODES];
    __shared__ float di_s[BNODES];

    int b = blockIdx.x, tid = threadIdx.x;
    int node0 = b << BSHIFT;
    int nn = min(BNODES, N - node0);
    int beg = bbase[b];

    if (tid < PB) {
        long flat = (long)tid * nbuck + b;
        cj[tid] = hist[flat];
        sj[tid] = offs[flat] + bsums[flat >> 8];
    }
    if (tid < BNODES) { cnt_s[tid] = 0; cntA_s[tid] = 0; }
    __syncthreads();

    if (tid < PB) sb[tid] = cj[tid];
    __syncthreads();
    for (int off = 1; off < PB; off <<= 1) {
        int t = 0;
        if (tid < PB && tid >= off) t = sb[tid - off];
        __syncthreads();
        if (tid < PB) sb[tid] += t;
        __syncthreads();
    }
    int m = sb[PB - 1];
    __syncthreads();

    // gather segments into LDS: 1 thread per segment (~8 edges each)
    {
        int j = tid;
        int base = sb[j] - cj[j], c = cj[j], s0 = sj[j];
        for (int k = 0; k < c; k++) {
            unsigned e = ebuf[s0 + k];
            int idx = base + k;
            if (idx < CAP) se[idx] = e;
            else {
                atomicAdd(&cnt_s[e >> 25], 1);
                if ((int)(e & 0x1FFFFFFu) < H) atomicAdd(&cntA_s[e >> 25], 1);
            }
        }
    }
    __syncthreads();

    int mcap = m < CAP ? m : CAP;
    for (int i = tid; i < mcap; i += 256) {
        unsigned e = se[i];
        atomicAdd(&cnt_s[e >> 25], 1);
        if ((int)(e & 0x1FFFFFFu) < H) atomicAdd(&cntA_s[e >> 25], 1);
    }
    __syncthreads();

    int v = (tid < BNODES) ? cnt_s[tid] : 0;
    if (tid < BNODES) scan_s[tid] = v;
    __syncthreads();
    for (int off = 1; off < BNODES; off <<= 1) {
        int t = 0;
        if (tid < BNODES && tid >= off) t = scan_s[tid - off];
        __syncthreads();
        if (tid < BNODES) scan_s[tid] += t;
        __syncthreads();
    }
    if (tid < nn) {
        int ex = scan_s[tid] - v;
        int st = beg + ex;
        int ca = cntA_s[tid];
        rowst[node0 + tid] = st;
        rowend[node0 + tid] = st + v;
        midp[node0 + tid] = st + ca;
        float di = rsqrtf((float)v + 1.0f);
        dinv[node0 + tid] = di;
        di_s[tid] = di;
        cur_s[tid] = ex;            // src<H cursor
        curB_s[tid] = ex + ca;      // src>=H cursor
    }
    __syncthreads();

    for (int i = tid; i < mcap; i += 256) {
        unsigned e = se[i];
        int s = (int)(e & 0x1FFFFFFu), d = e >> 25;
        int p = (s < H) ? atomicAdd(&cur_s[d], 1) : atomicAdd(&curB_s[d], 1);
        col[beg + p] = s;
    }
    if (m > CAP) {  // overflow spill (statistically never)
        int j = tid;
        int base = sb[j] - cj[j], c = cj[j], s0 = sj[j];
        for (int k = 0; k < c; k++) {
            int idx = base + k;
            if (idx >= CAP) {
                unsigned e = ebuf[s0 + k];
                int s = (int)(e & 0x1FFFFFFu), d = e >> 25;
                int p = (s < H) ? atomicAdd(&cur_s[d], 1) : atomicAdd(&curB_s[d], 1);
                col[beg + p] = s;
            }
        }
    }

    // fused msgX prep: msgX[n,64] f16 = dinv[n] * x[n,:]
    for (int t = tid; t < nn * 16; t += 256) {
        int nl = t >> 4, q = t & 15;
        int node = node0 + nl;
        float4 vx = *(const float4*)(x + (long)node * 64 + q * 4);
        float di = di_s[nl];
        vx.x *= di; vx.y *= di; vx.z *= di; vx.w *= di;
        store4h(msgX + (long)node * 64 + q * 4, vx);
    }
}

// ---- fused aggregate + MFMA GEMM (layer 1 only, K=64) ---------------------
// SMOUT: write C slice-major [FOUT/32][n][32] (for 64B-granule consumer).
// Col window of the block's 64 nodes staged in LDS (contiguous CSR ranges).
template <int K, int FOUT, bool BIAS, bool RELU, bool DINV_OUT, bool SMOUT>
__global__ __launch_bounds__(256) void fag_k(const _Float16* __restrict__ msg,
                                             const int* __restrict__ rowst,
                                             const int* __restrict__ rowend,
                                             const int* __restrict__ col,
                                             const float* __restrict__ dinv,
                                             const _Float16* __restrict__ Wsw,
                                             const float* __restrict__ bias,
                                             _Float16* __restrict__ C, int n) {
    constexpr int NT = FOUT / 16, NC = K / 32;
    constexpr int LDK = K + 8;
    constexpr int LPN = K / 8;
    constexpr int NPB = 256 / LPN;
    constexpr int CC = 2560;               // col window cap (mean ~1107)
    __shared__ _Float16 As[64 * LDK];
    __shared__ int cls[CC];

    int tid = threadIdx.x;
    int row0 = blockIdx.x * 64;

    // stage col window (coalesced bulk load; windows of consecutive nodes
    // are contiguous by CSR construction)
    int lastn = min(row0 + 64, n) - 1;
    int beg0 = rowst[row0];
    int win  = rowend[lastn] - beg0;
    int wl = min(win, CC);
    for (int i = tid; i < wl; i += 256) cls[i] = col[beg0 + i];
    __syncthreads();
    const int* cb = (win <= CC) ? (const int*)cls : (col + beg0);

#pragma unroll
    for (int pass = 0; pass < 64 / NPB; pass++) {
        int nl = pass * NPB + tid / LPN;
        int q = tid % LPN;
        int node = row0 + nl;
        float acc[8];
        if (node < n) {
            load8h(msg + (long)node * K + q * 8, acc);  // self (dinv folded)
            int beg = rowst[node] - beg0, end = rowend[node] - beg0;
            int e = beg;
            for (; e + 4 <= end; e += 4) {
                int s0 = cb[e], s1 = cb[e + 1], s2 = cb[e + 2], s3 = cb[e + 3];
                h8 v0 = *(const h8*)(msg + (long)s0 * K + q * 8);
                h8 v1 = *(const h8*)(msg + (long)s1 * K + q * 8);
                h8 v2 = *(const h8*)(msg + (long)s2 * K + q * 8);
                h8 v3 = *(const h8*)(msg + (long)s3 * K + q * 8);
#pragma unroll
                for (int j = 0; j < 8; j++)
                    acc[j] += ((float)v0[j] + (float)v1[j]) + ((float)v2[j] + (float)v3[j]);
            }
            for (; e < end; e++) {
                int s = cb[e];
                h8 v = *(const h8*)(msg + (long)s * K + q * 8);
#pragma unroll
                for (int j = 0; j < 8; j++) acc[j] += (float)v[j];
            }
            float di = dinv[node];
#pragma unroll
            for (int j = 0; j < 8; j++) acc[j] *= di;
        } else {
#pragma unroll
            for (int j = 0; j < 8; j++) acc[j] = 0.f;
        }
        h8 o;
#pragma unroll
        for (int j = 0; j < 8; j++) o[j] = (_Float16)acc[j];
        *(h8*)(As + nl * LDK + q * 8) = o;
    }
    __syncthreads();

    int lane = tid & 63, wave = tid >> 6;
    int quad = lane >> 4, cl = lane & 15;
    int r0 = wave * 16;

    h8 a[NC];
#pragma unroll
    for (int c = 0; c < NC; c++)
        a[c] = *(const h8*)(As + (r0 + cl) * LDK + quad * 8 + c * 32);

    f4 acc2[NT];
#pragma unroll
    for (int t = 0; t < NT; t++) acc2[t] = (f4){0.f, 0.f, 0.f, 0.f};

    const h8* wv = (const h8*)Wsw;
#pragma unroll
    for (int c = 0; c < NC; c++) {
#pragma unroll
        for (int t = 0; t < NT; t++)
            acc2[t] = __builtin_amdgcn_mfma_f32_16x16x32_f16(
                a[c], wv[(c * NT + t) * 64 + lane], acc2[t], 0, 0, 0);
    }

#pragma unroll
    for (int t = 0; t < NT; t++) {
        int c0 = t * 16 + cl;
        float bb = BIAS ? bias[c0] : 0.f;
#pragma unroll
        for (int r = 0; r < 4; r++) {
            int row = row0 + r0 + quad * 4 + r;
            if (row >= n) continue;
            float v = acc2[t][r] + bb;
            if (RELU) v = fmaxf(v, 0.f);
            if (DINV_OUT) v *= dinv[row];
            if (SMOUT)
                C[((long)(t >> 1) * n + row) * 32 + (t & 1) * 16 + cl] = (_Float16)v;
            else
                C[(long)row * FOUT + c0] = (_Float16)v;
        }
    }
}

// ---- layer-2 gather: 64B-granule slices, src-half partitioned, XCD-pinned -
// msg: [4][n][32] f16 slice-major. idx7 = blockIdx%8 -> slice=idx7&3,
// half=idx7>>2 (one (slice,half) per XCD; working set (n/2)*64B = 3.2MB).
// part: [2][4][n][32] f16 partial sums (no self, no dinv).
// 8 lanes/node: 2 edge-slots x 4 feature-quarters; 4 lanes coalesce 64B.
__global__ __launch_bounds__(256) void agg_h2_k(const _Float16* __restrict__ msg,
                                                const int* __restrict__ rowst,
                                                const int* __restrict__ midp,
                                                const int* __restrict__ rowend,
                                                const int* __restrict__ col,
                                                _Float16* __restrict__ part, int n) {
    constexpr int CC = 1536;               // col window cap (mean ~553)
    __shared__ int cls[CC];
    int idx7  = blockIdx.x & 7;
    int slice = idx7 & 3, half = idx7 >> 2;
    int blk   = blockIdx.x >> 3;
    int tid   = threadIdx.x;
    int node0b = blk * 32;

    int lastn = min(node0b + 32, n) - 1;
    int beg0 = rowst[node0b];
    int win  = rowend[lastn] - beg0;
    int wl = min(win, CC);
    for (int i = tid; i < wl; i += 256) cls[i] = col[beg0 + i];
    __syncthreads();
    const int* cb = (win <= CC) ? (const int*)cls : (col + beg0);

    int node  = node0b + (tid >> 3);
    int eslot = (tid >> 2) & 1;
    int q     = tid & 3;
    if (node >= n) return;
    const _Float16* mp = msg + (long)slice * n * 32 + q * 8;

    float acc[8];
#pragma unroll
    for (int j = 0; j < 8; j++) acc[j] = 0.f;

    int beg = (half ? midp[node] : rowst[node]) - beg0;
    int end = (half ? rowend[node] : midp[node]) - beg0;
    int e = beg + eslot;
    for (; e + 6 < end; e += 8) {          // 4 gathers in flight per lane
        int s0 = cb[e], s1 = cb[e + 2], s2 = cb[e + 4], s3 = cb[e + 6];
        h8 v0 = *(const h8*)(mp + (long)s0 * 32);
        h8 v1 = *(const h8*)(mp + (long)s1 * 32);
        h8 v2 = *(const h8*)(mp + (long)s2 * 32);
        h8 v3 = *(const h8*)(mp + (long)s3 * 32);
#pragma unroll
        for (int j = 0; j < 8; j++)
            acc[j] += (((float)v0[j] + (float)v1[j]) + ((float)v2[j] + (float)v3[j]));
    }
    for (; e < end; e += 2) {
        int s = cb[e];
        h8 v = *(const h8*)(mp + (long)s * 32);
#pragma unroll
        for (int j = 0; j < 8; j++) acc[j] += (float)v[j];
    }

    // reduce over the 2 edge slots (lanes ^4 share node & q)
#pragma unroll
    for (int j = 0; j < 8; j++) acc[j] += __shfl_xor(acc[j], 4);

    if (eslot == 0) {                      // 4 lanes/node write 64B contiguous
        store8h(part + (((long)half * 4 + slice) * n + node) * 32 + q * 8, acc);
    }
}

// ---- standalone row-major aggregation (layer 3; LDS col, 8-deep) ----------
template <int F, bool BIAS, bool F16OUT>
__global__ __launch_bounds__(256) void agg_f16_k(const _Float16* __restrict__ msg,
                                                 const int* __restrict__ rowst,
                                                 const int* __restrict__ rowend,
                                                 const int* __restrict__ col,
                                                 const float* __restrict__ dinv,
                                                 const float* __restrict__ b,
                                                 void* __restrict__ out, int n) {
    constexpr int LPN = F / 8;
    constexpr int NPB = 256 / LPN;
    constexpr int CC = NPB * 48;           // 1536 for NPB=32
    __shared__ int cls[CC];
    int tid = threadIdx.x;
    int node0b = blockIdx.x * NPB;

    int lastn = min(node0b + NPB, n) - 1;
    int beg0 = rowst[node0b];
    int win  = rowend[lastn] - beg0;
    int wl = min(win, CC);
    for (int i = tid; i < wl; i += 256) cls[i] = col[beg0 + i];
    __syncthreads();
    const int* cb = (win <= CC) ? (const int*)cls : (col + beg0);

    int node = node0b + tid / LPN;
    int q = tid % LPN;
    if (node >= n) return;

    float acc[8];
    load8h(msg + (long)node * F + q * 8, acc);

    int beg = rowst[node] - beg0, end = rowend[node] - beg0;
    int e = beg;
    for (; e + 8 <= end; e += 8) {     // 8 independent gathers in flight
        h8 v[8];
#pragma unroll
        for (int u = 0; u < 8; u++)
            v[u] = *(const h8*)(msg + (long)cb[e + u] * F + q * 8);
#pragma unroll
        for (int j = 0; j < 8; j++)
            acc[j] += (((float)v[0][j] + (float)v[1][j]) + ((float)v[2][j] + (float)v[3][j])) +
                      (((float)v[4][j] + (float)v[5][j]) + ((float)v[6][j] + (float)v[7][j]));
    }
    for (; e + 4 <= end; e += 4) {
        h8 v0 = *(const h8*)(msg + (long)cb[e] * F + q * 8);
        h8 v1 = *(const h8*)(msg + (long)cb[e + 1] * F + q * 8);
        h8 v2 = *(const h8*)(msg + (long)cb[e + 2] * F + q * 8);
        h8 v3 = *(const h8*)(msg + (long)cb[e + 3] * F + q * 8);
#pragma unroll
        for (int j = 0; j < 8; j++)
            acc[j] += ((float)v0[j] + (float)v1[j]) + ((float)v2[j] + (float)v3[j]);
    }
    for (; e < end; e++) {
        h8 v = *(const h8*)(msg + (long)cb[e] * F + q * 8);
#pragma unroll
        for (int j = 0; j < 8; j++) acc[j] += (float)v[j];
    }

    float di = dinv[node];
    float o[8];
#pragma unroll
    for (int j = 0; j < 8; j++) o[j] = di * acc[j];
    if (BIAS) {
#pragma unroll
        for (int j = 0; j < 8; j++) o[j] += b[q * 8 + j];
    }
    if (F16OUT) {
        store8h((_Float16*)out + (long)node * F + q * 8, o);
    } else {
        float* dst = (float*)out + (long)node * F + q * 8;
        *(float4*)dst = make_float4(o[0], o[1], o[2], o[3]);
        *(float4*)(dst + 4) = make_float4(o[4], o[5], o[6], o[7]);
    }
}

// ---- weight swizzle -------------------------------------------------------
template <int K, int FOUT>
__device__ inline void wfrag(const float* __restrict__ W,
                             _Float16* __restrict__ Wsw, int t) {
    constexpr int NT = FOUT / 16;
    int lane = t & 63;
    int tile = (t >> 6) % NT;
    int chunk = (t >> 6) / NT;
    int kbase = chunk * 32 + (lane >> 4) * 8;
    int nc = tile * 16 + (lane & 15);
    h8 v;
#pragma unroll
    for (int j = 0; j < 8; j++) v[j] = (_Float16)W[(kbase + j) * FOUT + nc];
    ((h8*)Wsw)[t] = v;
}

__global__ __launch_bounds__(256) void wprep3_k(const float* __restrict__ W1,
                                                const float* __restrict__ W2,
                                                const float* __restrict__ W3,
                                                _Float16* __restrict__ w1s,
                                                _Float16* __restrict__ w2s,
                                                _Float16* __restrict__ w3s) {
    int t = blockIdx.x * 256 + threadIdx.x;
    if (t < 1024) wfrag<64, 128>(W1, w1s, t);
    else if (t < 3072) wfrag<128, 128>(W2, w2s, t - 1024);
    else if (t < 4096) wfrag<128, 64>(W3, w3s, t - 3072);
}

// ---- fused double GEMM: msg3 = dinv (.) ( relu(A@W2 + b2) @ W3 ) ----------
// A combined in-register: (partA + partB + self) * dinv, all [4][n][32] f16.
// 64 rows/block, 4 waves; wave-private intermediate rows in LDS.
__global__ __launch_bounds__(256) void dgemm_k(const _Float16* __restrict__ part,
                                               const _Float16* __restrict__ selfm,
                                               const _Float16* __restrict__ w2s,
                                               const _Float16* __restrict__ w3s,
                                               const float* __restrict__ b2,
                                               const float* __restrict__ dinv,
                                               _Float16* __restrict__ C, int n) {
    constexpr int LDK = 136;
    __shared__ _Float16 Hs[64 * LDK];

    int tid = threadIdx.x, lane = tid & 63, wave = tid >> 6;
    int quad = lane >> 4, cl = lane & 15;
    int row0 = blockIdx.x * 64, r0 = wave * 16;
    int arow = row0 + r0 + cl;

    const _Float16* pA = part;
    const _Float16* pB = part + (long)4 * n * 32;
    float di = dinv[arow];                 // tail rows read garbage; row-isolated

    // GEMM-1: rows r0..r0+15, K=128 -> 128.  f = c*32+quad*8 -> slice c.
    h8 a[4];
#pragma unroll
    for (int c = 0; c < 4; c++) {
        long off = ((long)c * n + arow) * 32 + quad * 8;
        h8 va = *(const h8*)(pA + off);
        h8 vb = *(const h8*)(pB + off);
        h8 vs = *(const h8*)(selfm + off);
        h8 o;
#pragma unroll
        for (int j = 0; j < 8; j++) {
            float f = (((float)va[j] + (float)vb[j]) + (float)vs[j]) * di;
            o[j] = (_Float16)f;
        }
        a[c] = o;
    }

    f4 acc1[8];
#pragma unroll
    for (int t = 0; t < 8; t++) acc1[t] = (f4){0.f, 0.f, 0.f, 0.f};
    const h8* wv2 = (const h8*)w2s;
#pragma unroll
    for (int c = 0; c < 4; c++) {
#pragma unroll
        for (int t = 0; t < 8; t++)
            acc1[t] = __builtin_amdgcn_mfma_f32_16x16x32_f16(
                a[c], wv2[(c * 8 + t) * 64 + lane], acc1[t], 0, 0, 0);
    }

    // epilogue 1: +b2, relu -> wave-private LDS rows
#pragma unroll
    for (int t = 0; t < 8; t++) {
        int c0 = t * 16 + cl;
        float bb = b2[c0];
#pragma unroll
        for (int r = 0; r < 4; r++) {
            float v = fmaxf(acc1[t][r] + bb, 0.f);
            Hs[(r0 + quad * 4 + r) * LDK + c0] = (_Float16)v;
        }
    }
    __builtin_amdgcn_s_waitcnt(0);   // drain LDS writes (wave-private rows)

    // GEMM-2: K=128 -> 64
    h8 a2[4];
#pragma unroll
    for (int c = 0; c < 4; c++)
        a2[c] = *(const h8*)(Hs + (r0 + cl) * LDK + quad * 8 + c * 32);

    f4 acc2[4];
#pragma unroll
    for (int t = 0; t < 4; t++) acc2[t] = (f4){0.f, 0.f, 0.f, 0.f};
    const h8* wv3 = (const h8*)w3s;
#pragma unroll
    for (int c = 0; c < 4; c++) {
#pragma unroll
        for (int t = 0; t < 4; t++)
            acc2[t] = __builtin_amdgcn_mfma_f32_16x16x32_f16(
                a2[c], wv3[(c * 4 + t) * 64 + lane], acc2[t], 0, 0, 0);
    }

    // epilogue 2: *dinv, store msg3 row-major [n][64]
#pragma unroll
    for (int t = 0; t < 4; t++) {
        int c0 = t * 16 + cl;
#pragma unroll
        for (int r = 0; r < 4; r++) {
            int row = row0 + r0 + quad * 4 + r;
            if (row >= n) continue;
            float v = acc2[t][r] * dinv[row];
            C[(long)row * 64 + c0] = (_Float16)v;
        }
    }
}

extern "C" void kernel_launch(void* const* d_in, const int* in_sizes, int n_in,
                              void* d_out, int out_size, void* d_ws, size_t ws_size,
                              hipStream_t stream) {
    const float* x  = (const float*)d_in[0];
    const int*   ei = (const int*)d_in[1];
    const float* W1 = (const float*)d_in[2];
    const float* b1 = (const float*)d_in[3];
    const float* W2 = (const float*)d_in[4];
    const float* b2 = (const float*)d_in[5];
    const float* W3 = (const float*)d_in[6];
    const float* b3 = (const float*)d_in[7];
    float* out = (float*)d_out;

    const int N = in_sizes[0] / 64;
    const int E = in_sizes[1] / 2;
    const int* src = ei;
    const int* dst = ei + E;
    const int nbuck = (N + BNODES - 1) >> BSHIFT;   // 782
    const int chunk = (E + PB - 1) / PB;            // 6250
    const int n2 = PB * nbuck;                      // 200192
    const int nb2 = (n2 + 255) / 256;               // 782

    // workspace carve-up (4-byte elems)
    int*   hist   = (int*)d_ws;                   // PB*nbuck
    int*   offs   = hist + n2;                    // PB*nbuck
    int*   bsums  = offs + n2;                    // 1024
    int*   bbase  = bsums + 1024;                 // nbuck+1
    int*   rowst  = bbase + nbuck + 1;            // N
    int*   rowend = rowst + N;                    // N
    float* dinv   = (float*)(rowend + N);         // N
    int*   col    = (int*)(dinv + N);             // E
    _Float16* w1s = (_Float16*)(col + E);         // 64*128 f16
    _Float16* w2s = w1s + 64 * 128;               // 128*128 f16
    _Float16* w3s = w2s + 128 * 128;              // 128*64 f16
    float* P      = (float*)(w3s + 128 * 64);     // N*128 f32 worth
    float* Q      = P + (long)N * 128;            // N*128 f32 worth

    _Float16* msgX  = (_Float16*)P;   // N x 64 f16 (dead after fag)
    _Float16* part  = (_Float16*)P;   // [2][4][N][32] f16 partials (51.2MB = P)
    unsigned* ebuf  = (unsigned*)Q;   // E x 4B (dead after finalize)
    _Float16* msg1  = (_Float16*)Q;   // [4][N][32] f16 (F1 out; byte 0..256N)
    _Float16* msg3  = (_Float16*)(Q + (long)N * 64);  // [N][64] f16 (byte 256N..384N)
    int*      midp  = (int*)(Q + (long)N * 96);       // N ints (byte 384N..388N)

    const int gb = (N + 63) / 64;

    // ---- weight swizzle ----
    wprep3_k<<<16, 256, 0, stream>>>(W1, W2, W3, w1s, w2s, w3s);

    // ---- CSR build ----
    phist_k<<<PB, 256, 0, stream>>>(dst, hist, E, nbuck, chunk);
    scan_blocks_k<<<nb2, 256, 0, stream>>>(hist, offs, bsums, n2);
    mid_k<<<2, 1024, 0, stream>>>(bsums, nb2, hist, bbase, nbuck, E);
    part2_k<<<PB, 256, 0, stream>>>(src, dst, offs, bsums, ebuf, E, nbuck, chunk);
    finalize_k<<<nbuck, 256, 0, stream>>>(ebuf, hist, offs, bsums, bbase, nbuck,
                                          rowst, rowend, midp, dinv, col, x,
                                          msgX, N, N / 2);

    // ---- layer 1 (fused agg+gemm): msgX(P) -> msg1 [4][N][32] (Q) ----
    fag_k<64, 128, true, true, true, true><<<gb, 256, 0, stream>>>(
        msgX, rowst, rowend, col, dinv, w1s, b1, msg1, N);

    // ---- layer 2 gather (64B slices, src-half, XCD-pinned): msg1 -> part ----
    const int nb32 = (N + 31) / 32;      // 3125
    agg_h2_k<<<8 * nb32, 256, 0, stream>>>(
        msg1, rowst, midp, rowend, col, part, N);

    // ---- fused gemm2+gemm3 (+combine): part,msg1 -> msg3 row-major (Q) ----
    dgemm_k<<<gb, 256, 0, stream>>>(part, msg1, w2s, w3s, b2, dinv, msg3, N);

    // ---- layer 3 gather (row-major, LDS col, 8-deep): msg3(Q) -> out ----
    agg_f16_k<64, true, false><<<(N + 31) / 32, 256, 0, stream>>>(
        msg3, rowst, rowend, col, dinv, b3, (void*)out, N);
}

// Round 9
// 359.541 us; speedup vs baseline: 2.5399x; 1.0123x over previous
//
#include <hip/hip_runtime.h>
#include <hip/hip_bf16.h>
#include <hip/hip_fp16.h>

// ---------------------------------------------------------------------------
// GCN 3-layer forward. N=100000, E=1600000, F: 64 -> 128 -> 128 -> 64.
// R17: layer-1 gets the R16 partials treatment. fag_k (66us, FETCH 146MB,
//      unpartitioned 12.8MB table missing to LLC) is split into:
//      agg_h1 (64B-granule, 2 slices x 2 src-halves x 2 node-halves across
//      8 XCDs; window (N/2)*64B=3.2MB L2-resident; partials [2][2][N][32])
//      + fagc (streaming combine (pH0+pH1+self)*dinv -> MFMA GEMM, no gather).
//      finalize now writes msgX slice-major [2][N][32].
//   CSR: phist -> scan_blocks -> mid -> part2 -> finalize(+midp)
//   agg_h1: msgXs(P) -> part1 [2][2][N][32] (P hi)
//   fagc: (part1,msgXs,dinv) -> msg1 [4][N][32] (Q)  [+b1, relu, *dinv]
//   agg_h2: msg1(Q) -> part2 [2][4][N][32] (P)
//   dgemm: (part2,msg1,dinv) -> msg3 [N][64] (Q)     [W2,+b2,relu | W3,*dinv]
//   agg_f16<64>: msg3(Q) -> out (+b3, f32)
// ---------------------------------------------------------------------------

typedef _Float16 h8 __attribute__((ext_vector_type(8)));
typedef float f4 __attribute__((ext_vector_type(4)));

constexpr int BSHIFT = 7;                 // 128 nodes per bucket
constexpr int BNODES = 1 << BSHIFT;
constexpr int PB     = 256;               // partition blocks
constexpr int CAP    = 4096;              // finalize LDS stage capacity

// ---- f16 helpers ----------------------------------------------------------
__device__ inline void load8h(const _Float16* p, float* f) {
    h8 v = *(const h8*)p;
#pragma unroll
    for (int j = 0; j < 8; j++) f[j] = (float)v[j];
}

__device__ inline void store8h(_Float16* p, const float* f) {
    h8 v;
#pragma unroll
    for (int j = 0; j < 8; j++) v[j] = (_Float16)f[j];
    *(h8*)p = v;
}

__device__ inline void store4h(_Float16* p, float4 v) {
    _Float16 t[4] = {(_Float16)v.x, (_Float16)v.y, (_Float16)v.z, (_Float16)v.w};
    *(uint2*)p = *(uint2*)t;
}

// ---- CSR build ------------------------------------------------------------
__global__ __launch_bounds__(256) void phist_k(const int* __restrict__ dst,
                                               int* __restrict__ hist,
                                               int E, int nbuck, int chunk) {
    __shared__ int h[1024];
    for (int i = threadIdx.x; i < nbuck; i += 256) h[i] = 0;
    __syncthreads();
    int beg = blockIdx.x * chunk;
    int end = min(E, beg + chunk);
    for (int e = beg + threadIdx.x; e < end; e += 256)
        atomicAdd(&h[dst[e] >> BSHIFT], 1);
    __syncthreads();
    for (int i = threadIdx.x; i < nbuck; i += 256)
        hist[(long)blockIdx.x * nbuck + i] = h[i];
}

__global__ __launch_bounds__(256) void scan_blocks_k(const int* __restrict__ in,
                                                     int* __restrict__ excl,
                                                     int* __restrict__ bsums, int n) {
    __shared__ int s[256];
    int tid = threadIdx.x;
    int i = blockIdx.x * 256 + tid;
    int v = (i < n) ? in[i] : 0;
    s[tid] = v;
    __syncthreads();
    for (int off = 1; off < 256; off <<= 1) {
        int t = (tid >= off) ? s[tid - off] : 0;
        __syncthreads();
        s[tid] += t;
        __syncthreads();
    }
    if (i < n) excl[i] = s[tid] - v;
    if (tid == 255) bsums[blockIdx.x] = s[255];
}

// block 0: exclusive scan of bsums; block 1: column-sum hist -> scan -> bbase
__global__ __launch_bounds__(1024) void mid_k(int* __restrict__ bsums, int nb,
                                              const int* __restrict__ hist,
                                              int* __restrict__ bbase,
                                              int nbuck, int E) {
    __shared__ int s[1024];
    int tid = threadIdx.x;
    int v = 0;
    if (blockIdx.x == 0) {
        v = (tid < nb) ? bsums[tid] : 0;
    } else {
        if (tid < nbuck) {
            int t0 = 0, t1 = 0, t2 = 0, t3 = 0;
            for (int j = 0; j < PB; j += 4) {
                t0 += hist[(long)(j + 0) * nbuck + tid];
                t1 += hist[(long)(j + 1) * nbuck + tid];
                t2 += hist[(long)(j + 2) * nbuck + tid];
                t3 += hist[(long)(j + 3) * nbuck + tid];
            }
            v = (t0 + t1) + (t2 + t3);
        }
    }
    s[tid] = v;
    __syncthreads();
    for (int off = 1; off < 1024; off <<= 1) {
        int t = (tid >= off) ? s[tid - off] : 0;
        __syncthreads();
        s[tid] += t;
        __syncthreads();
    }
    if (blockIdx.x == 0) {
        if (tid < nb) bsums[tid] = s[tid] - v;
    } else {
        if (tid < nbuck) bbase[tid] = s[tid] - v;
        if (tid == 0) bbase[nbuck] = E;
    }
}

__global__ __launch_bounds__(256) void part2_k(const int* __restrict__ src,
                                               const int* __restrict__ dst,
                                               const int* __restrict__ offs,
                                               const int* __restrict__ bsums,
                                               unsigned* __restrict__ ebuf,
                                               int E, int nbuck, int chunk) {
    __shared__ int cur[1024];
    for (int i = threadIdx.x; i < nbuck; i += 256) {
        long flat = (long)blockIdx.x * nbuck + i;
        cur[i] = offs[flat] + bsums[flat >> 8];
    }
    __syncthreads();
    int beg = blockIdx.x * chunk;
    int end = min(E, beg + chunk);
    for (int e = beg + threadIdx.x; e < end; e += 256) {
        int d = dst[e];
        int b = d >> BSHIFT;
        int pos = atomicAdd(&cur[b], 1);
        ebuf[pos] = ((unsigned)(d & (BNODES - 1)) << 25) | (unsigned)src[e];
    }
}

__global__ __launch_bounds__(256) void finalize_k(const unsigned* __restrict__ ebuf,
                                                  const int* __restrict__ hist,
                                                  const int* __restrict__ offs,
                                                  const int* __restrict__ bsums,
                                                  const int* __restrict__ bbase,
                                                  int nbuck,
                                                  int* __restrict__ rowst,
                                                  int* __restrict__ rowend,
                                                  int* __restrict__ midp,
                                                  float* __restrict__ dinv,
                                                  int* __restrict__ col,
                                                  const float* __restrict__ x,
                                                  _Float16* __restrict__ msgX,
                                                  int N, int H) {
    __shared__ unsigned se[CAP];
    __shared__ int cj[PB], sj[PB], sb[PB];
    __shared__ int cnt_s[BNODES], cntA_s[BNODES], scan_s[BNODES];
    __shared__ int cur_s[BNODES], curB_s[BNODES];
    __shared__ float di_s[BNODES];

    int b = blockIdx.x, tid = threadIdx.x;
    int node0 = b << BSHIFT;
    int nn = min(BNODES, N - node0);
    int beg = bbase[b];

    if (tid < PB) {
        long flat = (long)tid * nbuck + b;
        cj[tid] = hist[flat];
        sj[tid] = offs[flat] + bsums[flat >> 8];
    }
    if (tid < BNODES) { cnt_s[tid] = 0; cntA_s[tid] = 0; }
    __syncthreads();

    if (tid < PB) sb[tid] = cj[tid];
    __syncthreads();
    for (int off = 1; off < PB; off <<= 1) {
        int t = 0;
        if (tid < PB && tid >= off) t = sb[tid - off];
        __syncthreads();
        if (tid < PB) sb[tid] += t;
        __syncthreads();
    }
    int m = sb[PB - 1];
    __syncthreads();

    // gather segments into LDS: 1 thread per segment (~8 edges each)
    {
        int j = tid;
        int base = sb[j] - cj[j], c = cj[j], s0 = sj[j];
        for (int k = 0; k < c; k++) {
            unsigned e = ebuf[s0 + k];
            int idx = base + k;
            if (idx < CAP) se[idx] = e;
            else {
                atomicAdd(&cnt_s[e >> 25], 1);
                if ((int)(e & 0x1FFFFFFu) < H) atomicAdd(&cntA_s[e >> 25], 1);
            }
        }
    }
    __syncthreads();

    int mcap = m < CAP ? m : CAP;
    for (int i = tid; i < mcap; i += 256) {
        unsigned e = se[i];
        atomicAdd(&cnt_s[e >> 25], 1);
        if ((int)(e & 0x1FFFFFFu) < H) atomicAdd(&cntA_s[e >> 25], 1);
    }
    __syncthreads();

    int v = (tid < BNODES) ? cnt_s[tid] : 0;
    if (tid < BNODES) scan_s[tid] = v;
    __syncthreads();
    for (int off = 1; off < BNODES; off <<= 1) {
        int t = 0;
        if (tid < BNODES && tid >= off) t = scan_s[tid - off];
        __syncthreads();
        if (tid < BNODES) scan_s[tid] += t;
        __syncthreads();
    }
    if (tid < nn) {
        int ex = scan_s[tid] - v;
        int st = beg + ex;
        int ca = cntA_s[tid];
        rowst[node0 + tid] = st;
        rowend[node0 + tid] = st + v;
        midp[node0 + tid] = st + ca;
        float di = rsqrtf((float)v + 1.0f);
        dinv[node0 + tid] = di;
        di_s[tid] = di;
        cur_s[tid] = ex;            // src<H cursor
        curB_s[tid] = ex + ca;      // src>=H cursor
    }
    __syncthreads();

    for (int i = tid; i < mcap; i += 256) {
        unsigned e = se[i];
        int s = (int)(e & 0x1FFFFFFu), d = e >> 25;
        int p = (s < H) ? atomicAdd(&cur_s[d], 1) : atomicAdd(&curB_s[d], 1);
        col[beg + p] = s;
    }
    if (m > CAP) {  // overflow spill (statistically never)
        int j = tid;
        int base = sb[j] - cj[j], c = cj[j], s0 = sj[j];
        for (int k = 0; k < c; k++) {
            int idx = base + k;
            if (idx >= CAP) {
                unsigned e = ebuf[s0 + k];
                int s = (int)(e & 0x1FFFFFFu), d = e >> 25;
                int p = (s < H) ? atomicAdd(&cur_s[d], 1) : atomicAdd(&curB_s[d], 1);
                col[beg + p] = s;
            }
        }
    }

    // fused msgX prep: msgX SLICE-MAJOR [2][N][32] f16 = dinv[n] * x[n,:]
    for (int t = tid; t < nn * 16; t += 256) {
        int nl = t >> 4, q = t & 15;
        int node = node0 + nl;
        float4 vx = *(const float4*)(x + (long)node * 64 + q * 4);
        float di = di_s[nl];
        vx.x *= di; vx.y *= di; vx.z *= di; vx.w *= di;
        int sl = q >> 3, ps = (q & 7) * 4;
        store4h(msgX + ((long)sl * N + node) * 32 + ps, vx);
    }
}

// ---- layer-1 gather: 64B-granule slices, src-half + node-half, XCD-pinned -
// msg: [2][n][32] f16 slice-major. idx7: slice=bit0, srcHalf=bit1,
// nodeHalf=bit2 (each XCD window = (n/2)*64B = 3.2MB; each (slice,half) on
// 2 XCDs split by node range). part: [2][2][n][32] f16 partials.
// 8 lanes/node: 2 edge-slots x 4 feature-quarters; 4 lanes coalesce 64B.
__global__ __launch_bounds__(256) void agg_h1_k(const _Float16* __restrict__ msg,
                                                const int* __restrict__ rowst,
                                                const int* __restrict__ midp,
                                                const int* __restrict__ rowend,
                                                const int* __restrict__ col,
                                                _Float16* __restrict__ part, int n) {
    constexpr int CC = 1536;               // col window cap (mean ~553)
    __shared__ int cls[CC];
    int idx7  = blockIdx.x & 7;
    int slice = idx7 & 1, half = (idx7 >> 1) & 1, nh = idx7 >> 2;
    int blk   = ((blockIdx.x >> 3) << 1) + nh;
    int tid   = threadIdx.x;
    int node0b = blk * 32;
    if (node0b >= n) return;

    int lastn = min(node0b + 32, n) - 1;
    int beg0 = rowst[node0b];
    int win  = rowend[lastn] - beg0;
    int wl = min(win, CC);
    for (int i = tid; i < wl; i += 256) cls[i] = col[beg0 + i];
    __syncthreads();
    const int* cb = (win <= CC) ? (const int*)cls : (col + beg0);

    int node  = node0b + (tid >> 3);
    int eslot = (tid >> 2) & 1;
    int q     = tid & 3;
    if (node >= n) return;
    const _Float16* mp = msg + (long)slice * n * 32 + q * 8;

    float acc[8];
#pragma unroll
    for (int j = 0; j < 8; j++) acc[j] = 0.f;

    int beg = (half ? midp[node] : rowst[node]) - beg0;
    int end = (half ? rowend[node] : midp[node]) - beg0;
    int e = beg + eslot;
    for (; e + 6 < end; e += 8) {          // 4 gathers in flight per lane
        int s0 = cb[e], s1 = cb[e + 2], s2 = cb[e + 4], s3 = cb[e + 6];
        h8 v0 = *(const h8*)(mp + (long)s0 * 32);
        h8 v1 = *(const h8*)(mp + (long)s1 * 32);
        h8 v2 = *(const h8*)(mp + (long)s2 * 32);
        h8 v3 = *(const h8*)(mp + (long)s3 * 32);
#pragma unroll
        for (int j = 0; j < 8; j++)
            acc[j] += (((float)v0[j] + (float)v1[j]) + ((float)v2[j] + (float)v3[j]));
    }
    for (; e < end; e += 2) {
        int s = cb[e];
        h8 v = *(const h8*)(mp + (long)s * 32);
#pragma unroll
        for (int j = 0; j < 8; j++) acc[j] += (float)v[j];
    }

    // reduce over the 2 edge slots (lanes ^4 share node & q)
#pragma unroll
    for (int j = 0; j < 8; j++) acc[j] += __shfl_xor(acc[j], 4);

    if (eslot == 0) {                      // 4 lanes/node write 64B contiguous
        store8h(part + (((long)half * 2 + slice) * n + node) * 32 + q * 8, acc);
    }
}

// ---- layer-1 combine + MFMA GEMM (streaming, no gather) -------------------
// A = (partH0 + partH1 + self) * dinv, all [2][n][32] f16 slice-major.
// C = relu(A@W1 + b1) * dinv, written slice-major [4][n][32] for agg_h2.
__global__ __launch_bounds__(256) void fagc_k(const _Float16* __restrict__ part,
                                              const _Float16* __restrict__ selfm,
                                              const float* __restrict__ dinv,
                                              const _Float16* __restrict__ w1s,
                                              const float* __restrict__ b1,
                                              _Float16* __restrict__ C, int n) {
    int tid = threadIdx.x, lane = tid & 63, wave = tid >> 6;
    int quad = lane >> 4, cl = lane & 15;
    int row0 = blockIdx.x * 64, r0 = wave * 16;
    int arow = row0 + r0 + cl;

    float di = dinv[arow];                 // tail rows read garbage; row-isolated

    // A: K=64 -> 2 chunks of 32 (= slice c), f = c*32 + quad*8
    h8 a[2];
#pragma unroll
    for (int c = 0; c < 2; c++) {
        long off = ((long)c * n + arow) * 32 + quad * 8;
        h8 v0 = *(const h8*)(part + off);                       // srcHalf 0
        h8 v1 = *(const h8*)(part + (long)2 * n * 32 + off);    // srcHalf 1
        h8 vs = *(const h8*)(selfm + off);                      // self
        h8 o;
#pragma unroll
        for (int j = 0; j < 8; j++) {
            float f = (((float)v0[j] + (float)v1[j]) + (float)vs[j]) * di;
            o[j] = (_Float16)f;
        }
        a[c] = o;
    }

    f4 acc[8];
#pragma unroll
    for (int t = 0; t < 8; t++) acc[t] = (f4){0.f, 0.f, 0.f, 0.f};
    const h8* wv = (const h8*)w1s;
#pragma unroll
    for (int c = 0; c < 2; c++) {
#pragma unroll
        for (int t = 0; t < 8; t++)
            acc[t] = __builtin_amdgcn_mfma_f32_16x16x32_f16(
                a[c], wv[(c * 8 + t) * 64 + lane], acc[t], 0, 0, 0);
    }

    // epilogue: +b1, relu, *dinv, store slice-major [4][n][32]
#pragma unroll
    for (int t = 0; t < 8; t++) {
        int c0 = t * 16 + cl;
        float bb = b1[c0];
#pragma unroll
        for (int r = 0; r < 4; r++) {
            int row = row0 + r0 + quad * 4 + r;
            if (row >= n) continue;
            float v = fmaxf(acc[t][r] + bb, 0.f) * dinv[row];
            C[((long)(t >> 1) * n + row) * 32 + (t & 1) * 16 + cl] = (_Float16)v;
        }
    }
}

// ---- layer-2 gather: 64B-granule slices, src-half partitioned, XCD-pinned -
// msg: [4][n][32] f16 slice-major. idx7 = blockIdx%8 -> slice=idx7&3,
// half=idx7>>2 (one (slice,half) per XCD; working set (n/2)*64B = 3.2MB).
// part: [2][4][n][32] f16 partial sums (no self, no dinv).
// 8 lanes/node: 2 edge-slots x 4 feature-quarters; 4 lanes coalesce 64B.
__global__ __launch_bounds__(256) void agg_h2_k(const _Float16* __restrict__ msg,
                                                const int* __restrict__ rowst,
                                                const int* __restrict__ midp,
                                                const int* __restrict__ rowend,
                                                const int* __restrict__ col,
                                                _Float16* __restrict__ part, int n) {
    constexpr int CC = 1536;               // col window cap (mean ~553)
    __shared__ int cls[CC];
    int idx7  = blockIdx.x & 7;
    int slice = idx7 & 3, half = idx7 >> 2;
    int blk   = blockIdx.x >> 3;
    int tid   = threadIdx.x;
    int node0b = blk * 32;

    int lastn = min(node0b + 32, n) - 1;
    int beg0 = rowst[node0b];
    int win  = rowend[lastn] - beg0;
    int wl = min(win, CC);
    for (int i = tid; i < wl; i += 256) cls[i] = col[beg0 + i];
    __syncthreads();
    const int* cb = (win <= CC) ? (const int*)cls : (col + beg0);

    int node  = node0b + (tid >> 3);
    int eslot = (tid >> 2) & 1;
    int q     = tid & 3;
    if (node >= n) return;
    const _Float16* mp = msg + (long)slice * n * 32 + q * 8;

    float acc[8];
#pragma unroll
    for (int j = 0; j < 8; j++) acc[j] = 0.f;

    int beg = (half ? midp[node] : rowst[node]) - beg0;
    int end = (half ? rowend[node] : midp[node]) - beg0;
    int e = beg + eslot;
    for (; e + 6 < end; e += 8) {          // 4 gathers in flight per lane
        int s0 = cb[e], s1 = cb[e + 2], s2 = cb[e + 4], s3 = cb[e + 6];
        h8 v0 = *(const h8*)(mp + (long)s0 * 32);
        h8 v1 = *(const h8*)(mp + (long)s1 * 32);
        h8 v2 = *(const h8*)(mp + (long)s2 * 32);
        h8 v3 = *(const h8*)(mp + (long)s3 * 32);
#pragma unroll
        for (int j = 0; j < 8; j++)
            acc[j] += (((float)v0[j] + (float)v1[j]) + ((float)v2[j] + (float)v3[j]));
    }
    for (; e < end; e += 2) {
        int s = cb[e];
        h8 v = *(const h8*)(mp + (long)s * 32);
#pragma unroll
        for (int j = 0; j < 8; j++) acc[j] += (float)v[j];
    }

    // reduce over the 2 edge slots (lanes ^4 share node & q)
#pragma unroll
    for (int j = 0; j < 8; j++) acc[j] += __shfl_xor(acc[j], 4);

    if (eslot == 0) {                      // 4 lanes/node write 64B contiguous
        store8h(part + (((long)half * 4 + slice) * n + node) * 32 + q * 8, acc);
    }
}

// ---- standalone row-major aggregation (layer 3; LDS col, 8-deep) ----------
template <int F, bool BIAS, bool F16OUT>
__global__ __launch_bounds__(256) void agg_f16_k(const _Float16* __restrict__ msg,
                                                 const int* __restrict__ rowst,
                                                 const int* __restrict__ rowend,
                                                 const int* __restrict__ col,
                                                 const float* __restrict__ dinv,
                                                 const float* __restrict__ b,
                                                 void* __restrict__ out, int n) {
    constexpr int LPN = F / 8;
    constexpr int NPB = 256 / LPN;
    constexpr int CC = NPB * 48;           // 1536 for NPB=32
    __shared__ int cls[CC];
    int tid = threadIdx.x;
    int node0b = blockIdx.x * NPB;

    int lastn = min(node0b + NPB, n) - 1;
    int beg0 = rowst[node0b];
    int win  = rowend[lastn] - beg0;
    int wl = min(win, CC);
    for (int i = tid; i < wl; i += 256) cls[i] = col[beg0 + i];
    __syncthreads();
    const int* cb = (win <= CC) ? (const int*)cls : (col + beg0);

    int node = node0b + tid / LPN;
    int q = tid % LPN;
    if (node >= n) return;

    float acc[8];
    load8h(msg + (long)node * F + q * 8, acc);

    int beg = rowst[node] - beg0, end = rowend[node] - beg0;
    int e = beg;
    for (; e + 8 <= end; e += 8) {     // 8 independent gathers in flight
        h8 v[8];
#pragma unroll
        for (int u = 0; u < 8; u++)
            v[u] = *(const h8*)(msg + (long)cb[e + u] * F + q * 8);
#pragma unroll
        for (int j = 0; j < 8; j++)
            acc[j] += (((float)v[0][j] + (float)v[1][j]) + ((float)v[2][j] + (float)v[3][j])) +
                      (((float)v[4][j] + (float)v[5][j]) + ((float)v[6][j] + (float)v[7][j]));
    }
    for (; e + 4 <= end; e += 4) {
        h8 v0 = *(const h8*)(msg + (long)cb[e] * F + q * 8);
        h8 v1 = *(const h8*)(msg + (long)cb[e + 1] * F + q * 8);
        h8 v2 = *(const h8*)(msg + (long)cb[e + 2] * F + q * 8);
        h8 v3 = *(const h8*)(msg + (long)cb[e + 3] * F + q * 8);
#pragma unroll
        for (int j = 0; j < 8; j++)
            acc[j] += ((float)v0[j] + (float)v1[j]) + ((float)v2[j] + (float)v3[j]);
    }
    for (; e < end; e++) {
        h8 v = *(const h8*)(msg + (long)cb[e] * F + q * 8);
#pragma unroll
        for (int j = 0; j < 8; j++) acc[j] += (float)v[j];
    }

    float di = dinv[node];
    float o[8];
#pragma unroll
    for (int j = 0; j < 8; j++) o[j] = di * acc[j];
    if (BIAS) {
#pragma unroll
        for (int j = 0; j < 8; j++) o[j] += b[q * 8 + j];
    }
    if (F16OUT) {
        store8h((_Float16*)out + (long)node * F + q * 8, o);
    } else {
        float* dst = (float*)out + (long)node * F + q * 8;
        *(float4*)dst = make_float4(o[0], o[1], o[2], o[3]);
        *(float4*)(dst + 4) = make_float4(o[4], o[5], o[6], o[7]);
    }
}

// ---- weight swizzle -------------------------------------------------------
template <int K, int FOUT>
__device__ inline void wfrag(const float* __restrict__ W,
                             _Float16* __restrict__ Wsw, int t) {
    constexpr int NT = FOUT / 16;
    int lane = t & 63;
    int tile = (t >> 6) % NT;
    int chunk = (t >> 6) / NT;
    int kbase = chunk * 32 + (lane >> 4) * 8;
    int nc = tile * 16 + (lane & 15);
    h8 v;
#pragma unroll
    for (int j = 0; j < 8; j++) v[j] = (_Float16)W[(kbase + j) * FOUT + nc];
    ((h8*)Wsw)[t] = v;
}

__global__ __launch_bounds__(256) void wprep3_k(const float* __restrict__ W1,
                                                const float* __restrict__ W2,
                                                const float* __restrict__ W3,
                                                _Float16* __restrict__ w1s,
                                                _Float16* __restrict__ w2s,
                                                _Float16* __restrict__ w3s) {
    int t = blockIdx.x * 256 + threadIdx.x;
    if (t < 1024) wfrag<64, 128>(W1, w1s, t);
    else if (t < 3072) wfrag<128, 128>(W2, w2s, t - 1024);
    else if (t < 4096) wfrag<128, 64>(W3, w3s, t - 3072);
}

// ---- fused double GEMM: msg3 = dinv (.) ( relu(A@W2 + b2) @ W3 ) ----------
// A combined in-register: (partA + partB + self) * dinv, all [4][n][32] f16.
// 64 rows/block, 4 waves; wave-private intermediate rows in LDS.
__global__ __launch_bounds__(256) void dgemm_k(const _Float16* __restrict__ part,
                                               const _Float16* __restrict__ selfm,
                                               const _Float16* __restrict__ w2s,
                                               const _Float16* __restrict__ w3s,
                                               const float* __restrict__ b2,
                                               const float* __restrict__ dinv,
                                               _Float16* __restrict__ C, int n) {
    constexpr int LDK = 136;
    __shared__ _Float16 Hs[64 * LDK];

    int tid = threadIdx.x, lane = tid & 63, wave = tid >> 6;
    int quad = lane >> 4, cl = lane & 15;
    int row0 = blockIdx.x * 64, r0 = wave * 16;
    int arow = row0 + r0 + cl;

    const _Float16* pA = part;
    const _Float16* pB = part + (long)4 * n * 32;
    float di = dinv[arow];                 // tail rows read garbage; row-isolated

    // GEMM-1: rows r0..r0+15, K=128 -> 128.  f = c*32+quad*8 -> slice c.
    h8 a[4];
#pragma unroll
    for (int c = 0; c < 4; c++) {
        long off = ((long)c * n + arow) * 32 + quad * 8;
        h8 va = *(const h8*)(pA + off);
        h8 vb = *(const h8*)(pB + off);
        h8 vs = *(const h8*)(selfm + off);
        h8 o;
#pragma unroll
        for (int j = 0; j < 8; j++) {
            float f = (((float)va[j] + (float)vb[j]) + (float)vs[j]) * di;
            o[j] = (_Float16)f;
        }
        a[c] = o;
    }

    f4 acc1[8];
#pragma unroll
    for (int t = 0; t < 8; t++) acc1[t] = (f4){0.f, 0.f, 0.f, 0.f};
    const h8* wv2 = (const h8*)w2s;
#pragma unroll
    for (int c = 0; c < 4; c++) {
#pragma unroll
        for (int t = 0; t < 8; t++)
            acc1[t] = __builtin_amdgcn_mfma_f32_16x16x32_f16(
                a[c], wv2[(c * 8 + t) * 64 + lane], acc1[t], 0, 0, 0);
    }

    // epilogue 1: +b2, relu -> wave-private LDS rows
#pragma unroll
    for (int t = 0; t < 8; t++) {
        int c0 = t * 16 + cl;
        float bb = b2[c0];
#pragma unroll
        for (int r = 0; r < 4; r++) {
            float v = fmaxf(acc1[t][r] + bb, 0.f);
            Hs[(r0 + quad * 4 + r) * LDK + c0] = (_Float16)v;
        }
    }
    __builtin_amdgcn_s_waitcnt(0);   // drain LDS writes (wave-private rows)

    // GEMM-2: K=128 -> 64
    h8 a2[4];
#pragma unroll
    for (int c = 0; c < 4; c++)
        a2[c] = *(const h8*)(Hs + (r0 + cl) * LDK + quad * 8 + c * 32);

    f4 acc2[4];
#pragma unroll
    for (int t = 0; t < 4; t++) acc2[t] = (f4){0.f, 0.f, 0.f, 0.f};
    const h8* wv3 = (const h8*)w3s;
#pragma unroll
    for (int c = 0; c < 4; c++) {
#pragma unroll
        for (int t = 0; t < 4; t++)
            acc2[t] = __builtin_amdgcn_mfma_f32_16x16x32_f16(
                a2[c], wv3[(c * 4 + t) * 64 + lane], acc2[t], 0, 0, 0);
    }

    // epilogue 2: *dinv, store msg3 row-major [n][64]
#pragma unroll
    for (int t = 0; t < 4; t++) {
        int c0 = t * 16 + cl;
#pragma unroll
        for (int r = 0; r < 4; r++) {
            int row = row0 + r0 + quad * 4 + r;
            if (row >= n) continue;
            float v = acc2[t][r] * dinv[row];
            C[(long)row * 64 + c0] = (_Float16)v;
        }
    }
}

extern "C" void kernel_launch(void* const* d_in, const int* in_sizes, int n_in,
                              void* d_out, int out_size, void* d_ws, size_t ws_size,
                              hipStream_t stream) {
    const float* x  = (const float*)d_in[0];
    const int*   ei = (const int*)d_in[1];
    const float* W1 = (const float*)d_in[2];
    const float* b1 = (const float*)d_in[3];
    const float* W2 = (const float*)d_in[4];
    const float* b2 = (const float*)d_in[5];
    const float* W3 = (const float*)d_in[6];
    const float* b3 = (const float*)d_in[7];
    float* out = (float*)d_out;

    const int N = in_sizes[0] / 64;
    const int E = in_sizes[1] / 2;
    const int* src = ei;
    const int* dst = ei + E;
    const int nbuck = (N + BNODES - 1) >> BSHIFT;   // 782
    const int chunk = (E + PB - 1) / PB;            // 6250
    const int n2 = PB * nbuck;                      // 200192
    const int nb2 = (n2 + 255) / 256;               // 782

    // workspace carve-up (4-byte elems)
    int*   hist   = (int*)d_ws;                   // PB*nbuck
    int*   offs   = hist + n2;                    // PB*nbuck
    int*   bsums  = offs + n2;                    // 1024
    int*   bbase  = bsums + 1024;                 // nbuck+1
    int*   rowst  = bbase + nbuck + 1;            // N
    int*   rowend = rowst + N;                    // N
    float* dinv   = (float*)(rowend + N);         // N
    int*   col    = (int*)(dinv + N);             // E
    _Float16* w1s = (_Float16*)(col + E);         // 64*128 f16
    _Float16* w2s = w1s + 64 * 128;               // 128*128 f16
    _Float16* w3s = w2s + 128 * 128;              // 128*64 f16
    float* P      = (float*)(w3s + 128 * 64);     // N*128 f32 worth
    float* Q      = P + (long)N * 128;            // N*128 f32 worth

    _Float16* msgXs = (_Float16*)P;   // [2][N][32] f16 slice-major (12.8MB)
    _Float16* part1 = msgXs + (long)N * 64;  // [2][2][N][32] f16 (25.6MB)
    _Float16* part2 = (_Float16*)P;   // [2][4][N][32] f16 (51.2MB; after part1 dead)
    unsigned* ebuf  = (unsigned*)Q;   // E x 4B (dead after finalize)
    _Float16* msg1  = (_Float16*)Q;   // [4][N][32] f16 (fagc out)
    _Float16* msg3  = (_Float16*)(Q + (long)N * 64);  // [N][64] f16
    int*      midp  = (int*)(Q + (long)N * 96);       // N ints

    const int gb = (N + 63) / 64;

    // ---- weight swizzle ----
    wprep3_k<<<16, 256, 0, stream>>>(W1, W2, W3, w1s, w2s, w3s);

    // ---- CSR build ----
    phist_k<<<PB, 256, 0, stream>>>(dst, hist, E, nbuck, chunk);
    scan_blocks_k<<<nb2, 256, 0, stream>>>(hist, offs, bsums, n2);
    mid_k<<<2, 1024, 0, stream>>>(bsums, nb2, hist, bbase, nbuck, E);
    part2_k<<<PB, 256, 0, stream>>>(src, dst, offs, bsums, ebuf, E, nbuck, chunk);
    finalize_k<<<nbuck, 256, 0, stream>>>(ebuf, hist, offs, bsums, bbase, nbuck,
                                          rowst, rowend, midp, dinv, col, x,
                                          msgXs, N, N / 2);

    // ---- layer 1 gather (64B slices, src+node halves, XCD-pinned) ----
    const int nbh = ((N + 31) / 32 + 1) / 2;   // 1563
    agg_h1_k<<<8 * nbh, 256, 0, stream>>>(
        msgXs, rowst, midp, rowend, col, part1, N);

    // ---- layer 1 combine+GEMM (streaming): part1,msgXs -> msg1 [4][N][32] ----
    fagc_k<<<gb, 256, 0, stream>>>(part1, msgXs, dinv, w1s, b1, msg1, N);

    // ---- layer 2 gather (64B slices, src-half, XCD-pinned): msg1 -> part2 ----
    const int nb32 = (N + 31) / 32;      // 3125
    agg_h2_k<<<8 * nb32, 256, 0, stream>>>(
        msg1, rowst, midp, rowend, col, part2, N);

    // ---- fused gemm2+gemm3 (+combine): part2,msg1 -> msg3 row-major (Q) ----
    dgemm_k<<<gb, 256, 0, stream>>>(part2, msg1, w2s, w3s, b2, dinv, msg3, N);

    // ---- layer 3 gather (row-major, LDS col, 8-deep): msg3(Q) -> out ----
    agg_f16_k<64, true, false><<<(N + 31) / 32, 256, 0, stream>>>(
        msg3, rowst, rowend, col, dinv, b3, (void*)out, N);
}